// Round 9
// baseline (266.968 us; speedup 1.0000x reference)
//
#include <hip/hip_runtime.h>
#include <hip/hip_bf16.h>
#include <math.h>

using bf16 = __hip_bfloat16;
typedef unsigned short u16;
typedef unsigned int u32;
typedef const float* __restrict__ cfp;

typedef __attribute__((ext_vector_type(8))) short short8v;
typedef __attribute__((ext_vector_type(4))) float f32x4;
typedef __attribute__((ext_vector_type(16))) float f32x16;

static constexpr int kS = 1024, kE = 128, kH = 8, kDH = 16, kDFF = 512;
static constexpr float kEps = 1e-5f;

__device__ __forceinline__ float geluf(float x) { return 0.5f * x * (1.f + erff(x * 0.70710678118654752f)); }
__device__ __forceinline__ u16 f2b(float f) {
  u32 u = __float_as_uint(f);
  u32 r = (u + 0x7FFFu + ((u >> 16) & 1u)) >> 16;
  return (u16)r;
}

template<int N> __device__ __forceinline__ void wait_vmcnt() {
  asm volatile("s_waitcnt vmcnt(%0)" :: "n"(N) : "memory");
  __builtin_amdgcn_sched_barrier(0);
}

// ---------------- dtype detection (inputs bf16 vs f32) ----------------
__global__ void detect_kernel(const u16* __restrict__ xb, int n, int* __restrict__ flag) {
  int i = blockIdx.x * 256 + threadIdx.x;
  if (i >= n) return;
  int e = (xb[i] >> 7) & 0xFF;
  if (e >= 0xB5) *flag = 1;
}

struct CvtArgs { const void* p[27]; int cum[28]; };

__global__ void convert_kernel(CvtArgs a, const int* __restrict__ flag,
                               float* __restrict__ out, int total) {
  int idx = blockIdx.x * 256 + threadIdx.x;
  if (idx >= total) return;
  int id = 0;
  while (idx >= a.cum[id + 1]) ++id;
  int local = idx - a.cum[id];
  float v;
  if (*flag) v = ((const float*)a.p[id])[local];
  else       v = __bfloat162float(((const bf16*)a.p[id])[local]);
  out[idx] = v;
}

// ---------------- w2 f32 -> bf16, chunk-permuted for gload_lds swizzle ----------------
__global__ __launch_bounds__(256) void wcvt_kernel(cfp w2, u16* __restrict__ w2b) {
  int n = blockIdx.x;
  int ck = threadIdx.x;
  const float* src = w2 + (size_t)n * 2048 + (size_t)ck * 8;
  float4 a = *(const float4*)src;
  float4 b = *(const float4*)(src + 4);
  short8v sv;
  sv[0] = (short)f2b(a.x); sv[1] = (short)f2b(a.y);
  sv[2] = (short)f2b(a.z); sv[3] = (short)f2b(a.w);
  sv[4] = (short)f2b(b.x); sv[5] = (short)f2b(b.y);
  sv[6] = (short)f2b(b.z); sv[7] = (short)f2b(b.w);
  int cd = (ck & ~7) | ((ck & 7) ^ (n & 7));
  *(short8v*)(w2b + (size_t)n * 2048 + cd * 8) = sv;
}

// ---------------- conv1+bn1+gelu -> Abuf bf16 [8192][2048], chunk-permuted ----------------
__global__ __launch_bounds__(256) void convstage_kernel(
    cfp x, cfp w1, cfp c1b, cfp g1, cfp b1, cfp m1, cfp v1,
    u16* __restrict__ Abuf, int grow0) {
  __shared__ float xs[8][4];
  int row = blockIdx.x;
  int grow = grow0 + row;
  int b = grow >> 10, s = grow & 1023;
  int tid = threadIdx.x;
  if (tid < 8) {
    int gs = s - 3 + tid;
    float4 xv = (gs >= 0 && gs < kS) ? ((const float4*)x)[b * kS + gs]
                                     : make_float4(0.f, 0.f, 0.f, 0.f);
    xs[tid][0] = xv.x; xs[tid][1] = xv.y; xs[tid][2] = xv.z; xs[tid][3] = xv.w;
  }
  __syncthreads();
  short8v outv;
#pragma unroll
  for (int cc = 0; cc < 2; ++cc) {
    int cx = tid * 2 + cc;
    float w[8];
#pragma unroll
    for (int t = 0; t < 8; ++t) w[t] = w1[cx * 8 + t];
    float sc = g1[cx] * __frsqrt_rn(v1[cx] + kEps);
    float ofs = b1[cx] - m1[cx] * sc;
    float cb = c1b[cx];
#pragma unroll
    for (int r = 0; r < 4; ++r) {
      float h = cb;
#pragma unroll
      for (int t = 0; t < 8; ++t) h += xs[t][r] * w[t];
      outv[cc * 4 + r] = (short)f2b(geluf(h * sc + ofs));
    }
  }
  int ck = (tid & ~7) | ((tid & 7) ^ (row & 7));
  *(short8v*)(Abuf + (size_t)row * 2048 + ck * 8) = outv;
}

// ---------------- rel-bias MFMA fragment table ----------------
__global__ __launch_bounds__(64) void rbtab_kernel(cfp relb, u16* __restrict__ T) {
  int t = blockIdx.x, h = blockIdx.y;
  int l = threadIdx.x;
  int lr = l & 15, lg = l >> 4;
  short8v v;
#pragma unroll
  for (int e = 0; e < 8; ++e) {
    int idx = 16 * t + 31 + lr - 8 * lg - e;
    v[e] = (short)f2b(relb[idx * 8 + h]);
  }
  *(short8v*)(T + ((size_t)(h * 126 + t) * 64 + l) * 8) = v;
}

// =====================================================================
// Pipelined conv GEMM (unchanged — proven)
// =====================================================================
__global__ __launch_bounds__(256, 2) void convgemm_kernel(
    const u16* __restrict__ Abuf, const u16* __restrict__ w2b,
    cfp c2b, cfp g2, cfp b2, cfp m2, cfp v2,
    float* __restrict__ xsrc, u16* __restrict__ xpeb, int mbase) {
  __shared__ short8v lds[3840];
  const int tid = threadIdx.x;
  const int mtile = blockIdx.x;
  const int wid = tid >> 6, lane = tid & 63;
  const int lrow = lane & 15, lk = lane >> 4;
  const int m0w = (wid & 1) * 16, n0w = (wid >> 1) * 64;

  float scn[4], cc[4], dv[4];
#pragma unroll
  for (int ni = 0; ni < 4; ++ni) {
    int n = n0w + ni * 16 + lrow;
    scn[ni] = g2[n] * __frsqrt_rn(v2[n] + kEps);
    cc[ni] = (c2b[n] - m2[n]) * scn[ni] + b2[n];
    dv[ni] = __expf((float)(n >> 1) * (-0.14391156824963732f)) * 0.125f;
  }

  f32x4 acc[4];
#pragma unroll
  for (int ni = 0; ni < 4; ++ni) acc[ni] = (f32x4){0.f, 0.f, 0.f, 0.f};

  const int q = wid * 64 + lane;
  const u16* aG = Abuf + (size_t)(mtile * 32 + (q >> 3)) * 2048 + (q & 7) * 8;

  auto stage = [&](int t) {
    int buf = t % 3;
    short8v* A = lds + buf * 1280;
    __builtin_amdgcn_global_load_lds(
        (const __attribute__((address_space(1))) void*)(aG + t * 64),
        (__attribute__((address_space(3))) void*)(A + wid * 64), 16, 0, 0);
#pragma unroll
    for (int r = 0; r < 4; ++r) {
      int qq = r * 256 + q;
      const u16* g = w2b + (size_t)(qq >> 3) * 2048 + t * 64 + (qq & 7) * 8;
      __builtin_amdgcn_global_load_lds(
          (const __attribute__((address_space(1))) void*)g,
          (__attribute__((address_space(3))) void*)(A + 256 + r * 256 + wid * 64), 16, 0, 0);
    }
  };

  auto compute = [&](int t) {
    int buf = t % 3;
    const short8v* A = lds + buf * 1280;
    const short8v* B = A + 256;
#pragma unroll
    for (int ks = 0; ks < 2; ++ks) {
      int ar = m0w + lrow;
      u32 ao = ((u32)(ar * 128 + ks * 64 + lk * 16)) ^ ((u32)((ar & 7) << 4));
      short8v af = A[ao >> 4];
#pragma unroll
      for (int ni = 0; ni < 4; ++ni) {
        int br = n0w + ni * 16 + lrow;
        u32 bo = ((u32)(br * 128 + ks * 64 + lk * 16)) ^ ((u32)((br & 7) << 4));
        short8v bf = B[bo >> 4];
        acc[ni] = __builtin_amdgcn_mfma_f32_16x16x32_bf16(af, bf, acc[ni], 0, 0, 0);
      }
    }
  };

  stage(0); stage(1); stage(2);
  for (int t = 0; t < 30; ++t) {
    wait_vmcnt<10>();
    __builtin_amdgcn_s_barrier();
    __builtin_amdgcn_sched_barrier(0);
    compute(t);
    asm volatile("" ::: "memory");
    __builtin_amdgcn_s_barrier();
    __builtin_amdgcn_sched_barrier(0);
    if (t <= 28) stage(t + 3);
  }
  wait_vmcnt<5>();
  __builtin_amdgcn_s_barrier();
  __builtin_amdgcn_sched_barrier(0);
  compute(30);
  asm volatile("" ::: "memory");
  __builtin_amdgcn_s_barrier();
  __builtin_amdgcn_sched_barrier(0);
  wait_vmcnt<0>();
  __builtin_amdgcn_s_barrier();
  __builtin_amdgcn_sched_barrier(0);
  compute(31);

#pragma unroll
  for (int ni = 0; ni < 4; ++ni) {
    int n = n0w + ni * 16 + lrow;
#pragma unroll
    for (int r = 0; r < 4; ++r) {
      int grow = mbase + mtile * 32 + m0w + lk * 4 + r;
      float gv = geluf(acc[ni][r] * scn[ni] + cc[ni]);
      xsrc[(size_t)grow * kE + n] = gv;
      int s = grow & 1023;
      float ang = (float)s * dv[ni];
      float pe = (n & 1) ? __cosf(ang) : __sinf(ang);
      xpeb[(size_t)grow * kE + n] = f2b(gv + pe);
    }
  }
}

// =====================================================================
// bf16 MFMA GEMM (QKV / FF1 / FF2). MODE==1 z==0 (Q) pre-scaled by
// 128^-0.5 * log2(e) so attention can use exp2 directly.
// =====================================================================
template<int ASRC, int MODE, int KTOT, int BM>
__global__ __launch_bounds__(256, 4) void gemm_kernel(
    const void* __restrict__ Ap, cfp Wf,
    cfp p0, cfp p1, cfp p2, cfp p3, cfp p4, cfp p5,
    cfp p6, cfp p7, cfp p8, cfp p9, cfp p10,
    void* __restrict__ Out, void* __restrict__ Out2, cfp res, int mbase) {
  constexpr int MI = BM / 32;
  __shared__ short8v Ab[BM * 8];
  __shared__ short8v Bb[512];

  int tid = threadIdx.x;
  int mtile = blockIdx.x, ntile = blockIdx.y;

  cfp Wsel = Wf;
  if (MODE == 1) Wsel = (blockIdx.z == 0) ? Wf : ((blockIdx.z == 1) ? p1 : p2);

  int wid = tid >> 6, lane = tid & 63;
  int m0w = (wid >> 1) * (BM / 2), n0w = (wid & 1) * 32;
  int lrow = lane & 15, lk = lane >> 4;

  f32x4 acc[MI][2];
#pragma unroll
  for (int mi = 0; mi < MI; ++mi)
#pragma unroll
    for (int ni = 0; ni < 2; ++ni) acc[mi][ni] = (f32x4){0.f, 0.f, 0.f, 0.f};

  for (int k0 = 0; k0 < KTOT; k0 += 64) {
    __syncthreads();
#pragma unroll
    for (int c = 0; c < BM / 32; ++c) {
      int chunk = tid + 256 * c;
      int row = chunk >> 3, kc = chunk & 7;
      int arow = mtile * BM + row;
      u32 off = ((u32)(row * 128 + kc * 16)) ^ ((u32)((row & 7) << 4));
      const u16* As = (const u16*)Ap + (size_t)arow * KTOT + k0 + kc * 8;
      Ab[off >> 4] = *(const short8v*)As;
    }
#pragma unroll
    for (int c = 0; c < 2; ++c) {
      int chunk = tid + 256 * c;
      int row = chunk >> 3, kc = chunk & 7;
      const float* Wp = Wsel + (size_t)(ntile * 64 + row) * KTOT + k0 + kc * 8;
      float4 xa = *(const float4*)Wp;
      float4 xb = *(const float4*)(Wp + 4);
      short8v sv;
      sv[0] = (short)f2b(xa.x); sv[1] = (short)f2b(xa.y);
      sv[2] = (short)f2b(xa.z); sv[3] = (short)f2b(xa.w);
      sv[4] = (short)f2b(xb.x); sv[5] = (short)f2b(xb.y);
      sv[6] = (short)f2b(xb.z); sv[7] = (short)f2b(xb.w);
      u32 off = ((u32)(row * 128 + kc * 16)) ^ ((u32)((row & 7) << 4));
      Bb[off >> 4] = sv;
    }
    __syncthreads();
#pragma unroll
    for (int ks = 0; ks < 2; ++ks) {
      short8v af[MI], bfr[2];
#pragma unroll
      for (int mi = 0; mi < MI; ++mi) {
        int row = m0w + mi * 16 + lrow;
        u32 off = ((u32)(row * 128 + ks * 64 + lk * 16)) ^ ((u32)((row & 7) << 4));
        af[mi] = Ab[off >> 4];
      }
#pragma unroll
      for (int ni = 0; ni < 2; ++ni) {
        int row = n0w + ni * 16 + lrow;
        u32 off = ((u32)(row * 128 + ks * 64 + lk * 16)) ^ ((u32)((row & 7) << 4));
        bfr[ni] = Bb[off >> 4];
      }
#pragma unroll
      for (int mi = 0; mi < MI; ++mi)
#pragma unroll
        for (int ni = 0; ni < 2; ++ni)
          acc[mi][ni] = __builtin_amdgcn_mfma_f32_16x16x32_bf16(af[mi], bfr[ni], acc[mi][ni], 0, 0, 0);
    }
  }

  const float qsc = 0.088388347648318447f * 1.4426950408889634f;
#pragma unroll
  for (int ni = 0; ni < 2; ++ni) {
    int n = ntile * 64 + n0w + ni * 16 + lrow;
    float c0 = 0.f;
    if (MODE == 2 || MODE == 3) c0 = p0[n];
#pragma unroll
    for (int mi = 0; mi < MI; ++mi) {
#pragma unroll
      for (int r = 0; r < 4; ++r) {
        int grow = mbase + mtile * BM + m0w + mi * 16 + lk * 4 + r;
        float val = acc[mi][ni][r];
        if (MODE == 1) {
          if (blockIdx.z == 0) val *= qsc;
          int s = grow & 1023, b_ = grow >> 10;
          u16* ob = (u16*)Out + (size_t)blockIdx.z * 2097152;
          ob[(((size_t)(b_ * kH + (n >> 4))) * kS + s) * kDH + (n & 15)] = f2b(val);
        } else if (MODE == 2) {
          ((u16*)Out)[(size_t)grow * kDFF + n] = f2b(fmaxf(val + c0, 0.f));
        } else {
          ((float*)Out)[(size_t)grow * kE + n] = val + c0 + res[(size_t)grow * kE + n];
        }
      }
    }
  }
}

// =====================================================================
// MFMA attention v4: 32x32x16 QK, exp2, cvt_pk packing, conflict-free
// P stride 34, softmax denominator via ones-MFMA (same C layout as PV).
// =====================================================================
__global__ __launch_bounds__(512, 4) void attn_kernel(
    const u16* __restrict__ qb, const u16* __restrict__ kb,
    const u16* __restrict__ vb, const u16* __restrict__ rbT,
    float* __restrict__ o) {
  __shared__ u16 Vsh[16 * 1032];   // V^T [d][j], stride 1032
  __shared__ u16 Pt[8][1088];      // per-wave P [32 q][34 k-stride]

  int tid = threadIdx.x;
  int quarter = blockIdx.x & 3;
  int h = (blockIdx.x >> 2) & 7;
  int bb = blockIdx.x >> 5;
  size_t base = (size_t)(bb * kH + h) * (kS * kDH);

  for (int j = tid; j < 1024; j += 512) {
    const uint4* src = (const uint4*)(vb + base + j * 16);
    uint4 a = src[0], b = src[1];
    u32 wv[8] = {a.x, a.y, a.z, a.w, b.x, b.y, b.z, b.w};
#pragma unroll
    for (int p = 0; p < 8; ++p) {
      Vsh[(2 * p) * 1032 + j]     = (u16)(wv[p] & 0xFFFFu);
      Vsh[(2 * p + 1) * 1032 + j] = (u16)(wv[p] >> 16);
    }
  }
  __syncthreads();

  int w = tid >> 6, l = tid & 63;
  int lr = l & 15, lg = l >> 4;      // PV-side coords
  int q32 = l & 31, hi = l >> 5;     // QK-side coords
  u16* P = Pt[w];
  int q0w = quarter * 256 + w * 32;
  int tbase = (q0w + 992) >> 4;
  const u16* rbh = rbT + (size_t)h * 126 * 512;

  short8v qf = *(const short8v*)(qb + base + (size_t)(q0w + q32) * 16 + hi * 8);
  short8v ones;
#pragma unroll
  for (int e = 0; e < 8; ++e) ones[e] = (short)0x3F80;

  f32x4 acc_e[2], acc_rb[2], acc_l[2];
#pragma unroll
  for (int qt = 0; qt < 2; ++qt) {
    acc_e[qt] = (f32x4){0.f, 0.f, 0.f, 0.f};
    acc_rb[qt] = (f32x4){0.f, 0.f, 0.f, 0.f};
    acc_l[qt] = (f32x4){0.f, 0.f, 0.f, 0.f};
  }
  const f32x16 z16 = {0.f,0.f,0.f,0.f,0.f,0.f,0.f,0.f,0.f,0.f,0.f,0.f,0.f,0.f,0.f,0.f};

  for (int jb = 0; jb < 32; ++jb) {
    short8v kf = *(const short8v*)(kb + base + (size_t)(jb * 32 + q32) * 16 + hi * 8);
    // S^T: lane holds col q = q32, rows k = (reg&3) + 8*(reg>>2) + 4*hi
    f32x16 s = __builtin_amdgcn_mfma_f32_32x32x16_bf16(kf, qf, z16, 0, 0, 0);
    float ev[16];
#pragma unroll
    for (int r = 0; r < 16; ++r) ev[r] = exp2f(s[r]);
#pragma unroll
    for (int rq = 0; rq < 4; ++rq) {
      u32 p0, p1;
      asm("v_cvt_pk_bf16_f32 %0, %1, %2" : "=v"(p0) : "v"(ev[4 * rq]), "v"(ev[4 * rq + 1]));
      asm("v_cvt_pk_bf16_f32 %0, %1, %2" : "=v"(p1) : "v"(ev[4 * rq + 2]), "v"(ev[4 * rq + 3]));
      *(uint2*)(P + q32 * 34 + rq * 8 + hi * 4) = make_uint2(p0, p1);
    }
    short8v vf = *(const short8v*)(Vsh + lr * 1032 + jb * 32 + lg * 8);
#pragma unroll
    for (int qt = 0; qt < 2; ++qt) {
      short8v pf = *(const short8v*)(P + (qt * 16 + lr) * 34 + lg * 8);
      int t = tbase + qt - 2 * jb;
      short8v rf = *(const short8v*)(rbh + ((size_t)t * 64 + l) * 8);
      acc_e[qt]  = __builtin_amdgcn_mfma_f32_16x16x32_bf16(pf, vf, acc_e[qt], 0, 0, 0);
      acc_l[qt]  = __builtin_amdgcn_mfma_f32_16x16x32_bf16(pf, ones, acc_l[qt], 0, 0, 0);
      acc_rb[qt] = __builtin_amdgcn_mfma_f32_16x16x32_bf16(rf, vf, acc_rb[qt], 0, 0, 0);
    }
  }

#pragma unroll
  for (int qt = 0; qt < 2; ++qt) {
#pragma unroll
    for (int r = 0; r < 4; ++r) {
      int qloc = qt * 16 + lg * 4 + r;
      int row = q0w + qloc;
      o[(size_t)(bb * kS + row) * kE + h * kDH + lr] =
          acc_e[qt][r] / acc_l[qt][r] + acc_rb[qt][r];
    }
  }
}

// ---------------- LN(attn out) + residual + LN1 -> att (f32 + bf16) ----------------
__global__ __launch_bounds__(256) void ln_kernel(
    cfp o, cfp xsrc, cfp lag, cfp lab, cfp l1g, cfp l1b,
    float* __restrict__ att, u16* __restrict__ attb) {
  int row = blockIdx.x * 4 + (threadIdx.x >> 6);
  int lane = threadIdx.x & 63;
  float2 a = ((const float2*)(o + (size_t)row * kE))[lane];
  float sum = a.x + a.y;
  for (int off = 1; off < 64; off <<= 1) sum += __shfl_xor(sum, off);
  float mean = sum * (1.f / 128.f);
  float d0 = a.x - mean, d1 = a.y - mean;
  float ss = d0 * d0 + d1 * d1;
  for (int off = 1; off < 64; off <<= 1) ss += __shfl_xor(ss, off);
  float inv = 1.f / sqrtf(ss * (1.f / 128.f) + kEps);
  float t0 = d0 * inv * lag[2 * lane] + lab[2 * lane];
  float t1 = d1 * inv * lag[2 * lane + 1] + lab[2 * lane + 1];
  float2 xv = ((const float2*)(xsrc + (size_t)row * kE))[lane];
  t0 += xv.x; t1 += xv.y;
  float sum2 = t0 + t1;
  for (int off = 1; off < 64; off <<= 1) sum2 += __shfl_xor(sum2, off);
  float mean2 = sum2 * (1.f / 128.f);
  float e0 = t0 - mean2, e1 = t1 - mean2;
  float ss2 = e0 * e0 + e1 * e1;
  for (int off = 1; off < 64; off <<= 1) ss2 += __shfl_xor(ss2, off);
  float inv2 = 1.f / sqrtf(ss2 * (1.f / 128.f) + kEps);
  float r0 = e0 * inv2 * l1g[2 * lane] + l1b[2 * lane];
  float r1 = e1 * inv2 * l1g[2 * lane + 1] + l1b[2 * lane + 1];
  ((float2*)(att + (size_t)row * kE))[lane] = make_float2(r0, r1);
  ((u32*)attb)[(size_t)row * 64 + lane] = (u32)f2b(r0) | ((u32)f2b(r1) << 16);
}

// ---------------- LN2 + GAP ----------------
__global__ __launch_bounds__(256) void ln2gap_kernel(
    cfp yff, cfp l2g, cfp l2b, float* __restrict__ outacc) {
  __shared__ float red[128];
  int tid = threadIdx.x;
  if (tid < 128) red[tid] = 0.f;
  __syncthreads();
  int row = blockIdx.x * 4 + (tid >> 6);
  int lane = tid & 63;
  float2 a = ((const float2*)(yff + (size_t)row * kE))[lane];
  float sum = a.x + a.y;
  for (int off = 1; off < 64; off <<= 1) sum += __shfl_xor(sum, off);
  float mean = sum * (1.f / 128.f);
  float d0 = a.x - mean, d1 = a.y - mean;
  float ss = d0 * d0 + d1 * d1;
  for (int off = 1; off < 64; off <<= 1) ss += __shfl_xor(ss, off);
  float inv = 1.f / sqrtf(ss * (1.f / 128.f) + kEps);
  float r0 = d0 * inv * l2g[2 * lane] + l2b[2 * lane];
  float r1 = d1 * inv * l2g[2 * lane + 1] + l2b[2 * lane + 1];
  atomicAdd(&red[2 * lane], r0);
  atomicAdd(&red[2 * lane + 1], r1);
  __syncthreads();
  int bb = (blockIdx.x * 4) >> 10;
  if (tid < 128) atomicAdd(&outacc[bb * kE + tid], red[tid]);
}

// ---------------- finalize ----------------
__global__ void fin_kernel(cfp outacc, const int* __restrict__ flag, void* __restrict__ out) {
  int i = blockIdx.x * 256 + threadIdx.x;
  float v = outacc[i] * (1.f / 1024.f);
  if (*flag) ((float*)out)[i] = v;
  else       ((bf16*)out)[i] = __float2bfloat16(v);
}

extern "C" void kernel_launch(void* const* d_in, const int* in_sizes, int n_in,
                              void* d_out, int out_size, void* d_ws, size_t ws_size,
                              hipStream_t stream) {
  CvtArgs args;
  int cum = 0;
  for (int i = 0; i < n_in && i < 27; ++i) {
    args.p[i] = d_in[i];
    args.cum[i] = cum;
    cum += in_sizes[i];
  }
  args.cum[n_in] = cum;
  int total = cum;
  int totalPad = (total + 15) & ~15;

  float* ws = (float*)d_ws;
  int* flag    = (int*)ws;
  float* wsinf = ws + 16;
  float* xsrc  = wsinf + totalPad;               // 2,097,152 f32
  float* att   = xsrc + 2097152;                 // 2,097,152 f32
  float* qkv0  = att + 2097152;                  // 3,145,728 (q,k,v bf16)
  float* ext   = qkv0 + 3145728;                 // 1,048,576 (rbT; ff1b tail)
  float* o     = ext + 1048576;                  // 2,097,152 (later yff)
  float* outacc = o + 2097152;                   // 2,048
  u16* xpeb    = (u16*)(outacc + 2048);          // 2,097,152 u16
  u16* w2b     = xpeb + 2097152;                 // 262,144 u16

  u16* Abuf = (u16*)att;
  u16* qb = (u16*)qkv0;
  u16* kb = qb + 2097152;
  u16* vb = kb + 2097152;
  u16* rbT = (u16*)ext;
  u16* ff1b = (u16*)qkv0;
  u16* attb = xpeb;
  float* yff = o;

  const float* wf[27];
  for (int i = 0; i < n_in && i < 27; ++i) wf[i] = wsinf + args.cum[i];

  hipMemsetAsync(flag, 0, sizeof(int), stream);
  hipMemsetAsync(outacc, 0, 2048 * sizeof(float), stream);
  detect_kernel<<<(in_sizes[0] + 255) / 256, 256, 0, stream>>>(
      (const u16*)d_in[0], in_sizes[0], flag);
  convert_kernel<<<(total + 255) / 256, 256, 0, stream>>>(args, flag, wsinf, total);
  wcvt_kernel<<<128, 256, 0, stream>>>(wf[7], w2b);

  for (int hm = 0; hm < 2; ++hm) {
    convstage_kernel<<<8192, 256, 0, stream>>>(
        wf[0], wf[1], wf[2], wf[3], wf[4], wf[5], wf[6], Abuf, hm * 8192);
    convgemm_kernel<<<256, 256, 0, stream>>>(
        Abuf, w2b, wf[8], wf[9], wf[10], wf[11], wf[12], xsrc, xpeb, hm * 8192);
  }

  rbtab_kernel<<<dim3(126, 8), 64, 0, stream>>>(wf[16], rbT);

  // QKV: BM=64, grid 1536 -> 6 blocks/CU
  gemm_kernel<3, 1, 128, 64><<<dim3(256, 2, 3), 256, 0, stream>>>(
      xpeb, wf[13], nullptr, wf[14], wf[15], nullptr, nullptr, nullptr,
      nullptr, nullptr, nullptr, nullptr, nullptr, qb, nullptr, nullptr, 0);

  attn_kernel<<<512, 512, 0, stream>>>(qb, kb, vb, rbT, o);
  ln_kernel<<<4096, 256, 0, stream>>>(o, xsrc, wf[17], wf[18], wf[19], wf[20], att, attb);

  // FF1: BM=64, grid 2048 -> 8 blocks/CU
  gemm_kernel<3, 2, 128, 64><<<dim3(256, 8), 256, 0, stream>>>(
      attb, wf[21], wf[22], nullptr, nullptr, nullptr, nullptr, nullptr,
      nullptr, nullptr, nullptr, nullptr, nullptr, ff1b, nullptr, nullptr, 0);
  // FF2: BM=64, grid 512 -> 2 blocks/CU
  gemm_kernel<3, 3, 512, 64><<<dim3(256, 2), 256, 0, stream>>>(
      ff1b, wf[23], wf[24], nullptr, nullptr, nullptr, nullptr, nullptr,
      nullptr, nullptr, nullptr, nullptr, nullptr, yff, nullptr, att, 0);

  ln2gap_kernel<<<4096, 256, 0, stream>>>(yff, wf[25], wf[26], outacc);
  fin_kernel<<<8, 256, 0, stream>>>(outacc, flag, d_out);
}

// Round 10
// 213.464 us; speedup vs baseline: 1.2506x; 1.2506x over previous
//
#include <hip/hip_runtime.h>
#include <hip/hip_bf16.h>
#include <math.h>

using bf16 = __hip_bfloat16;
typedef unsigned short u16;
typedef unsigned int u32;
typedef const float* __restrict__ cfp;

typedef __attribute__((ext_vector_type(8))) short short8v;
typedef __attribute__((ext_vector_type(4))) float f32x4;
typedef __attribute__((ext_vector_type(16))) float f32x16;

static constexpr int kS = 1024, kE = 128, kH = 8, kDH = 16, kDFF = 512;
static constexpr float kEps = 1e-5f;

__device__ __forceinline__ float geluf(float x) { return 0.5f * x * (1.f + erff(x * 0.70710678118654752f)); }
__device__ __forceinline__ u16 f2b(float f) {
  u32 u = __float_as_uint(f);
  u32 r = (u + 0x7FFFu + ((u >> 16) & 1u)) >> 16;
  return (u16)r;
}

template<int N> __device__ __forceinline__ void wait_vmcnt() {
  asm volatile("s_waitcnt vmcnt(%0)" :: "n"(N) : "memory");
  __builtin_amdgcn_sched_barrier(0);
}

// ---------------- dtype detection (inputs bf16 vs f32) ----------------
__global__ void detect_kernel(const u16* __restrict__ xb, int n, int* __restrict__ flag) {
  int i = blockIdx.x * 256 + threadIdx.x;
  if (i >= n) return;
  int e = (xb[i] >> 7) & 0xFF;
  if (e >= 0xB5) *flag = 1;
}

struct CvtArgs { const void* p[27]; int cum[28]; };

__global__ void convert_kernel(CvtArgs a, const int* __restrict__ flag,
                               float* __restrict__ out, int total) {
  int idx = blockIdx.x * 256 + threadIdx.x;
  if (idx >= total) return;
  int id = 0;
  while (idx >= a.cum[id + 1]) ++id;
  int local = idx - a.cum[id];
  float v;
  if (*flag) v = ((const float*)a.p[id])[local];
  else       v = __bfloat162float(((const bf16*)a.p[id])[local]);
  out[idx] = v;
}

// ---------------- w2 f32 -> bf16, chunk-permuted for gload_lds swizzle ----------------
__global__ __launch_bounds__(256) void wcvt_kernel(cfp w2, u16* __restrict__ w2b) {
  int n = blockIdx.x;
  int ck = threadIdx.x;
  const float* src = w2 + (size_t)n * 2048 + (size_t)ck * 8;
  float4 a = *(const float4*)src;
  float4 b = *(const float4*)(src + 4);
  short8v sv;
  sv[0] = (short)f2b(a.x); sv[1] = (short)f2b(a.y);
  sv[2] = (short)f2b(a.z); sv[3] = (short)f2b(a.w);
  sv[4] = (short)f2b(b.x); sv[5] = (short)f2b(b.y);
  sv[6] = (short)f2b(b.z); sv[7] = (short)f2b(b.w);
  int cd = (ck & ~7) | ((ck & 7) ^ (n & 7));
  *(short8v*)(w2b + (size_t)n * 2048 + cd * 8) = sv;
}

// ---------------- conv1+bn1+gelu -> Abuf bf16 [8192][2048], chunk-permuted ----------------
__global__ __launch_bounds__(256) void convstage_kernel(
    cfp x, cfp w1, cfp c1b, cfp g1, cfp b1, cfp m1, cfp v1,
    u16* __restrict__ Abuf, int grow0) {
  __shared__ float xs[8][4];
  int row = blockIdx.x;
  int grow = grow0 + row;
  int b = grow >> 10, s = grow & 1023;
  int tid = threadIdx.x;
  if (tid < 8) {
    int gs = s - 3 + tid;
    float4 xv = (gs >= 0 && gs < kS) ? ((const float4*)x)[b * kS + gs]
                                     : make_float4(0.f, 0.f, 0.f, 0.f);
    xs[tid][0] = xv.x; xs[tid][1] = xv.y; xs[tid][2] = xv.z; xs[tid][3] = xv.w;
  }
  __syncthreads();
  short8v outv;
#pragma unroll
  for (int cc = 0; cc < 2; ++cc) {
    int cx = tid * 2 + cc;
    float w[8];
#pragma unroll
    for (int t = 0; t < 8; ++t) w[t] = w1[cx * 8 + t];
    float sc = g1[cx] * __frsqrt_rn(v1[cx] + kEps);
    float ofs = b1[cx] - m1[cx] * sc;
    float cb = c1b[cx];
#pragma unroll
    for (int r = 0; r < 4; ++r) {
      float h = cb;
#pragma unroll
      for (int t = 0; t < 8; ++t) h += xs[t][r] * w[t];
      outv[cc * 4 + r] = (short)f2b(geluf(h * sc + ofs));
    }
  }
  int ck = (tid & ~7) | ((tid & 7) ^ (row & 7));
  *(short8v*)(Abuf + (size_t)row * 2048 + ck * 8) = outv;
}

// ---------------- rel-bias MFMA fragment table ----------------
__global__ __launch_bounds__(64) void rbtab_kernel(cfp relb, u16* __restrict__ T) {
  int t = blockIdx.x, h = blockIdx.y;
  int l = threadIdx.x;
  int lr = l & 15, lg = l >> 4;
  short8v v;
#pragma unroll
  for (int e = 0; e < 8; ++e) {
    int idx = 16 * t + 31 + lr - 8 * lg - e;
    v[e] = (short)f2b(relb[idx * 8 + h]);
  }
  *(short8v*)(T + ((size_t)(h * 126 + t) * 64 + l) * 8) = v;
}

// =====================================================================
// Pipelined conv GEMM (unchanged — proven)
// =====================================================================
__global__ __launch_bounds__(256, 2) void convgemm_kernel(
    const u16* __restrict__ Abuf, const u16* __restrict__ w2b,
    cfp c2b, cfp g2, cfp b2, cfp m2, cfp v2,
    float* __restrict__ xsrc, u16* __restrict__ xpeb, int mbase) {
  __shared__ short8v lds[3840];
  const int tid = threadIdx.x;
  const int mtile = blockIdx.x;
  const int wid = tid >> 6, lane = tid & 63;
  const int lrow = lane & 15, lk = lane >> 4;
  const int m0w = (wid & 1) * 16, n0w = (wid >> 1) * 64;

  float scn[4], cc[4], dv[4];
#pragma unroll
  for (int ni = 0; ni < 4; ++ni) {
    int n = n0w + ni * 16 + lrow;
    scn[ni] = g2[n] * __frsqrt_rn(v2[n] + kEps);
    cc[ni] = (c2b[n] - m2[n]) * scn[ni] + b2[n];
    dv[ni] = __expf((float)(n >> 1) * (-0.14391156824963732f)) * 0.125f;
  }

  f32x4 acc[4];
#pragma unroll
  for (int ni = 0; ni < 4; ++ni) acc[ni] = (f32x4){0.f, 0.f, 0.f, 0.f};

  const int q = wid * 64 + lane;
  const u16* aG = Abuf + (size_t)(mtile * 32 + (q >> 3)) * 2048 + (q & 7) * 8;

  auto stage = [&](int t) {
    int buf = t % 3;
    short8v* A = lds + buf * 1280;
    __builtin_amdgcn_global_load_lds(
        (const __attribute__((address_space(1))) void*)(aG + t * 64),
        (__attribute__((address_space(3))) void*)(A + wid * 64), 16, 0, 0);
#pragma unroll
    for (int r = 0; r < 4; ++r) {
      int qq = r * 256 + q;
      const u16* g = w2b + (size_t)(qq >> 3) * 2048 + t * 64 + (qq & 7) * 8;
      __builtin_amdgcn_global_load_lds(
          (const __attribute__((address_space(1))) void*)g,
          (__attribute__((address_space(3))) void*)(A + 256 + r * 256 + wid * 64), 16, 0, 0);
    }
  };

  auto compute = [&](int t) {
    int buf = t % 3;
    const short8v* A = lds + buf * 1280;
    const short8v* B = A + 256;
#pragma unroll
    for (int ks = 0; ks < 2; ++ks) {
      int ar = m0w + lrow;
      u32 ao = ((u32)(ar * 128 + ks * 64 + lk * 16)) ^ ((u32)((ar & 7) << 4));
      short8v af = A[ao >> 4];
#pragma unroll
      for (int ni = 0; ni < 4; ++ni) {
        int br = n0w + ni * 16 + lrow;
        u32 bo = ((u32)(br * 128 + ks * 64 + lk * 16)) ^ ((u32)((br & 7) << 4));
        short8v bf = B[bo >> 4];
        acc[ni] = __builtin_amdgcn_mfma_f32_16x16x32_bf16(af, bf, acc[ni], 0, 0, 0);
      }
    }
  };

  stage(0); stage(1); stage(2);
  for (int t = 0; t < 30; ++t) {
    wait_vmcnt<10>();
    __builtin_amdgcn_s_barrier();
    __builtin_amdgcn_sched_barrier(0);
    compute(t);
    asm volatile("" ::: "memory");
    __builtin_amdgcn_s_barrier();
    __builtin_amdgcn_sched_barrier(0);
    if (t <= 28) stage(t + 3);
  }
  wait_vmcnt<5>();
  __builtin_amdgcn_s_barrier();
  __builtin_amdgcn_sched_barrier(0);
  compute(30);
  asm volatile("" ::: "memory");
  __builtin_amdgcn_s_barrier();
  __builtin_amdgcn_sched_barrier(0);
  wait_vmcnt<0>();
  __builtin_amdgcn_s_barrier();
  __builtin_amdgcn_sched_barrier(0);
  compute(31);

#pragma unroll
  for (int ni = 0; ni < 4; ++ni) {
    int n = n0w + ni * 16 + lrow;
#pragma unroll
    for (int r = 0; r < 4; ++r) {
      int grow = mbase + mtile * 32 + m0w + lk * 4 + r;
      float gv = geluf(acc[ni][r] * scn[ni] + cc[ni]);
      xsrc[(size_t)grow * kE + n] = gv;
      int s = grow & 1023;
      float ang = (float)s * dv[ni];
      float pe = (n & 1) ? __cosf(ang) : __sinf(ang);
      xpeb[(size_t)grow * kE + n] = f2b(gv + pe);
    }
  }
}

// =====================================================================
// bf16 MFMA GEMM (QKV / FF1 / FF2). MODE==1 z==0 (Q) pre-scaled by
// 128^-0.5 * log2(e) so attention can use exp2 directly.
// =====================================================================
template<int ASRC, int MODE, int KTOT, int BM>
__global__ __launch_bounds__(256, 4) void gemm_kernel(
    const void* __restrict__ Ap, cfp Wf,
    cfp p0, cfp p1, cfp p2, cfp p3, cfp p4, cfp p5,
    cfp p6, cfp p7, cfp p8, cfp p9, cfp p10,
    void* __restrict__ Out, void* __restrict__ Out2, cfp res, int mbase) {
  constexpr int MI = BM / 32;
  __shared__ short8v Ab[BM * 8];
  __shared__ short8v Bb[512];

  int tid = threadIdx.x;
  int mtile = blockIdx.x, ntile = blockIdx.y;

  cfp Wsel = Wf;
  if (MODE == 1) Wsel = (blockIdx.z == 0) ? Wf : ((blockIdx.z == 1) ? p1 : p2);

  int wid = tid >> 6, lane = tid & 63;
  int m0w = (wid >> 1) * (BM / 2), n0w = (wid & 1) * 32;
  int lrow = lane & 15, lk = lane >> 4;

  f32x4 acc[MI][2];
#pragma unroll
  for (int mi = 0; mi < MI; ++mi)
#pragma unroll
    for (int ni = 0; ni < 2; ++ni) acc[mi][ni] = (f32x4){0.f, 0.f, 0.f, 0.f};

  for (int k0 = 0; k0 < KTOT; k0 += 64) {
    __syncthreads();
#pragma unroll
    for (int c = 0; c < BM / 32; ++c) {
      int chunk = tid + 256 * c;
      int row = chunk >> 3, kc = chunk & 7;
      int arow = mtile * BM + row;
      u32 off = ((u32)(row * 128 + kc * 16)) ^ ((u32)((row & 7) << 4));
      const u16* As = (const u16*)Ap + (size_t)arow * KTOT + k0 + kc * 8;
      Ab[off >> 4] = *(const short8v*)As;
    }
#pragma unroll
    for (int c = 0; c < 2; ++c) {
      int chunk = tid + 256 * c;
      int row = chunk >> 3, kc = chunk & 7;
      const float* Wp = Wsel + (size_t)(ntile * 64 + row) * KTOT + k0 + kc * 8;
      float4 xa = *(const float4*)Wp;
      float4 xb = *(const float4*)(Wp + 4);
      short8v sv;
      sv[0] = (short)f2b(xa.x); sv[1] = (short)f2b(xa.y);
      sv[2] = (short)f2b(xa.z); sv[3] = (short)f2b(xa.w);
      sv[4] = (short)f2b(xb.x); sv[5] = (short)f2b(xb.y);
      sv[6] = (short)f2b(xb.z); sv[7] = (short)f2b(xb.w);
      u32 off = ((u32)(row * 128 + kc * 16)) ^ ((u32)((row & 7) << 4));
      Bb[off >> 4] = sv;
    }
    __syncthreads();
#pragma unroll
    for (int ks = 0; ks < 2; ++ks) {
      short8v af[MI], bfr[2];
#pragma unroll
      for (int mi = 0; mi < MI; ++mi) {
        int row = m0w + mi * 16 + lrow;
        u32 off = ((u32)(row * 128 + ks * 64 + lk * 16)) ^ ((u32)((row & 7) << 4));
        af[mi] = Ab[off >> 4];
      }
#pragma unroll
      for (int ni = 0; ni < 2; ++ni) {
        int row = n0w + ni * 16 + lrow;
        u32 off = ((u32)(row * 128 + ks * 64 + lk * 16)) ^ ((u32)((row & 7) << 4));
        bfr[ni] = Bb[off >> 4];
      }
#pragma unroll
      for (int mi = 0; mi < MI; ++mi)
#pragma unroll
        for (int ni = 0; ni < 2; ++ni)
          acc[mi][ni] = __builtin_amdgcn_mfma_f32_16x16x32_bf16(af[mi], bfr[ni], acc[mi][ni], 0, 0, 0);
    }
  }

  const float qsc = 0.088388347648318447f * 1.4426950408889634f;
#pragma unroll
  for (int ni = 0; ni < 2; ++ni) {
    int n = ntile * 64 + n0w + ni * 16 + lrow;
    float c0 = 0.f;
    if (MODE == 2 || MODE == 3) c0 = p0[n];
#pragma unroll
    for (int mi = 0; mi < MI; ++mi) {
#pragma unroll
      for (int r = 0; r < 4; ++r) {
        int grow = mbase + mtile * BM + m0w + mi * 16 + lk * 4 + r;
        float val = acc[mi][ni][r];
        if (MODE == 1) {
          if (blockIdx.z == 0) val *= qsc;
          int s = grow & 1023, b_ = grow >> 10;
          u16* ob = (u16*)Out + (size_t)blockIdx.z * 2097152;
          ob[(((size_t)(b_ * kH + (n >> 4))) * kS + s) * kDH + (n & 15)] = f2b(val);
        } else if (MODE == 2) {
          ((u16*)Out)[(size_t)grow * kDFF + n] = f2b(fmaxf(val + c0, 0.f));
        } else {
          ((float*)Out)[(size_t)grow * kE + n] = val + c0 + res[(size_t)grow * kE + n];
        }
      }
    }
  }
}

// =====================================================================
// MFMA attention v5: 32x32x16 QK, exp2, cvt_pk, ones-MFMA denominator,
// aligned P stride 40 (16B reads/8B writes), XCD-friendly block remap.
// =====================================================================
__global__ __launch_bounds__(512, 4) void attn_kernel(
    const u16* __restrict__ qb, const u16* __restrict__ kb,
    const u16* __restrict__ vb, const u16* __restrict__ rbT,
    float* __restrict__ o) {
  __shared__ u16 Vsh[16 * 1032];   // V^T [d][j], stride 1032
  __shared__ u16 Pt[8][1280];      // per-wave P [32 q][40 k-stride]

  int tid = threadIdx.x;
  // remap: blocks sharing (bb,h) are == mod 8 -> same XCD -> K/V L2-resident
  int bid = blockIdx.x;
  int quarter = bid >> 7;
  int bb = (bid >> 3) & 15;
  int h = bid & 7;
  size_t base = (size_t)(bb * kH + h) * (kS * kDH);

  for (int j = tid; j < 1024; j += 512) {
    const uint4* src = (const uint4*)(vb + base + j * 16);
    uint4 a = src[0], b = src[1];
    u32 wv[8] = {a.x, a.y, a.z, a.w, b.x, b.y, b.z, b.w};
#pragma unroll
    for (int p = 0; p < 8; ++p) {
      Vsh[(2 * p) * 1032 + j]     = (u16)(wv[p] & 0xFFFFu);
      Vsh[(2 * p + 1) * 1032 + j] = (u16)(wv[p] >> 16);
    }
  }
  __syncthreads();

  int w = tid >> 6, l = tid & 63;
  int lr = l & 15, lg = l >> 4;      // PV-side coords
  int q32 = l & 31, hi = l >> 5;     // QK-side coords
  u16* P = Pt[w];
  int q0w = quarter * 256 + w * 32;
  int tbase = (q0w + 992) >> 4;
  const u16* rbh = rbT + (size_t)h * 126 * 512;

  short8v qf = *(const short8v*)(qb + base + (size_t)(q0w + q32) * 16 + hi * 8);
  short8v ones;
#pragma unroll
  for (int e = 0; e < 8; ++e) ones[e] = (short)0x3F80;

  f32x4 acc_e[2], acc_rb[2], acc_l[2];
#pragma unroll
  for (int qt = 0; qt < 2; ++qt) {
    acc_e[qt] = (f32x4){0.f, 0.f, 0.f, 0.f};
    acc_rb[qt] = (f32x4){0.f, 0.f, 0.f, 0.f};
    acc_l[qt] = (f32x4){0.f, 0.f, 0.f, 0.f};
  }
  const f32x16 z16 = {0.f,0.f,0.f,0.f,0.f,0.f,0.f,0.f,0.f,0.f,0.f,0.f,0.f,0.f,0.f,0.f};

  for (int jb = 0; jb < 32; ++jb) {
    short8v kf = *(const short8v*)(kb + base + (size_t)(jb * 32 + q32) * 16 + hi * 8);
    f32x16 s = __builtin_amdgcn_mfma_f32_32x32x16_bf16(kf, qf, z16, 0, 0, 0);
    float ev[16];
#pragma unroll
    for (int r = 0; r < 16; ++r) ev[r] = exp2f(s[r]);
#pragma unroll
    for (int rq = 0; rq < 4; ++rq) {
      u32 p0, p1;
      asm("v_cvt_pk_bf16_f32 %0, %1, %2" : "=v"(p0) : "v"(ev[4 * rq]), "v"(ev[4 * rq + 1]));
      asm("v_cvt_pk_bf16_f32 %0, %1, %2" : "=v"(p1) : "v"(ev[4 * rq + 2]), "v"(ev[4 * rq + 3]));
      *(uint2*)(P + q32 * 40 + rq * 8 + hi * 4) = make_uint2(p0, p1);
    }
    short8v vf = *(const short8v*)(Vsh + lr * 1032 + jb * 32 + lg * 8);
#pragma unroll
    for (int qt = 0; qt < 2; ++qt) {
      short8v pf = *(const short8v*)(P + (qt * 16 + lr) * 40 + lg * 8);
      int t = tbase + qt - 2 * jb;
      short8v rf = *(const short8v*)(rbh + ((size_t)t * 64 + l) * 8);
      acc_e[qt]  = __builtin_amdgcn_mfma_f32_16x16x32_bf16(pf, vf, acc_e[qt], 0, 0, 0);
      acc_l[qt]  = __builtin_amdgcn_mfma_f32_16x16x32_bf16(pf, ones, acc_l[qt], 0, 0, 0);
      acc_rb[qt] = __builtin_amdgcn_mfma_f32_16x16x32_bf16(rf, vf, acc_rb[qt], 0, 0, 0);
    }
  }

#pragma unroll
  for (int qt = 0; qt < 2; ++qt) {
#pragma unroll
    for (int r = 0; r < 4; ++r) {
      int qloc = qt * 16 + lg * 4 + r;
      int row = q0w + qloc;
      o[(size_t)(bb * kS + row) * kE + h * kDH + lr] =
          acc_e[qt][r] / acc_l[qt][r] + acc_rb[qt][r];
    }
  }
}

// ---------------- LN(attn out) + residual + LN1 -> att (f32 + bf16) ----------------
__global__ __launch_bounds__(256) void ln_kernel(
    cfp o, cfp xsrc, cfp lag, cfp lab, cfp l1g, cfp l1b,
    float* __restrict__ att, u16* __restrict__ attb) {
  int row = blockIdx.x * 4 + (threadIdx.x >> 6);
  int lane = threadIdx.x & 63;
  float2 a = ((const float2*)(o + (size_t)row * kE))[lane];
  float sum = a.x + a.y;
  for (int off = 1; off < 64; off <<= 1) sum += __shfl_xor(sum, off);
  float mean = sum * (1.f / 128.f);
  float d0 = a.x - mean, d1 = a.y - mean;
  float ss = d0 * d0 + d1 * d1;
  for (int off = 1; off < 64; off <<= 1) ss += __shfl_xor(ss, off);
  float inv = 1.f / sqrtf(ss * (1.f / 128.f) + kEps);
  float t0 = d0 * inv * lag[2 * lane] + lab[2 * lane];
  float t1 = d1 * inv * lag[2 * lane + 1] + lab[2 * lane + 1];
  float2 xv = ((const float2*)(xsrc + (size_t)row * kE))[lane];
  t0 += xv.x; t1 += xv.y;
  float sum2 = t0 + t1;
  for (int off = 1; off < 64; off <<= 1) sum2 += __shfl_xor(sum2, off);
  float mean2 = sum2 * (1.f / 128.f);
  float e0 = t0 - mean2, e1 = t1 - mean2;
  float ss2 = e0 * e0 + e1 * e1;
  for (int off = 1; off < 64; off <<= 1) ss2 += __shfl_xor(ss2, off);
  float inv2 = 1.f / sqrtf(ss2 * (1.f / 128.f) + kEps);
  float r0 = e0 * inv2 * l1g[2 * lane] + l1b[2 * lane];
  float r1 = e1 * inv2 * l1g[2 * lane + 1] + l1b[2 * lane + 1];
  ((float2*)(att + (size_t)row * kE))[lane] = make_float2(r0, r1);
  ((u32*)attb)[(size_t)row * 64 + lane] = (u32)f2b(r0) | ((u32)f2b(r1) << 16);
}

// ---------------- LN2 + GAP ----------------
__global__ __launch_bounds__(256) void ln2gap_kernel(
    cfp yff, cfp l2g, cfp l2b, float* __restrict__ outacc) {
  __shared__ float red[128];
  int tid = threadIdx.x;
  if (tid < 128) red[tid] = 0.f;
  __syncthreads();
  int row = blockIdx.x * 4 + (tid >> 6);
  int lane = tid & 63;
  float2 a = ((const float2*)(yff + (size_t)row * kE))[lane];
  float sum = a.x + a.y;
  for (int off = 1; off < 64; off <<= 1) sum += __shfl_xor(sum, off);
  float mean = sum * (1.f / 128.f);
  float d0 = a.x - mean, d1 = a.y - mean;
  float ss = d0 * d0 + d1 * d1;
  for (int off = 1; off < 64; off <<= 1) ss += __shfl_xor(ss, off);
  float inv = 1.f / sqrtf(ss * (1.f / 128.f) + kEps);
  float r0 = d0 * inv * l2g[2 * lane] + l2b[2 * lane];
  float r1 = d1 * inv * l2g[2 * lane + 1] + l2b[2 * lane + 1];
  atomicAdd(&red[2 * lane], r0);
  atomicAdd(&red[2 * lane + 1], r1);
  __syncthreads();
  int bb = (blockIdx.x * 4) >> 10;
  if (tid < 128) atomicAdd(&outacc[bb * kE + tid], red[tid]);
}

// ---------------- finalize ----------------
__global__ void fin_kernel(cfp outacc, const int* __restrict__ flag, void* __restrict__ out) {
  int i = blockIdx.x * 256 + threadIdx.x;
  float v = outacc[i] * (1.f / 1024.f);
  if (*flag) ((float*)out)[i] = v;
  else       ((bf16*)out)[i] = __float2bfloat16(v);
}

extern "C" void kernel_launch(void* const* d_in, const int* in_sizes, int n_in,
                              void* d_out, int out_size, void* d_ws, size_t ws_size,
                              hipStream_t stream) {
  CvtArgs args;
  int cum = 0;
  for (int i = 0; i < n_in && i < 27; ++i) {
    args.p[i] = d_in[i];
    args.cum[i] = cum;
    cum += in_sizes[i];
  }
  args.cum[n_in] = cum;
  int total = cum;
  int totalPad = (total + 15) & ~15;

  float* ws = (float*)d_ws;
  int* flag    = (int*)ws;
  float* wsinf = ws + 16;
  float* xsrc  = wsinf + totalPad;               // 2,097,152 f32
  float* att   = xsrc + 2097152;                 // 2,097,152 f32
  float* qkv0  = att + 2097152;                  // 3,145,728 (q,k,v bf16)
  float* ext   = qkv0 + 3145728;                 // 1,048,576 (rbT; ff1b tail)
  float* o     = ext + 1048576;                  // 2,097,152 (later yff)
  float* outacc = o + 2097152;                   // 2,048
  u16* xpeb    = (u16*)(outacc + 2048);          // 2,097,152 u16
  u16* w2b     = xpeb + 2097152;                 // 262,144 u16

  u16* Abuf = (u16*)att;
  u16* qb = (u16*)qkv0;
  u16* kb = qb + 2097152;
  u16* vb = kb + 2097152;
  u16* rbT = (u16*)ext;
  u16* ff1b = (u16*)qkv0;
  u16* attb = xpeb;
  float* yff = o;

  const float* wf[27];
  for (int i = 0; i < n_in && i < 27; ++i) wf[i] = wsinf + args.cum[i];

  hipMemsetAsync(flag, 0, sizeof(int), stream);
  hipMemsetAsync(outacc, 0, 2048 * sizeof(float), stream);
  detect_kernel<<<(in_sizes[0] + 255) / 256, 256, 0, stream>>>(
      (const u16*)d_in[0], in_sizes[0], flag);
  convert_kernel<<<(total + 255) / 256, 256, 0, stream>>>(args, flag, wsinf, total);
  wcvt_kernel<<<128, 256, 0, stream>>>(wf[7], w2b);

  for (int hm = 0; hm < 2; ++hm) {
    convstage_kernel<<<8192, 256, 0, stream>>>(
        wf[0], wf[1], wf[2], wf[3], wf[4], wf[5], wf[6], Abuf, hm * 8192);
    convgemm_kernel<<<256, 256, 0, stream>>>(
        Abuf, w2b, wf[8], wf[9], wf[10], wf[11], wf[12], xsrc, xpeb, hm * 8192);
  }

  rbtab_kernel<<<dim3(126, 8), 64, 0, stream>>>(wf[16], rbT);

  gemm_kernel<3, 1, 128, 64><<<dim3(256, 2, 3), 256, 0, stream>>>(
      xpeb, wf[13], nullptr, wf[14], wf[15], nullptr, nullptr, nullptr,
      nullptr, nullptr, nullptr, nullptr, nullptr, qb, nullptr, nullptr, 0);

  attn_kernel<<<512, 512, 0, stream>>>(qb, kb, vb, rbT, o);
  ln_kernel<<<4096, 256, 0, stream>>>(o, xsrc, wf[17], wf[18], wf[19], wf[20], att, attb);

  gemm_kernel<3, 2, 128, 64><<<dim3(256, 8), 256, 0, stream>>>(
      attb, wf[21], wf[22], nullptr, nullptr, nullptr, nullptr, nullptr,
      nullptr, nullptr, nullptr, nullptr, nullptr, ff1b, nullptr, nullptr, 0);
  gemm_kernel<3, 3, 512, 64><<<dim3(256, 2), 256, 0, stream>>>(
      ff1b, wf[23], wf[24], nullptr, nullptr, nullptr, nullptr, nullptr,
      nullptr, nullptr, nullptr, nullptr, nullptr, yff, nullptr, att, 0);

  ln2gap_kernel<<<4096, 256, 0, stream>>>(yff, wf[25], wf[26], outacc);
  fin_kernel<<<8, 256, 0, stream>>>(outacc, flag, d_out);
}

// Round 13
// 191.328 us; speedup vs baseline: 1.3953x; 1.1157x over previous
//
#include <hip/hip_runtime.h>
#include <hip/hip_bf16.h>
#include <math.h>

using bf16 = __hip_bfloat16;
typedef unsigned short u16;
typedef unsigned int u32;
typedef const float* __restrict__ cfp;

typedef __attribute__((ext_vector_type(8))) short short8v;
typedef __attribute__((ext_vector_type(4))) float f32x4;
typedef __attribute__((ext_vector_type(16))) float f32x16;

static constexpr int kS = 1024, kE = 128, kH = 8, kDH = 16, kDFF = 512;
static constexpr float kEps = 1e-5f;

__device__ __forceinline__ float geluf(float x) { return 0.5f * x * (1.f + erff(x * 0.70710678118654752f)); }
__device__ __forceinline__ u16 f2b(float f) {
  u32 u = __float_as_uint(f);
  u32 r = (u + 0x7FFFu + ((u >> 16) & 1u)) >> 16;
  return (u16)r;
}

template<int N> __device__ __forceinline__ void wait_vmcnt() {
  asm volatile("s_waitcnt vmcnt(%0)" :: "n"(N) : "memory");
  __builtin_amdgcn_sched_barrier(0);
}

// ---------------- prep: w2->bf16 chunk-permuted  +  rel-bias fragment table ----------------
// NOTE: rbT must NOT live under the Abuf overlay (round-12 bug) — it now sits
// in the workspace tail after w2b, untouched by every later kernel.
__global__ __launch_bounds__(256) void prep_kernel(
    cfp w2, u16* __restrict__ w2b, cfp relb, u16* __restrict__ T) {
  int bid = blockIdx.x;
  if (bid < 128) {
    int n = bid, ck = threadIdx.x;
    const float* src = w2 + (size_t)n * 2048 + (size_t)ck * 8;
    float4 a = *(const float4*)src;
    float4 b = *(const float4*)(src + 4);
    short8v sv;
    sv[0] = (short)f2b(a.x); sv[1] = (short)f2b(a.y);
    sv[2] = (short)f2b(a.z); sv[3] = (short)f2b(a.w);
    sv[4] = (short)f2b(b.x); sv[5] = (short)f2b(b.y);
    sv[6] = (short)f2b(b.z); sv[7] = (short)f2b(b.w);
    int cd = (ck & ~7) | ((ck & 7) ^ (n & 7));
    *(short8v*)(w2b + (size_t)n * 2048 + cd * 8) = sv;
  } else {
    int idx = (bid - 128) * 4 + (threadIdx.x >> 6);   // 0..1007 = h*126+t
    int l = threadIdx.x & 63;
    int h = idx / 126, t = idx - h * 126;
    int lr = l & 15, lg = l >> 4;
    short8v v;
#pragma unroll
    for (int e = 0; e < 8; ++e) {
      int ix = 16 * t + 31 + lr - 8 * lg - e;
      v[e] = (short)f2b(relb[ix * 8 + h]);
    }
    *(short8v*)(T + ((size_t)(h * 126 + t) * 64 + l) * 8) = v;
  }
}

// ---------------- conv1+bn1+gelu -> Abuf bf16 [8192][2048], chunk-permuted ----------------
__global__ __launch_bounds__(256) void convstage_kernel(
    cfp x, cfp w1, cfp c1b, cfp g1, cfp b1, cfp m1, cfp v1,
    u16* __restrict__ Abuf, int grow0) {
  __shared__ float xs[8][4];
  int row = blockIdx.x;
  int grow = grow0 + row;
  int b = grow >> 10, s = grow & 1023;
  int tid = threadIdx.x;
  if (tid < 8) {
    int gs = s - 3 + tid;
    float4 xv = (gs >= 0 && gs < kS) ? ((const float4*)x)[b * kS + gs]
                                     : make_float4(0.f, 0.f, 0.f, 0.f);
    xs[tid][0] = xv.x; xs[tid][1] = xv.y; xs[tid][2] = xv.z; xs[tid][3] = xv.w;
  }
  __syncthreads();
  short8v outv;
#pragma unroll
  for (int cc = 0; cc < 2; ++cc) {
    int cx = tid * 2 + cc;
    float w[8];
#pragma unroll
    for (int t = 0; t < 8; ++t) w[t] = w1[cx * 8 + t];
    float sc = g1[cx] * __frsqrt_rn(v1[cx] + kEps);
    float ofs = b1[cx] - m1[cx] * sc;
    float cb = c1b[cx];
#pragma unroll
    for (int r = 0; r < 4; ++r) {
      float h = cb;
#pragma unroll
      for (int t = 0; t < 8; ++t) h += xs[t][r] * w[t];
      outv[cc * 4 + r] = (short)f2b(geluf(h * sc + ofs));
    }
  }
  int ck = (tid & ~7) | ((tid & 7) ^ (row & 7));
  *(short8v*)(Abuf + (size_t)row * 2048 + ck * 8) = outv;
}

// =====================================================================
// Pipelined conv GEMM (unchanged — proven)
// =====================================================================
__global__ __launch_bounds__(256, 2) void convgemm_kernel(
    const u16* __restrict__ Abuf, const u16* __restrict__ w2b,
    cfp c2b, cfp g2, cfp b2, cfp m2, cfp v2,
    float* __restrict__ xsrc, u16* __restrict__ xpeb, int mbase) {
  __shared__ short8v lds[3840];
  const int tid = threadIdx.x;
  const int mtile = blockIdx.x;
  const int wid = tid >> 6, lane = tid & 63;
  const int lrow = lane & 15, lk = lane >> 4;
  const int m0w = (wid & 1) * 16, n0w = (wid >> 1) * 64;

  float scn[4], cc[4], dv[4];
#pragma unroll
  for (int ni = 0; ni < 4; ++ni) {
    int n = n0w + ni * 16 + lrow;
    scn[ni] = g2[n] * __frsqrt_rn(v2[n] + kEps);
    cc[ni] = (c2b[n] - m2[n]) * scn[ni] + b2[n];
    dv[ni] = __expf((float)(n >> 1) * (-0.14391156824963732f)) * 0.125f;
  }

  f32x4 acc[4];
#pragma unroll
  for (int ni = 0; ni < 4; ++ni) acc[ni] = (f32x4){0.f, 0.f, 0.f, 0.f};

  const int q = wid * 64 + lane;
  const u16* aG = Abuf + (size_t)(mtile * 32 + (q >> 3)) * 2048 + (q & 7) * 8;

  auto stage = [&](int t) {
    int buf = t % 3;
    short8v* A = lds + buf * 1280;
    __builtin_amdgcn_global_load_lds(
        (const __attribute__((address_space(1))) void*)(aG + t * 64),
        (__attribute__((address_space(3))) void*)(A + wid * 64), 16, 0, 0);
#pragma unroll
    for (int r = 0; r < 4; ++r) {
      int qq = r * 256 + q;
      const u16* g = w2b + (size_t)(qq >> 3) * 2048 + t * 64 + (qq & 7) * 8;
      __builtin_amdgcn_global_load_lds(
          (const __attribute__((address_space(1))) void*)g,
          (__attribute__((address_space(3))) void*)(A + 256 + r * 256 + wid * 64), 16, 0, 0);
    }
  };

  auto compute = [&](int t) {
    int buf = t % 3;
    const short8v* A = lds + buf * 1280;
    const short8v* B = A + 256;
#pragma unroll
    for (int ks = 0; ks < 2; ++ks) {
      int ar = m0w + lrow;
      u32 ao = ((u32)(ar * 128 + ks * 64 + lk * 16)) ^ ((u32)((ar & 7) << 4));
      short8v af = A[ao >> 4];
#pragma unroll
      for (int ni = 0; ni < 4; ++ni) {
        int br = n0w + ni * 16 + lrow;
        u32 bo = ((u32)(br * 128 + ks * 64 + lk * 16)) ^ ((u32)((br & 7) << 4));
        short8v bf = B[bo >> 4];
        acc[ni] = __builtin_amdgcn_mfma_f32_16x16x32_bf16(af, bf, acc[ni], 0, 0, 0);
      }
    }
  };

  stage(0); stage(1); stage(2);
  for (int t = 0; t < 30; ++t) {
    wait_vmcnt<10>();
    __builtin_amdgcn_s_barrier();
    __builtin_amdgcn_sched_barrier(0);
    compute(t);
    asm volatile("" ::: "memory");
    __builtin_amdgcn_s_barrier();
    __builtin_amdgcn_sched_barrier(0);
    if (t <= 28) stage(t + 3);
  }
  wait_vmcnt<5>();
  __builtin_amdgcn_s_barrier();
  __builtin_amdgcn_sched_barrier(0);
  compute(30);
  asm volatile("" ::: "memory");
  __builtin_amdgcn_s_barrier();
  __builtin_amdgcn_sched_barrier(0);
  wait_vmcnt<0>();
  __builtin_amdgcn_s_barrier();
  __builtin_amdgcn_sched_barrier(0);
  compute(31);

#pragma unroll
  for (int ni = 0; ni < 4; ++ni) {
    int n = n0w + ni * 16 + lrow;
#pragma unroll
    for (int r = 0; r < 4; ++r) {
      int grow = mbase + mtile * 32 + m0w + lk * 4 + r;
      float gv = geluf(acc[ni][r] * scn[ni] + cc[ni]);
      xsrc[(size_t)grow * kE + n] = gv;
      int s = grow & 1023;
      float ang = (float)s * dv[ni];
      float pe = (n & 1) ? __cosf(ang) : __sinf(ang);
      xpeb[(size_t)grow * kE + n] = f2b(gv + pe);
    }
  }
}

// =====================================================================
// bf16 MFMA GEMM (QKV / FF1 / FF2). MODE==1 z==0 (Q) pre-scaled by
// 128^-0.5 * log2(e) so attention can use exp2 directly.
// =====================================================================
template<int ASRC, int MODE, int KTOT, int BM>
__global__ __launch_bounds__(256, 4) void gemm_kernel(
    const void* __restrict__ Ap, cfp Wf,
    cfp p0, cfp p1, cfp p2,
    void* __restrict__ Out, cfp res, int mbase) {
  constexpr int MI = BM / 32;
  __shared__ short8v Ab[BM * 8];
  __shared__ short8v Bb[512];

  int tid = threadIdx.x;
  int mtile = blockIdx.x, ntile = blockIdx.y;

  cfp Wsel = Wf;
  if (MODE == 1) Wsel = (blockIdx.z == 0) ? Wf : ((blockIdx.z == 1) ? p1 : p2);

  int wid = tid >> 6, lane = tid & 63;
  int m0w = (wid >> 1) * (BM / 2), n0w = (wid & 1) * 32;
  int lrow = lane & 15, lk = lane >> 4;

  f32x4 acc[MI][2];
#pragma unroll
  for (int mi = 0; mi < MI; ++mi)
#pragma unroll
    for (int ni = 0; ni < 2; ++ni) acc[mi][ni] = (f32x4){0.f, 0.f, 0.f, 0.f};

  for (int k0 = 0; k0 < KTOT; k0 += 64) {
    __syncthreads();
#pragma unroll
    for (int c = 0; c < BM / 32; ++c) {
      int chunk = tid + 256 * c;
      int row = chunk >> 3, kc = chunk & 7;
      int arow = mtile * BM + row;
      u32 off = ((u32)(row * 128 + kc * 16)) ^ ((u32)((row & 7) << 4));
      const u16* As = (const u16*)Ap + (size_t)arow * KTOT + k0 + kc * 8;
      Ab[off >> 4] = *(const short8v*)As;
    }
#pragma unroll
    for (int c = 0; c < 2; ++c) {
      int chunk = tid + 256 * c;
      int row = chunk >> 3, kc = chunk & 7;
      const float* Wp = Wsel + (size_t)(ntile * 64 + row) * KTOT + k0 + kc * 8;
      float4 xa = *(const float4*)Wp;
      float4 xb = *(const float4*)(Wp + 4);
      short8v sv;
      sv[0] = (short)f2b(xa.x); sv[1] = (short)f2b(xa.y);
      sv[2] = (short)f2b(xa.z); sv[3] = (short)f2b(xa.w);
      sv[4] = (short)f2b(xb.x); sv[5] = (short)f2b(xb.y);
      sv[6] = (short)f2b(xb.z); sv[7] = (short)f2b(xb.w);
      u32 off = ((u32)(row * 128 + kc * 16)) ^ ((u32)((row & 7) << 4));
      Bb[off >> 4] = sv;
    }
    __syncthreads();
#pragma unroll
    for (int ks = 0; ks < 2; ++ks) {
      short8v af[MI], bfr[2];
#pragma unroll
      for (int mi = 0; mi < MI; ++mi) {
        int row = m0w + mi * 16 + lrow;
        u32 off = ((u32)(row * 128 + ks * 64 + lk * 16)) ^ ((u32)((row & 7) << 4));
        af[mi] = Ab[off >> 4];
      }
#pragma unroll
      for (int ni = 0; ni < 2; ++ni) {
        int row = n0w + ni * 16 + lrow;
        u32 off = ((u32)(row * 128 + ks * 64 + lk * 16)) ^ ((u32)((row & 7) << 4));
        bfr[ni] = Bb[off >> 4];
      }
#pragma unroll
      for (int mi = 0; mi < MI; ++mi)
#pragma unroll
        for (int ni = 0; ni < 2; ++ni)
          acc[mi][ni] = __builtin_amdgcn_mfma_f32_16x16x32_bf16(af[mi], bfr[ni], acc[mi][ni], 0, 0, 0);
    }
  }

  const float qsc = 0.088388347648318447f * 1.4426950408889634f;
#pragma unroll
  for (int ni = 0; ni < 2; ++ni) {
    int n = ntile * 64 + n0w + ni * 16 + lrow;
    float c0 = 0.f;
    if (MODE == 2 || MODE == 3) c0 = p0[n];
#pragma unroll
    for (int mi = 0; mi < MI; ++mi) {
#pragma unroll
      for (int r = 0; r < 4; ++r) {
        int grow = mbase + mtile * BM + m0w + mi * 16 + lk * 4 + r;
        float val = acc[mi][ni][r];
        if (MODE == 1) {
          if (blockIdx.z == 0) val *= qsc;
          int s = grow & 1023, b_ = grow >> 10;
          u16* ob = (u16*)Out + (size_t)blockIdx.z * 2097152;
          ob[(((size_t)(b_ * kH + (n >> 4))) * kS + s) * kDH + (n & 15)] = f2b(val);
        } else if (MODE == 2) {
          ((u16*)Out)[(size_t)grow * kDFF + n] = f2b(fmaxf(val + c0, 0.f));
        } else {
          ((float*)Out)[(size_t)grow * kE + n] = val + c0 + res[(size_t)grow * kE + n];
        }
      }
    }
  }
}

// =====================================================================
// MFMA attention v5 (unchanged — proven): 32x32x16 QK, exp2, cvt_pk,
// ones-MFMA denominator, aligned P stride 40, XCD-friendly remap.
// =====================================================================
__global__ __launch_bounds__(512, 4) void attn_kernel(
    const u16* __restrict__ qb, const u16* __restrict__ kb,
    const u16* __restrict__ vb, const u16* __restrict__ rbT,
    float* __restrict__ o) {
  __shared__ u16 Vsh[16 * 1032];
  __shared__ u16 Pt[8][1280];

  int tid = threadIdx.x;
  int bid = blockIdx.x;
  int quarter = bid >> 7;
  int bb = (bid >> 3) & 15;
  int h = bid & 7;
  size_t base = (size_t)(bb * kH + h) * (kS * kDH);

  for (int j = tid; j < 1024; j += 512) {
    const uint4* src = (const uint4*)(vb + base + j * 16);
    uint4 a = src[0], b = src[1];
    u32 wv[8] = {a.x, a.y, a.z, a.w, b.x, b.y, b.z, b.w};
#pragma unroll
    for (int p = 0; p < 8; ++p) {
      Vsh[(2 * p) * 1032 + j]     = (u16)(wv[p] & 0xFFFFu);
      Vsh[(2 * p + 1) * 1032 + j] = (u16)(wv[p] >> 16);
    }
  }
  __syncthreads();

  int w = tid >> 6, l = tid & 63;
  int lr = l & 15, lg = l >> 4;
  int q32 = l & 31, hi = l >> 5;
  u16* P = Pt[w];
  int q0w = quarter * 256 + w * 32;
  int tbase = (q0w + 992) >> 4;
  const u16* rbh = rbT + (size_t)h * 126 * 512;

  short8v qf = *(const short8v*)(qb + base + (size_t)(q0w + q32) * 16 + hi * 8);
  short8v ones;
#pragma unroll
  for (int e = 0; e < 8; ++e) ones[e] = (short)0x3F80;

  f32x4 acc_e[2], acc_rb[2], acc_l[2];
#pragma unroll
  for (int qt = 0; qt < 2; ++qt) {
    acc_e[qt] = (f32x4){0.f, 0.f, 0.f, 0.f};
    acc_rb[qt] = (f32x4){0.f, 0.f, 0.f, 0.f};
    acc_l[qt] = (f32x4){0.f, 0.f, 0.f, 0.f};
  }
  const f32x16 z16 = {0.f,0.f,0.f,0.f,0.f,0.f,0.f,0.f,0.f,0.f,0.f,0.f,0.f,0.f,0.f,0.f};

  for (int jb = 0; jb < 32; ++jb) {
    short8v kf = *(const short8v*)(kb + base + (size_t)(jb * 32 + q32) * 16 + hi * 8);
    f32x16 s = __builtin_amdgcn_mfma_f32_32x32x16_bf16(kf, qf, z16, 0, 0, 0);
    float ev[16];
#pragma unroll
    for (int r = 0; r < 16; ++r) ev[r] = exp2f(s[r]);
#pragma unroll
    for (int rq = 0; rq < 4; ++rq) {
      u32 p0, p1;
      asm("v_cvt_pk_bf16_f32 %0, %1, %2" : "=v"(p0) : "v"(ev[4 * rq]), "v"(ev[4 * rq + 1]));
      asm("v_cvt_pk_bf16_f32 %0, %1, %2" : "=v"(p1) : "v"(ev[4 * rq + 2]), "v"(ev[4 * rq + 3]));
      *(uint2*)(P + q32 * 40 + rq * 8 + hi * 4) = make_uint2(p0, p1);
    }
    short8v vf = *(const short8v*)(Vsh + lr * 1032 + jb * 32 + lg * 8);
#pragma unroll
    for (int qt = 0; qt < 2; ++qt) {
      short8v pf = *(const short8v*)(P + (qt * 16 + lr) * 40 + lg * 8);
      int t = tbase + qt - 2 * jb;
      short8v rf = *(const short8v*)(rbh + ((size_t)t * 64 + l) * 8);
      acc_e[qt]  = __builtin_amdgcn_mfma_f32_16x16x32_bf16(pf, vf, acc_e[qt], 0, 0, 0);
      acc_l[qt]  = __builtin_amdgcn_mfma_f32_16x16x32_bf16(pf, ones, acc_l[qt], 0, 0, 0);
      acc_rb[qt] = __builtin_amdgcn_mfma_f32_16x16x32_bf16(rf, vf, acc_rb[qt], 0, 0, 0);
    }
  }

#pragma unroll
  for (int qt = 0; qt < 2; ++qt) {
#pragma unroll
    for (int r = 0; r < 4; ++r) {
      int qloc = qt * 16 + lg * 4 + r;
      int row = q0w + qloc;
      o[(size_t)(bb * kS + row) * kE + h * kDH + lr] =
          acc_e[qt][r] / acc_l[qt][r] + acc_rb[qt][r];
    }
  }
}

// ---------------- LN(attn out) + residual + LN1 -> att (f32 + bf16) ----------------
__global__ __launch_bounds__(256) void ln_kernel(
    cfp o, cfp xsrc, cfp lag, cfp lab, cfp l1g, cfp l1b,
    float* __restrict__ att, u16* __restrict__ attb) {
  int row = blockIdx.x * 4 + (threadIdx.x >> 6);
  int lane = threadIdx.x & 63;
  float2 a = ((const float2*)(o + (size_t)row * kE))[lane];
  float sum = a.x + a.y;
  for (int off = 1; off < 64; off <<= 1) sum += __shfl_xor(sum, off);
  float mean = sum * (1.f / 128.f);
  float d0 = a.x - mean, d1 = a.y - mean;
  float ss = d0 * d0 + d1 * d1;
  for (int off = 1; off < 64; off <<= 1) ss += __shfl_xor(ss, off);
  float inv = 1.f / sqrtf(ss * (1.f / 128.f) + kEps);
  float t0 = d0 * inv * lag[2 * lane] + lab[2 * lane];
  float t1 = d1 * inv * lag[2 * lane + 1] + lab[2 * lane + 1];
  float2 xv = ((const float2*)(xsrc + (size_t)row * kE))[lane];
  t0 += xv.x; t1 += xv.y;
  float sum2 = t0 + t1;
  for (int off = 1; off < 64; off <<= 1) sum2 += __shfl_xor(sum2, off);
  float mean2 = sum2 * (1.f / 128.f);
  float e0 = t0 - mean2, e1 = t1 - mean2;
  float ss2 = e0 * e0 + e1 * e1;
  for (int off = 1; off < 64; off <<= 1) ss2 += __shfl_xor(ss2, off);
  float inv2 = 1.f / sqrtf(ss2 * (1.f / 128.f) + kEps);
  float r0 = e0 * inv2 * l1g[2 * lane] + l1b[2 * lane];
  float r1 = e1 * inv2 * l1g[2 * lane + 1] + l1b[2 * lane + 1];
  ((float2*)(att + (size_t)row * kE))[lane] = make_float2(r0, r1);
  ((u32*)attb)[(size_t)row * 64 + lane] = (u32)f2b(r0) | ((u32)f2b(r1) << 16);
}

// ---------------- LN2 + GAP (scaled, straight into d_out) ----------------
__global__ __launch_bounds__(256) void ln2gap_kernel(
    cfp yff, cfp l2g, cfp l2b, float* __restrict__ dout) {
  __shared__ float red[128];
  int tid = threadIdx.x;
  if (tid < 128) red[tid] = 0.f;
  __syncthreads();
  int row = blockIdx.x * 4 + (tid >> 6);
  int lane = tid & 63;
  float2 a = ((const float2*)(yff + (size_t)row * kE))[lane];
  float sum = a.x + a.y;
  for (int off = 1; off < 64; off <<= 1) sum += __shfl_xor(sum, off);
  float mean = sum * (1.f / 128.f);
  float d0 = a.x - mean, d1 = a.y - mean;
  float ss = d0 * d0 + d1 * d1;
  for (int off = 1; off < 64; off <<= 1) ss += __shfl_xor(ss, off);
  float inv = 1.f / sqrtf(ss * (1.f / 128.f) + kEps);
  float r0 = d0 * inv * l2g[2 * lane] + l2b[2 * lane];
  float r1 = d1 * inv * l2g[2 * lane + 1] + l2b[2 * lane + 1];
  atomicAdd(&red[2 * lane], r0);
  atomicAdd(&red[2 * lane + 1], r1);
  __syncthreads();
  int bb = (blockIdx.x * 4) >> 10;
  if (tid < 128) atomicAdd(&dout[bb * kE + tid], red[tid] * (1.f / 1024.f));
}

extern "C" void kernel_launch(void* const* d_in, const int* in_sizes, int n_in,
                              void* d_out, int out_size, void* d_ws, size_t ws_size,
                              hipStream_t stream) {
  const float* wf[27];
  for (int i = 0; i < n_in && i < 27; ++i) wf[i] = (const float*)d_in[i];

  float* ws = (float*)d_ws;
  float* xsrc  = ws;                             // 2,097,152 f32
  float* att   = xsrc + 2097152;                 // 2,097,152 f32
  float* qkv0  = att + 2097152;                  // 3,145,728 (q,k,v bf16)
  float* ext   = qkv0 + 3145728;                 // 1,048,576 (ff1b tail only)
  float* o     = ext + 1048576;                  // 2,097,152 (later yff)
  u16* xpeb    = (u16*)(o + 2097152);            // 2,097,152 u16
  u16* w2b     = xpeb + 2097152;                 // 262,144 u16
  u16* rbT     = w2b + 262144;                   // 516,096 u16 — NOT under Abuf overlay

  u16* Abuf = (u16*)att;                         // overlays att..o (8,388,608 f32) exactly
  u16* qb = (u16*)qkv0;
  u16* kb = qb + 2097152;
  u16* vb = kb + 2097152;
  u16* ff1b = (u16*)qkv0;                        // spans qkv0+ext
  u16* attb = xpeb;
  float* yff = o;
  float* doutf = (float*)d_out;

  (void)hipMemsetAsync(d_out, 0, (size_t)out_size * sizeof(float), stream);

  prep_kernel<<<380, 256, 0, stream>>>(wf[7], w2b, wf[16], rbT);

  for (int hm = 0; hm < 2; ++hm) {
    convstage_kernel<<<8192, 256, 0, stream>>>(
        wf[0], wf[1], wf[2], wf[3], wf[4], wf[5], wf[6], Abuf, hm * 8192);
    convgemm_kernel<<<256, 256, 0, stream>>>(
        Abuf, w2b, wf[8], wf[9], wf[10], wf[11], wf[12], xsrc, xpeb, hm * 8192);
  }

  gemm_kernel<3, 1, 128, 64><<<dim3(256, 2, 3), 256, 0, stream>>>(
      xpeb, wf[13], nullptr, wf[14], wf[15], qb, nullptr, 0);

  attn_kernel<<<512, 512, 0, stream>>>(qb, kb, vb, rbT, o);
  ln_kernel<<<4096, 256, 0, stream>>>(o, xsrc, wf[17], wf[18], wf[19], wf[20], att, attb);

  gemm_kernel<3, 2, 128, 64><<<dim3(256, 8), 256, 0, stream>>>(
      attb, wf[21], wf[22], nullptr, nullptr, ff1b, nullptr, 0);
  gemm_kernel<3, 3, 512, 64><<<dim3(256, 2), 256, 0, stream>>>(
      ff1b, wf[23], wf[24], nullptr, nullptr, yff, att, 0);

  ln2gap_kernel<<<4096, 256, 0, stream>>>(yff, wf[25], wf[26], doutf);
}

// Round 14
// 162.062 us; speedup vs baseline: 1.6473x; 1.1806x over previous
//
#include <hip/hip_runtime.h>
#include <hip/hip_bf16.h>
#include <math.h>

using bf16 = __hip_bfloat16;
typedef unsigned short u16;
typedef unsigned int u32;
typedef const float* __restrict__ cfp;

typedef __attribute__((ext_vector_type(8))) short short8v;
typedef __attribute__((ext_vector_type(4))) float f32x4;
typedef __attribute__((ext_vector_type(16))) float f32x16;

static constexpr int kS = 1024, kE = 128, kH = 8, kDH = 16, kDFF = 512;
static constexpr float kEps = 1e-5f;

__device__ __forceinline__ float geluf(float x) { return 0.5f * x * (1.f + erff(x * 0.70710678118654752f)); }
__device__ __forceinline__ u16 f2b(float f) {
  u32 u = __float_as_uint(f);
  u32 r = (u + 0x7FFFu + ((u >> 16) & 1u)) >> 16;
  return (u16)r;
}

template<int N> __device__ __forceinline__ void wait_vmcnt() {
  asm volatile("s_waitcnt vmcnt(%0)" :: "n"(N) : "memory");
  __builtin_amdgcn_sched_barrier(0);
}

// ---------------- prep: w2conv->bf16 perm + rbT table + ffw2->bf16 perm ----------------
__global__ __launch_bounds__(256) void prep_kernel(
    cfp w2, u16* __restrict__ w2b, cfp relb, u16* __restrict__ T,
    cfp fw2, u16* __restrict__ w2fb) {
  int bid = blockIdx.x;
  if (bid < 128) {
    int n = bid, ck = threadIdx.x;
    const float* src = w2 + (size_t)n * 2048 + (size_t)ck * 8;
    float4 a = *(const float4*)src;
    float4 b = *(const float4*)(src + 4);
    short8v sv;
    sv[0] = (short)f2b(a.x); sv[1] = (short)f2b(a.y);
    sv[2] = (short)f2b(a.z); sv[3] = (short)f2b(a.w);
    sv[4] = (short)f2b(b.x); sv[5] = (short)f2b(b.y);
    sv[6] = (short)f2b(b.z); sv[7] = (short)f2b(b.w);
    int cd = (ck & ~7) | ((ck & 7) ^ (n & 7));
    *(short8v*)(w2b + (size_t)n * 2048 + cd * 8) = sv;
  } else if (bid < 380) {
    int idx = (bid - 128) * 4 + (threadIdx.x >> 6);   // 0..1007 = h*126+t
    int l = threadIdx.x & 63;
    int h = idx / 126, t = idx - h * 126;
    int lr = l & 15, lg = l >> 4;
    short8v v;
#pragma unroll
    for (int e = 0; e < 8; ++e) {
      int ix = 16 * t + 31 + lr - 8 * lg - e;
      v[e] = (short)f2b(relb[ix * 8 + h]);
    }
    *(short8v*)(T + ((size_t)(h * 126 + t) * 64 + l) * 8) = v;
  } else {
    int n = (bid - 380) * 4 + (threadIdx.x >> 6);     // 0..127
    int ck = threadIdx.x & 63;                        // 64 chunks of 8 u16
    const float* src = fw2 + (size_t)n * 512 + (size_t)ck * 8;
    float4 a = *(const float4*)src;
    float4 b = *(const float4*)(src + 4);
    short8v sv;
    sv[0] = (short)f2b(a.x); sv[1] = (short)f2b(a.y);
    sv[2] = (short)f2b(a.z); sv[3] = (short)f2b(a.w);
    sv[4] = (short)f2b(b.x); sv[5] = (short)f2b(b.y);
    sv[6] = (short)f2b(b.z); sv[7] = (short)f2b(b.w);
    int cd = (ck & ~7) | ((ck & 7) ^ (n & 7));
    *(short8v*)(w2fb + (size_t)n * 512 + cd * 8) = sv;
  }
}

// ---------------- conv1+bn1+gelu -> Abuf bf16 [8192][2048], chunk-permuted ----------------
__global__ __launch_bounds__(256) void convstage_kernel(
    cfp x, cfp w1, cfp c1b, cfp g1, cfp b1, cfp m1, cfp v1,
    u16* __restrict__ Abuf, int grow0) {
  __shared__ float xs[8][4];
  int row = blockIdx.x;
  int grow = grow0 + row;
  int b = grow >> 10, s = grow & 1023;
  int tid = threadIdx.x;
  if (tid < 8) {
    int gs = s - 3 + tid;
    float4 xv = (gs >= 0 && gs < kS) ? ((const float4*)x)[b * kS + gs]
                                     : make_float4(0.f, 0.f, 0.f, 0.f);
    xs[tid][0] = xv.x; xs[tid][1] = xv.y; xs[tid][2] = xv.z; xs[tid][3] = xv.w;
  }
  __syncthreads();
  short8v outv;
#pragma unroll
  for (int cc = 0; cc < 2; ++cc) {
    int cx = tid * 2 + cc;
    float w[8];
#pragma unroll
    for (int t = 0; t < 8; ++t) w[t] = w1[cx * 8 + t];
    float sc = g1[cx] * __frsqrt_rn(v1[cx] + kEps);
    float ofs = b1[cx] - m1[cx] * sc;
    float cb = c1b[cx];
#pragma unroll
    for (int r = 0; r < 4; ++r) {
      float h = cb;
#pragma unroll
      for (int t = 0; t < 8; ++t) h += xs[t][r] * w[t];
      outv[cc * 4 + r] = (short)f2b(geluf(h * sc + ofs));
    }
  }
  int ck = (tid & ~7) | ((tid & 7) ^ (row & 7));
  *(short8v*)(Abuf + (size_t)row * 2048 + ck * 8) = outv;
}

// =====================================================================
// Pipelined conv GEMM (unchanged — proven)
// =====================================================================
__global__ __launch_bounds__(256, 2) void convgemm_kernel(
    const u16* __restrict__ Abuf, const u16* __restrict__ w2b,
    cfp c2b, cfp g2, cfp b2, cfp m2, cfp v2,
    float* __restrict__ xsrc, u16* __restrict__ xpeb, int mbase) {
  __shared__ short8v lds[3840];
  const int tid = threadIdx.x;
  const int mtile = blockIdx.x;
  const int wid = tid >> 6, lane = tid & 63;
  const int lrow = lane & 15, lk = lane >> 4;
  const int m0w = (wid & 1) * 16, n0w = (wid >> 1) * 64;

  float scn[4], cc[4], dv[4];
#pragma unroll
  for (int ni = 0; ni < 4; ++ni) {
    int n = n0w + ni * 16 + lrow;
    scn[ni] = g2[n] * __frsqrt_rn(v2[n] + kEps);
    cc[ni] = (c2b[n] - m2[n]) * scn[ni] + b2[n];
    dv[ni] = __expf((float)(n >> 1) * (-0.14391156824963732f)) * 0.125f;
  }

  f32x4 acc[4];
#pragma unroll
  for (int ni = 0; ni < 4; ++ni) acc[ni] = (f32x4){0.f, 0.f, 0.f, 0.f};

  const int q = wid * 64 + lane;
  const u16* aG = Abuf + (size_t)(mtile * 32 + (q >> 3)) * 2048 + (q & 7) * 8;

  auto stage = [&](int t) {
    int buf = t % 3;
    short8v* A = lds + buf * 1280;
    __builtin_amdgcn_global_load_lds(
        (const __attribute__((address_space(1))) void*)(aG + t * 64),
        (__attribute__((address_space(3))) void*)(A + wid * 64), 16, 0, 0);
#pragma unroll
    for (int r = 0; r < 4; ++r) {
      int qq = r * 256 + q;
      const u16* g = w2b + (size_t)(qq >> 3) * 2048 + t * 64 + (qq & 7) * 8;
      __builtin_amdgcn_global_load_lds(
          (const __attribute__((address_space(1))) void*)g,
          (__attribute__((address_space(3))) void*)(A + 256 + r * 256 + wid * 64), 16, 0, 0);
    }
  };

  auto compute = [&](int t) {
    int buf = t % 3;
    const short8v* A = lds + buf * 1280;
    const short8v* B = A + 256;
#pragma unroll
    for (int ks = 0; ks < 2; ++ks) {
      int ar = m0w + lrow;
      u32 ao = ((u32)(ar * 128 + ks * 64 + lk * 16)) ^ ((u32)((ar & 7) << 4));
      short8v af = A[ao >> 4];
#pragma unroll
      for (int ni = 0; ni < 4; ++ni) {
        int br = n0w + ni * 16 + lrow;
        u32 bo = ((u32)(br * 128 + ks * 64 + lk * 16)) ^ ((u32)((br & 7) << 4));
        short8v bf = B[bo >> 4];
        acc[ni] = __builtin_amdgcn_mfma_f32_16x16x32_bf16(af, bf, acc[ni], 0, 0, 0);
      }
    }
  };

  stage(0); stage(1); stage(2);
  for (int t = 0; t < 30; ++t) {
    wait_vmcnt<10>();
    __builtin_amdgcn_s_barrier();
    __builtin_amdgcn_sched_barrier(0);
    compute(t);
    asm volatile("" ::: "memory");
    __builtin_amdgcn_s_barrier();
    __builtin_amdgcn_sched_barrier(0);
    if (t <= 28) stage(t + 3);
  }
  wait_vmcnt<5>();
  __builtin_amdgcn_s_barrier();
  __builtin_amdgcn_sched_barrier(0);
  compute(30);
  asm volatile("" ::: "memory");
  __builtin_amdgcn_s_barrier();
  __builtin_amdgcn_sched_barrier(0);
  wait_vmcnt<0>();
  __builtin_amdgcn_s_barrier();
  __builtin_amdgcn_sched_barrier(0);
  compute(31);

#pragma unroll
  for (int ni = 0; ni < 4; ++ni) {
    int n = n0w + ni * 16 + lrow;
#pragma unroll
    for (int r = 0; r < 4; ++r) {
      int grow = mbase + mtile * 32 + m0w + lk * 4 + r;
      float gv = geluf(acc[ni][r] * scn[ni] + cc[ni]);
      xsrc[(size_t)grow * kE + n] = gv;
      int s = grow & 1023;
      float ang = (float)s * dv[ni];
      float pe = (n & 1) ? __cosf(ang) : __sinf(ang);
      xpeb[(size_t)grow * kE + n] = f2b(gv + pe);
    }
  }
}

// =====================================================================
// bf16 MFMA GEMM (QKV / FF1). MODE==1 z==0 (Q) pre-scaled by
// 128^-0.5*log2(e). MODE==2 writes ff1b chunk-permuted for ff2ln.
// =====================================================================
template<int ASRC, int MODE, int KTOT, int BM>
__global__ __launch_bounds__(256, 4) void gemm_kernel(
    const void* __restrict__ Ap, cfp Wf,
    cfp p0, cfp p1, cfp p2,
    void* __restrict__ Out, cfp res, int mbase) {
  constexpr int MI = BM / 32;
  __shared__ short8v Ab[BM * 8];
  __shared__ short8v Bb[512];

  int tid = threadIdx.x;
  int mtile = blockIdx.x, ntile = blockIdx.y;

  cfp Wsel = Wf;
  if (MODE == 1) Wsel = (blockIdx.z == 0) ? Wf : ((blockIdx.z == 1) ? p1 : p2);

  int wid = tid >> 6, lane = tid & 63;
  int m0w = (wid >> 1) * (BM / 2), n0w = (wid & 1) * 32;
  int lrow = lane & 15, lk = lane >> 4;

  f32x4 acc[MI][2];
#pragma unroll
  for (int mi = 0; mi < MI; ++mi)
#pragma unroll
    for (int ni = 0; ni < 2; ++ni) acc[mi][ni] = (f32x4){0.f, 0.f, 0.f, 0.f};

  for (int k0 = 0; k0 < KTOT; k0 += 64) {
    __syncthreads();
#pragma unroll
    for (int c = 0; c < BM / 32; ++c) {
      int chunk = tid + 256 * c;
      int row = chunk >> 3, kc = chunk & 7;
      int arow = mtile * BM + row;
      u32 off = ((u32)(row * 128 + kc * 16)) ^ ((u32)((row & 7) << 4));
      const u16* As = (const u16*)Ap + (size_t)arow * KTOT + k0 + kc * 8;
      Ab[off >> 4] = *(const short8v*)As;
    }
#pragma unroll
    for (int c = 0; c < 2; ++c) {
      int chunk = tid + 256 * c;
      int row = chunk >> 3, kc = chunk & 7;
      const float* Wp = Wsel + (size_t)(ntile * 64 + row) * KTOT + k0 + kc * 8;
      float4 xa = *(const float4*)Wp;
      float4 xb = *(const float4*)(Wp + 4);
      short8v sv;
      sv[0] = (short)f2b(xa.x); sv[1] = (short)f2b(xa.y);
      sv[2] = (short)f2b(xa.z); sv[3] = (short)f2b(xa.w);
      sv[4] = (short)f2b(xb.x); sv[5] = (short)f2b(xb.y);
      sv[6] = (short)f2b(xb.z); sv[7] = (short)f2b(xb.w);
      u32 off = ((u32)(row * 128 + kc * 16)) ^ ((u32)((row & 7) << 4));
      Bb[off >> 4] = sv;
    }
    __syncthreads();
#pragma unroll
    for (int ks = 0; ks < 2; ++ks) {
      short8v af[MI], bfr[2];
#pragma unroll
      for (int mi = 0; mi < MI; ++mi) {
        int row = m0w + mi * 16 + lrow;
        u32 off = ((u32)(row * 128 + ks * 64 + lk * 16)) ^ ((u32)((row & 7) << 4));
        af[mi] = Ab[off >> 4];
      }
#pragma unroll
      for (int ni = 0; ni < 2; ++ni) {
        int row = n0w + ni * 16 + lrow;
        u32 off = ((u32)(row * 128 + ks * 64 + lk * 16)) ^ ((u32)((row & 7) << 4));
        bfr[ni] = Bb[off >> 4];
      }
#pragma unroll
      for (int mi = 0; mi < MI; ++mi)
#pragma unroll
        for (int ni = 0; ni < 2; ++ni)
          acc[mi][ni] = __builtin_amdgcn_mfma_f32_16x16x32_bf16(af[mi], bfr[ni], acc[mi][ni], 0, 0, 0);
    }
  }

  const float qsc = 0.088388347648318447f * 1.4426950408889634f;
#pragma unroll
  for (int ni = 0; ni < 2; ++ni) {
    int n = ntile * 64 + n0w + ni * 16 + lrow;
    float c0 = 0.f;
    if (MODE == 2) c0 = p0[n];
#pragma unroll
    for (int mi = 0; mi < MI; ++mi) {
#pragma unroll
      for (int r = 0; r < 4; ++r) {
        int grow = mbase + mtile * BM + m0w + mi * 16 + lk * 4 + r;
        float val = acc[mi][ni][r];
        if (MODE == 1) {
          if (blockIdx.z == 0) val *= qsc;
          int s = grow & 1023, b_ = grow >> 10;
          u16* ob = (u16*)Out + (size_t)blockIdx.z * 2097152;
          ob[(((size_t)(b_ * kH + (n >> 4))) * kS + s) * kDH + (n & 15)] = f2b(val);
        } else if (MODE == 2) {
          // chunk-permuted write: chunk-in-step (n>>3)&7 XOR'd with row&7
          int np = (n & ~56) | ((((n >> 3) ^ grow) & 7) << 3);
          ((u16*)Out)[(size_t)grow * kDFF + np] = f2b(fmaxf(val + c0, 0.f));
        }
      }
    }
  }
}

// =====================================================================
// FF2 pipelined (convgemm template, KTOT=512) + fused bias/residual/
// LN2/GAP epilogue -> atomicAdd into d_out. Eliminates yff + ln2gap.
// =====================================================================
__global__ __launch_bounds__(256, 2) void ff2ln_kernel(
    const u16* __restrict__ Abuf, const u16* __restrict__ w2fb,
    cfp fb2, cfp l2g, cfp l2b, cfp res, float* __restrict__ dout) {
  __shared__ short8v lds[3840];
  __shared__ float st1[2][32], st2[2][32];
  __shared__ float red[128];
  const int tid = threadIdx.x;
  const int mtile = blockIdx.x;
  const int wid = tid >> 6, lane = tid & 63;
  const int lrow = lane & 15, lk = lane >> 4;
  const int m0w = (wid & 1) * 16, n0w = (wid >> 1) * 64;
  if (tid < 128) red[tid] = 0.f;

  float c0[4], gg[4], bb[4];
#pragma unroll
  for (int ni = 0; ni < 4; ++ni) {
    int n = n0w + ni * 16 + lrow;
    c0[ni] = fb2[n]; gg[ni] = l2g[n]; bb[ni] = l2b[n];
  }

  f32x4 acc[4];
#pragma unroll
  for (int ni = 0; ni < 4; ++ni) acc[ni] = (f32x4){0.f, 0.f, 0.f, 0.f};

  const int q = wid * 64 + lane;
  const u16* aG = Abuf + (size_t)(mtile * 32 + (q >> 3)) * 512 + (q & 7) * 8;

  auto stage = [&](int t) {
    int buf = t % 3;
    short8v* A = lds + buf * 1280;
    __builtin_amdgcn_global_load_lds(
        (const __attribute__((address_space(1))) void*)(aG + t * 64),
        (__attribute__((address_space(3))) void*)(A + wid * 64), 16, 0, 0);
#pragma unroll
    for (int r = 0; r < 4; ++r) {
      int qq = r * 256 + q;
      const u16* g = w2fb + (size_t)(qq >> 3) * 512 + t * 64 + (qq & 7) * 8;
      __builtin_amdgcn_global_load_lds(
          (const __attribute__((address_space(1))) void*)g,
          (__attribute__((address_space(3))) void*)(A + 256 + r * 256 + wid * 64), 16, 0, 0);
    }
  };

  auto compute = [&](int t) {
    int buf = t % 3;
    const short8v* A = lds + buf * 1280;
    const short8v* B = A + 256;
#pragma unroll
    for (int ks = 0; ks < 2; ++ks) {
      int ar = m0w + lrow;
      u32 ao = ((u32)(ar * 128 + ks * 64 + lk * 16)) ^ ((u32)((ar & 7) << 4));
      short8v af = A[ao >> 4];
#pragma unroll
      for (int ni = 0; ni < 4; ++ni) {
        int br = n0w + ni * 16 + lrow;
        u32 bo = ((u32)(br * 128 + ks * 64 + lk * 16)) ^ ((u32)((br & 7) << 4));
        short8v bf = B[bo >> 4];
        acc[ni] = __builtin_amdgcn_mfma_f32_16x16x32_bf16(af, bf, acc[ni], 0, 0, 0);
      }
    }
  };

  stage(0); stage(1); stage(2);
  for (int t = 0; t < 6; ++t) {
    wait_vmcnt<10>();
    __builtin_amdgcn_s_barrier();
    __builtin_amdgcn_sched_barrier(0);
    compute(t);
    asm volatile("" ::: "memory");
    __builtin_amdgcn_s_barrier();
    __builtin_amdgcn_sched_barrier(0);
    if (t <= 4) stage(t + 3);
  }
  wait_vmcnt<5>();
  __builtin_amdgcn_s_barrier();
  __builtin_amdgcn_sched_barrier(0);
  compute(6);
  asm volatile("" ::: "memory");
  __builtin_amdgcn_s_barrier();
  __builtin_amdgcn_sched_barrier(0);
  wait_vmcnt<0>();
  __builtin_amdgcn_s_barrier();
  __builtin_amdgcn_sched_barrier(0);
  compute(7);

  // ---- fused epilogue: y = acc + b2 + att ; LN2 over n ; GAP ----
  float y[4][4];
  float s1[4] = {0.f, 0.f, 0.f, 0.f}, s2[4] = {0.f, 0.f, 0.f, 0.f};
#pragma unroll
  for (int ni = 0; ni < 4; ++ni) {
    int n = n0w + ni * 16 + lrow;
#pragma unroll
    for (int r = 0; r < 4; ++r) {
      int grow = mtile * 32 + m0w + lk * 4 + r;
      float v = acc[ni][r] + c0[ni] + res[(size_t)grow * kE + n];
      y[ni][r] = v;
      s1[r] += v;
      s2[r] += v * v;
    }
  }
#pragma unroll
  for (int r = 0; r < 4; ++r) {
    for (int off = 1; off < 16; off <<= 1) {
      s1[r] += __shfl_xor(s1[r], off);
      s2[r] += __shfl_xor(s2[r], off);
    }
  }
  // combine the two n-halves via LDS (wave half = wid>>1)
  __syncthreads();   // red[] init + pipeline done
  if (lrow == 0) {
#pragma unroll
    for (int r = 0; r < 4; ++r) {
      int ridx = m0w + lk * 4 + r;
      st1[wid >> 1][ridx] = s1[r];
      st2[wid >> 1][ridx] = s2[r];
    }
  }
  __syncthreads();
  float colsum[4] = {0.f, 0.f, 0.f, 0.f};
#pragma unroll
  for (int r = 0; r < 4; ++r) {
    int ridx = m0w + lk * 4 + r;
    float t1 = st1[0][ridx] + st1[1][ridx];
    float t2 = st2[0][ridx] + st2[1][ridx];
    float mean = t1 * (1.f / 128.f);
    float var = t2 * (1.f / 128.f) - mean * mean;
    float inv = __frsqrt_rn(var + kEps);
#pragma unroll
    for (int ni = 0; ni < 4; ++ni)
      colsum[ni] += (y[ni][r] - mean) * inv * gg[ni] + bb[ni];
  }
#pragma unroll
  for (int ni = 0; ni < 4; ++ni) {
    colsum[ni] += __shfl_xor(colsum[ni], 16);
    colsum[ni] += __shfl_xor(colsum[ni], 32);
  }
  if (lk == 0) {
#pragma unroll
    for (int ni = 0; ni < 4; ++ni)
      atomicAdd(&red[n0w + ni * 16 + lrow], colsum[ni]);
  }
  __syncthreads();
  int b = mtile >> 5;
  if (tid < 128) atomicAdd(&dout[b * kE + tid], red[tid] * (1.f / 1024.f));
}

// =====================================================================
// MFMA attention v5 (unchanged — proven)
// =====================================================================
__global__ __launch_bounds__(512, 4) void attn_kernel(
    const u16* __restrict__ qb, const u16* __restrict__ kb,
    const u16* __restrict__ vb, const u16* __restrict__ rbT,
    float* __restrict__ o) {
  __shared__ u16 Vsh[16 * 1032];
  __shared__ u16 Pt[8][1280];

  int tid = threadIdx.x;
  int bid = blockIdx.x;
  int quarter = bid >> 7;
  int bb = (bid >> 3) & 15;
  int h = bid & 7;
  size_t base = (size_t)(bb * kH + h) * (kS * kDH);

  for (int j = tid; j < 1024; j += 512) {
    const uint4* src = (const uint4*)(vb + base + j * 16);
    uint4 a = src[0], b = src[1];
    u32 wv[8] = {a.x, a.y, a.z, a.w, b.x, b.y, b.z, b.w};
#pragma unroll
    for (int p = 0; p < 8; ++p) {
      Vsh[(2 * p) * 1032 + j]     = (u16)(wv[p] & 0xFFFFu);
      Vsh[(2 * p + 1) * 1032 + j] = (u16)(wv[p] >> 16);
    }
  }
  __syncthreads();

  int w = tid >> 6, l = tid & 63;
  int lr = l & 15, lg = l >> 4;
  int q32 = l & 31, hi = l >> 5;
  u16* P = Pt[w];
  int q0w = quarter * 256 + w * 32;
  int tbase = (q0w + 992) >> 4;
  const u16* rbh = rbT + (size_t)h * 126 * 512;

  short8v qf = *(const short8v*)(qb + base + (size_t)(q0w + q32) * 16 + hi * 8);
  short8v ones;
#pragma unroll
  for (int e = 0; e < 8; ++e) ones[e] = (short)0x3F80;

  f32x4 acc_e[2], acc_rb[2], acc_l[2];
#pragma unroll
  for (int qt = 0; qt < 2; ++qt) {
    acc_e[qt] = (f32x4){0.f, 0.f, 0.f, 0.f};
    acc_rb[qt] = (f32x4){0.f, 0.f, 0.f, 0.f};
    acc_l[qt] = (f32x4){0.f, 0.f, 0.f, 0.f};
  }
  const f32x16 z16 = {0.f,0.f,0.f,0.f,0.f,0.f,0.f,0.f,0.f,0.f,0.f,0.f,0.f,0.f,0.f,0.f};

  for (int jb = 0; jb < 32; ++jb) {
    short8v kf = *(const short8v*)(kb + base + (size_t)(jb * 32 + q32) * 16 + hi * 8);
    f32x16 s = __builtin_amdgcn_mfma_f32_32x32x16_bf16(kf, qf, z16, 0, 0, 0);
    float ev[16];
#pragma unroll
    for (int r = 0; r < 16; ++r) ev[r] = exp2f(s[r]);
#pragma unroll
    for (int rq = 0; rq < 4; ++rq) {
      u32 p0, p1;
      asm("v_cvt_pk_bf16_f32 %0, %1, %2" : "=v"(p0) : "v"(ev[4 * rq]), "v"(ev[4 * rq + 1]));
      asm("v_cvt_pk_bf16_f32 %0, %1, %2" : "=v"(p1) : "v"(ev[4 * rq + 2]), "v"(ev[4 * rq + 3]));
      *(uint2*)(P + q32 * 40 + rq * 8 + hi * 4) = make_uint2(p0, p1);
    }
    short8v vf = *(const short8v*)(Vsh + lr * 1032 + jb * 32 + lg * 8);
#pragma unroll
    for (int qt = 0; qt < 2; ++qt) {
      short8v pf = *(const short8v*)(P + (qt * 16 + lr) * 40 + lg * 8);
      int t = tbase + qt - 2 * jb;
      short8v rf = *(const short8v*)(rbh + ((size_t)t * 64 + l) * 8);
      acc_e[qt]  = __builtin_amdgcn_mfma_f32_16x16x32_bf16(pf, vf, acc_e[qt], 0, 0, 0);
      acc_l[qt]  = __builtin_amdgcn_mfma_f32_16x16x32_bf16(pf, ones, acc_l[qt], 0, 0, 0);
      acc_rb[qt] = __builtin_amdgcn_mfma_f32_16x16x32_bf16(rf, vf, acc_rb[qt], 0, 0, 0);
    }
  }

#pragma unroll
  for (int qt = 0; qt < 2; ++qt) {
#pragma unroll
    for (int r = 0; r < 4; ++r) {
      int qloc = qt * 16 + lg * 4 + r;
      int row = q0w + qloc;
      o[(size_t)(bb * kS + row) * kE + h * kDH + lr] =
          acc_e[qt][r] / acc_l[qt][r] + acc_rb[qt][r];
    }
  }
}

// ---------------- LN(attn out) + residual + LN1 -> att (f32 + bf16) ----------------
__global__ __launch_bounds__(256) void ln_kernel(
    cfp o, cfp xsrc, cfp lag, cfp lab, cfp l1g, cfp l1b,
    float* __restrict__ att, u16* __restrict__ attb) {
  int row = blockIdx.x * 4 + (threadIdx.x >> 6);
  int lane = threadIdx.x & 63;
  float2 a = ((const float2*)(o + (size_t)row * kE))[lane];
  float sum = a.x + a.y;
  for (int off = 1; off < 64; off <<= 1) sum += __shfl_xor(sum, off);
  float mean = sum * (1.f / 128.f);
  float d0 = a.x - mean, d1 = a.y - mean;
  float ss = d0 * d0 + d1 * d1;
  for (int off = 1; off < 64; off <<= 1) ss += __shfl_xor(ss, off);
  float inv = 1.f / sqrtf(ss * (1.f / 128.f) + kEps);
  float t0 = d0 * inv * lag[2 * lane] + lab[2 * lane];
  float t1 = d1 * inv * lag[2 * lane + 1] + lab[2 * lane + 1];
  float2 xv = ((const float2*)(xsrc + (size_t)row * kE))[lane];
  t0 += xv.x; t1 += xv.y;
  float sum2 = t0 + t1;
  for (int off = 1; off < 64; off <<= 1) sum2 += __shfl_xor(sum2, off);
  float mean2 = sum2 * (1.f / 128.f);
  float e0 = t0 - mean2, e1 = t1 - mean2;
  float ss2 = e0 * e0 + e1 * e1;
  for (int off = 1; off < 64; off <<= 1) ss2 += __shfl_xor(ss2, off);
  float inv2 = 1.f / sqrtf(ss2 * (1.f / 128.f) + kEps);
  float r0 = e0 * inv2 * l1g[2 * lane] + l1b[2 * lane];
  float r1 = e1 * inv2 * l1g[2 * lane + 1] + l1b[2 * lane + 1];
  ((float2*)(att + (size_t)row * kE))[lane] = make_float2(r0, r1);
  ((u32*)attb)[(size_t)row * 64 + lane] = (u32)f2b(r0) | ((u32)f2b(r1) << 16);
}

extern "C" void kernel_launch(void* const* d_in, const int* in_sizes, int n_in,
                              void* d_out, int out_size, void* d_ws, size_t ws_size,
                              hipStream_t stream) {
  const float* wf[27];
  for (int i = 0; i < n_in && i < 27; ++i) wf[i] = (const float*)d_in[i];

  float* ws = (float*)d_ws;
  float* xsrc  = ws;                             // 2,097,152 f32
  float* att   = xsrc + 2097152;                 // 2,097,152 f32
  float* qkv0  = att + 2097152;                  // 3,145,728 (q,k,v bf16)
  float* ext   = qkv0 + 3145728;                 // 1,048,576 (ff1b tail only)
  float* o     = ext + 1048576;                  // 2,097,152
  u16* xpeb    = (u16*)(o + 2097152);            // 2,097,152 u16
  u16* w2b     = xpeb + 2097152;                 // 262,144 u16
  u16* rbT     = w2b + 262144;                   // 516,096 u16 — outside Abuf overlay
  u16* w2fb    = rbT + 516096;                   // 65,536 u16

  u16* Abuf = (u16*)att;                         // overlays att..o (8,388,608 f32) exactly
  u16* qb = (u16*)qkv0;
  u16* kb = qb + 2097152;
  u16* vb = kb + 2097152;
  u16* ff1b = (u16*)qkv0;                        // spans qkv0+ext
  u16* attb = xpeb;
  float* doutf = (float*)d_out;

  (void)hipMemsetAsync(d_out, 0, (size_t)out_size * sizeof(float), stream);

  prep_kernel<<<412, 256, 0, stream>>>(wf[7], w2b, wf[16], rbT, wf[23], w2fb);

  for (int hm = 0; hm < 2; ++hm) {
    convstage_kernel<<<8192, 256, 0, stream>>>(
        wf[0], wf[1], wf[2], wf[3], wf[4], wf[5], wf[6], Abuf, hm * 8192);
    convgemm_kernel<<<256, 256, 0, stream>>>(
        Abuf, w2b, wf[8], wf[9], wf[10], wf[11], wf[12], xsrc, xpeb, hm * 8192);
  }

  gemm_kernel<3, 1, 128, 64><<<dim3(256, 2, 3), 256, 0, stream>>>(
      xpeb, wf[13], nullptr, wf[14], wf[15], qb, nullptr, 0);

  attn_kernel<<<512, 512, 0, stream>>>(qb, kb, vb, rbT, o);
  ln_kernel<<<4096, 256, 0, stream>>>(o, xsrc, wf[17], wf[18], wf[19], wf[20], att, attb);

  gemm_kernel<3, 2, 128, 64><<<dim3(256, 8), 256, 0, stream>>>(
      attb, wf[21], wf[22], nullptr, nullptr, ff1b, nullptr, 0);

  ff2ln_kernel<<<512, 256, 0, stream>>>(ff1b, w2fb, wf[24], wf[25], wf[26], att, doutf);
}

// Round 15
// 140.150 us; speedup vs baseline: 1.9049x; 1.1563x over previous
//
#include <hip/hip_runtime.h>
#include <hip/hip_bf16.h>
#include <math.h>

using bf16 = __hip_bfloat16;
typedef unsigned short u16;
typedef unsigned int u32;
typedef const float* __restrict__ cfp;

typedef __attribute__((ext_vector_type(8))) short short8v;
typedef __attribute__((ext_vector_type(4))) float f32x4;
typedef __attribute__((ext_vector_type(16))) float f32x16;

static constexpr int kS = 1024, kE = 128, kH = 8, kDH = 16, kDFF = 512;
static constexpr float kEps = 1e-5f;

__device__ __forceinline__ float geluf(float x) { return 0.5f * x * (1.f + erff(x * 0.70710678118654752f)); }
__device__ __forceinline__ u16 f2b(float f) {
  u32 u = __float_as_uint(f);
  u32 r = (u + 0x7FFFu + ((u >> 16) & 1u)) >> 16;
  return (u16)r;
}

template<int N> __device__ __forceinline__ void wait_vmcnt() {
  asm volatile("s_waitcnt vmcnt(%0)" :: "n"(N) : "memory");
  __builtin_amdgcn_sched_barrier(0);
}

// ---------------- prep: w2conv->bf16 perm + rbT table + ffw2->bf16 perm + zero d_out ----------------
__global__ __launch_bounds__(256) void prep_kernel(
    cfp w2, u16* __restrict__ w2b, cfp relb, u16* __restrict__ T,
    cfp fw2, u16* __restrict__ w2fb, float* __restrict__ dout) {
  int bid = blockIdx.x;
  if (bid < 128) {
    int n = bid, ck = threadIdx.x;
    const float* src = w2 + (size_t)n * 2048 + (size_t)ck * 8;
    float4 a = *(const float4*)src;
    float4 b = *(const float4*)(src + 4);
    short8v sv;
    sv[0] = (short)f2b(a.x); sv[1] = (short)f2b(a.y);
    sv[2] = (short)f2b(a.z); sv[3] = (short)f2b(a.w);
    sv[4] = (short)f2b(b.x); sv[5] = (short)f2b(b.y);
    sv[6] = (short)f2b(b.z); sv[7] = (short)f2b(b.w);
    int cd = (ck & ~7) | ((ck & 7) ^ (n & 7));
    *(short8v*)(w2b + (size_t)n * 2048 + cd * 8) = sv;
  } else if (bid < 380) {
    int idx = (bid - 128) * 4 + (threadIdx.x >> 6);   // 0..1007 = h*126+t
    int l = threadIdx.x & 63;
    int h = idx / 126, t = idx - h * 126;
    int lr = l & 15, lg = l >> 4;
    short8v v;
#pragma unroll
    for (int e = 0; e < 8; ++e) {
      int ix = 16 * t + 31 + lr - 8 * lg - e;
      v[e] = (short)f2b(relb[ix * 8 + h]);
    }
    *(short8v*)(T + ((size_t)(h * 126 + t) * 64 + l) * 8) = v;
  } else if (bid < 412) {
    int n = (bid - 380) * 4 + (threadIdx.x >> 6);     // 0..127
    int ck = threadIdx.x & 63;                        // 64 chunks of 8 u16
    const float* src = fw2 + (size_t)n * 512 + (size_t)ck * 8;
    float4 a = *(const float4*)src;
    float4 b = *(const float4*)(src + 4);
    short8v sv;
    sv[0] = (short)f2b(a.x); sv[1] = (short)f2b(a.y);
    sv[2] = (short)f2b(a.z); sv[3] = (short)f2b(a.w);
    sv[4] = (short)f2b(b.x); sv[5] = (short)f2b(b.y);
    sv[6] = (short)f2b(b.z); sv[7] = (short)f2b(b.w);
    int cd = (ck & ~7) | ((ck & 7) ^ (n & 7));
    *(short8v*)(w2fb + (size_t)n * 512 + cd * 8) = sv;
  } else {
    // zero d_out (2048 f32) — replaces the hipMemsetAsync graph node
#pragma unroll
    for (int e = 0; e < 8; ++e) dout[threadIdx.x * 8 + e] = 0.f;
  }
}

// ---------------- conv1+bn1+gelu -> Abuf bf16 [16384][2048], chunk-permuted ----------------
__global__ __launch_bounds__(256) void convstage_kernel(
    cfp x, cfp w1, cfp c1b, cfp g1, cfp b1, cfp m1, cfp v1,
    u16* __restrict__ Abuf) {
  __shared__ float xs[8][4];
  int row = blockIdx.x;
  int b = row >> 10, s = row & 1023;
  int tid = threadIdx.x;
  if (tid < 8) {
    int gs = s - 3 + tid;
    float4 xv = (gs >= 0 && gs < kS) ? ((const float4*)x)[b * kS + gs]
                                     : make_float4(0.f, 0.f, 0.f, 0.f);
    xs[tid][0] = xv.x; xs[tid][1] = xv.y; xs[tid][2] = xv.z; xs[tid][3] = xv.w;
  }
  __syncthreads();
  short8v outv;
#pragma unroll
  for (int cc = 0; cc < 2; ++cc) {
    int cx = tid * 2 + cc;
    float w[8];
#pragma unroll
    for (int t = 0; t < 8; ++t) w[t] = w1[cx * 8 + t];
    float sc = g1[cx] * __frsqrt_rn(v1[cx] + kEps);
    float ofs = b1[cx] - m1[cx] * sc;
    float cb = c1b[cx];
#pragma unroll
    for (int r = 0; r < 4; ++r) {
      float h = cb;
#pragma unroll
      for (int t = 0; t < 8; ++t) h += xs[t][r] * w[t];
      outv[cc * 4 + r] = (short)f2b(geluf(h * sc + ofs));
    }
  }
  int ck = (tid & ~7) | ((tid & 7) ^ (row & 7));
  *(short8v*)(Abuf + (size_t)row * 2048 + ck * 8) = outv;
}

// =====================================================================
// Pipelined conv GEMM (proven; now grid 512 = 2 blocks/CU, full M)
// =====================================================================
__global__ __launch_bounds__(256, 2) void convgemm_kernel(
    const u16* __restrict__ Abuf, const u16* __restrict__ w2b,
    cfp c2b, cfp g2, cfp b2, cfp m2, cfp v2,
    float* __restrict__ xsrc, u16* __restrict__ xpeb) {
  __shared__ short8v lds[3840];
  const int tid = threadIdx.x;
  const int mtile = blockIdx.x;
  const int wid = tid >> 6, lane = tid & 63;
  const int lrow = lane & 15, lk = lane >> 4;
  const int m0w = (wid & 1) * 16, n0w = (wid >> 1) * 64;

  float scn[4], cc[4], dv[4];
#pragma unroll
  for (int ni = 0; ni < 4; ++ni) {
    int n = n0w + ni * 16 + lrow;
    scn[ni] = g2[n] * __frsqrt_rn(v2[n] + kEps);
    cc[ni] = (c2b[n] - m2[n]) * scn[ni] + b2[n];
    dv[ni] = __expf((float)(n >> 1) * (-0.14391156824963732f)) * 0.125f;
  }

  f32x4 acc[4];
#pragma unroll
  for (int ni = 0; ni < 4; ++ni) acc[ni] = (f32x4){0.f, 0.f, 0.f, 0.f};

  const int q = wid * 64 + lane;
  const u16* aG = Abuf + (size_t)(mtile * 32 + (q >> 3)) * 2048 + (q & 7) * 8;

  auto stage = [&](int t) {
    int buf = t % 3;
    short8v* A = lds + buf * 1280;
    __builtin_amdgcn_global_load_lds(
        (const __attribute__((address_space(1))) void*)(aG + t * 64),
        (__attribute__((address_space(3))) void*)(A + wid * 64), 16, 0, 0);
#pragma unroll
    for (int r = 0; r < 4; ++r) {
      int qq = r * 256 + q;
      const u16* g = w2b + (size_t)(qq >> 3) * 2048 + t * 64 + (qq & 7) * 8;
      __builtin_amdgcn_global_load_lds(
          (const __attribute__((address_space(1))) void*)g,
          (__attribute__((address_space(3))) void*)(A + 256 + r * 256 + wid * 64), 16, 0, 0);
    }
  };

  auto compute = [&](int t) {
    int buf = t % 3;
    const short8v* A = lds + buf * 1280;
    const short8v* B = A + 256;
#pragma unroll
    for (int ks = 0; ks < 2; ++ks) {
      int ar = m0w + lrow;
      u32 ao = ((u32)(ar * 128 + ks * 64 + lk * 16)) ^ ((u32)((ar & 7) << 4));
      short8v af = A[ao >> 4];
#pragma unroll
      for (int ni = 0; ni < 4; ++ni) {
        int br = n0w + ni * 16 + lrow;
        u32 bo = ((u32)(br * 128 + ks * 64 + lk * 16)) ^ ((u32)((br & 7) << 4));
        short8v bf = B[bo >> 4];
        acc[ni] = __builtin_amdgcn_mfma_f32_16x16x32_bf16(af, bf, acc[ni], 0, 0, 0);
      }
    }
  };

  stage(0); stage(1); stage(2);
  for (int t = 0; t < 30; ++t) {
    wait_vmcnt<10>();
    __builtin_amdgcn_s_barrier();
    __builtin_amdgcn_sched_barrier(0);
    compute(t);
    asm volatile("" ::: "memory");
    __builtin_amdgcn_s_barrier();
    __builtin_amdgcn_sched_barrier(0);
    if (t <= 28) stage(t + 3);
  }
  wait_vmcnt<5>();
  __builtin_amdgcn_s_barrier();
  __builtin_amdgcn_sched_barrier(0);
  compute(30);
  asm volatile("" ::: "memory");
  __builtin_amdgcn_s_barrier();
  __builtin_amdgcn_sched_barrier(0);
  wait_vmcnt<0>();
  __builtin_amdgcn_s_barrier();
  __builtin_amdgcn_sched_barrier(0);
  compute(31);

#pragma unroll
  for (int ni = 0; ni < 4; ++ni) {
    int n = n0w + ni * 16 + lrow;
#pragma unroll
    for (int r = 0; r < 4; ++r) {
      int grow = mtile * 32 + m0w + lk * 4 + r;
      float gv = geluf(acc[ni][r] * scn[ni] + cc[ni]);
      xsrc[(size_t)grow * kE + n] = gv;
      int s = grow & 1023;
      float ang = (float)s * dv[ni];
      float pe = (n & 1) ? __cosf(ang) : __sinf(ang);
      xpeb[(size_t)grow * kE + n] = f2b(gv + pe);
    }
  }
}

// =====================================================================
// bf16 MFMA GEMM (QKV / FF1). MODE==1 z==0 (Q) pre-scaled by
// 128^-0.5*log2(e). MODE==2 writes ff1b chunk-permuted for ff2ln.
// =====================================================================
template<int ASRC, int MODE, int KTOT, int BM>
__global__ __launch_bounds__(256, 4) void gemm_kernel(
    const void* __restrict__ Ap, cfp Wf,
    cfp p0, cfp p1, cfp p2,
    void* __restrict__ Out, cfp res, int mbase) {
  constexpr int MI = BM / 32;
  __shared__ short8v Ab[BM * 8];
  __shared__ short8v Bb[512];

  int tid = threadIdx.x;
  int mtile = blockIdx.x, ntile = blockIdx.y;

  cfp Wsel = Wf;
  if (MODE == 1) Wsel = (blockIdx.z == 0) ? Wf : ((blockIdx.z == 1) ? p1 : p2);

  int wid = tid >> 6, lane = tid & 63;
  int m0w = (wid >> 1) * (BM / 2), n0w = (wid & 1) * 32;
  int lrow = lane & 15, lk = lane >> 4;

  f32x4 acc[MI][2];
#pragma unroll
  for (int mi = 0; mi < MI; ++mi)
#pragma unroll
    for (int ni = 0; ni < 2; ++ni) acc[mi][ni] = (f32x4){0.f, 0.f, 0.f, 0.f};

  for (int k0 = 0; k0 < KTOT; k0 += 64) {
    __syncthreads();
#pragma unroll
    for (int c = 0; c < BM / 32; ++c) {
      int chunk = tid + 256 * c;
      int row = chunk >> 3, kc = chunk & 7;
      int arow = mtile * BM + row;
      u32 off = ((u32)(row * 128 + kc * 16)) ^ ((u32)((row & 7) << 4));
      const u16* As = (const u16*)Ap + (size_t)arow * KTOT + k0 + kc * 8;
      Ab[off >> 4] = *(const short8v*)As;
    }
#pragma unroll
    for (int c = 0; c < 2; ++c) {
      int chunk = tid + 256 * c;
      int row = chunk >> 3, kc = chunk & 7;
      const float* Wp = Wsel + (size_t)(ntile * 64 + row) * KTOT + k0 + kc * 8;
      float4 xa = *(const float4*)Wp;
      float4 xb = *(const float4*)(Wp + 4);
      short8v sv;
      sv[0] = (short)f2b(xa.x); sv[1] = (short)f2b(xa.y);
      sv[2] = (short)f2b(xa.z); sv[3] = (short)f2b(xa.w);
      sv[4] = (short)f2b(xb.x); sv[5] = (short)f2b(xb.y);
      sv[6] = (short)f2b(xb.z); sv[7] = (short)f2b(xb.w);
      u32 off = ((u32)(row * 128 + kc * 16)) ^ ((u32)((row & 7) << 4));
      Bb[off >> 4] = sv;
    }
    __syncthreads();
#pragma unroll
    for (int ks = 0; ks < 2; ++ks) {
      short8v af[MI], bfr[2];
#pragma unroll
      for (int mi = 0; mi < MI; ++mi) {
        int row = m0w + mi * 16 + lrow;
        u32 off = ((u32)(row * 128 + ks * 64 + lk * 16)) ^ ((u32)((row & 7) << 4));
        af[mi] = Ab[off >> 4];
      }
#pragma unroll
      for (int ni = 0; ni < 2; ++ni) {
        int row = n0w + ni * 16 + lrow;
        u32 off = ((u32)(row * 128 + ks * 64 + lk * 16)) ^ ((u32)((row & 7) << 4));
        bfr[ni] = Bb[off >> 4];
      }
#pragma unroll
      for (int mi = 0; mi < MI; ++mi)
#pragma unroll
        for (int ni = 0; ni < 2; ++ni)
          acc[mi][ni] = __builtin_amdgcn_mfma_f32_16x16x32_bf16(af[mi], bfr[ni], acc[mi][ni], 0, 0, 0);
    }
  }

  const float qsc = 0.088388347648318447f * 1.4426950408889634f;
#pragma unroll
  for (int ni = 0; ni < 2; ++ni) {
    int n = ntile * 64 + n0w + ni * 16 + lrow;
    float c0 = 0.f;
    if (MODE == 2) c0 = p0[n];
#pragma unroll
    for (int mi = 0; mi < MI; ++mi) {
#pragma unroll
      for (int r = 0; r < 4; ++r) {
        int grow = mbase + mtile * BM + m0w + mi * 16 + lk * 4 + r;
        float val = acc[mi][ni][r];
        if (MODE == 1) {
          if (blockIdx.z == 0) val *= qsc;
          int s = grow & 1023, b_ = grow >> 10;
          u16* ob = (u16*)Out + (size_t)blockIdx.z * 2097152;
          ob[(((size_t)(b_ * kH + (n >> 4))) * kS + s) * kDH + (n & 15)] = f2b(val);
        } else if (MODE == 2) {
          int np = (n & ~56) | ((((n >> 3) ^ grow) & 7) << 3);
          ((u16*)Out)[(size_t)grow * kDFF + np] = f2b(fmaxf(val + c0, 0.f));
        }
      }
    }
  }
}

// =====================================================================
// FF2 pipelined + fused bias/residual/LN2/GAP epilogue (proven)
// =====================================================================
__global__ __launch_bounds__(256, 2) void ff2ln_kernel(
    const u16* __restrict__ Abuf, const u16* __restrict__ w2fb,
    cfp fb2, cfp l2g, cfp l2b, cfp res, float* __restrict__ dout) {
  __shared__ short8v lds[3840];
  __shared__ float st1[2][32], st2[2][32];
  __shared__ float red[128];
  const int tid = threadIdx.x;
  const int mtile = blockIdx.x;
  const int wid = tid >> 6, lane = tid & 63;
  const int lrow = lane & 15, lk = lane >> 4;
  const int m0w = (wid & 1) * 16, n0w = (wid >> 1) * 64;
  if (tid < 128) red[tid] = 0.f;

  float c0[4], gg[4], bb[4];
#pragma unroll
  for (int ni = 0; ni < 4; ++ni) {
    int n = n0w + ni * 16 + lrow;
    c0[ni] = fb2[n]; gg[ni] = l2g[n]; bb[ni] = l2b[n];
  }

  f32x4 acc[4];
#pragma unroll
  for (int ni = 0; ni < 4; ++ni) acc[ni] = (f32x4){0.f, 0.f, 0.f, 0.f};

  const int q = wid * 64 + lane;
  const u16* aG = Abuf + (size_t)(mtile * 32 + (q >> 3)) * 512 + (q & 7) * 8;

  auto stage = [&](int t) {
    int buf = t % 3;
    short8v* A = lds + buf * 1280;
    __builtin_amdgcn_global_load_lds(
        (const __attribute__((address_space(1))) void*)(aG + t * 64),
        (__attribute__((address_space(3))) void*)(A + wid * 64), 16, 0, 0);
#pragma unroll
    for (int r = 0; r < 4; ++r) {
      int qq = r * 256 + q;
      const u16* g = w2fb + (size_t)(qq >> 3) * 512 + t * 64 + (qq & 7) * 8;
      __builtin_amdgcn_global_load_lds(
          (const __attribute__((address_space(1))) void*)g,
          (__attribute__((address_space(3))) void*)(A + 256 + r * 256 + wid * 64), 16, 0, 0);
    }
  };

  auto compute = [&](int t) {
    int buf = t % 3;
    const short8v* A = lds + buf * 1280;
    const short8v* B = A + 256;
#pragma unroll
    for (int ks = 0; ks < 2; ++ks) {
      int ar = m0w + lrow;
      u32 ao = ((u32)(ar * 128 + ks * 64 + lk * 16)) ^ ((u32)((ar & 7) << 4));
      short8v af = A[ao >> 4];
#pragma unroll
      for (int ni = 0; ni < 4; ++ni) {
        int br = n0w + ni * 16 + lrow;
        u32 bo = ((u32)(br * 128 + ks * 64 + lk * 16)) ^ ((u32)((br & 7) << 4));
        short8v bf = B[bo >> 4];
        acc[ni] = __builtin_amdgcn_mfma_f32_16x16x32_bf16(af, bf, acc[ni], 0, 0, 0);
      }
    }
  };

  stage(0); stage(1); stage(2);
  for (int t = 0; t < 6; ++t) {
    wait_vmcnt<10>();
    __builtin_amdgcn_s_barrier();
    __builtin_amdgcn_sched_barrier(0);
    compute(t);
    asm volatile("" ::: "memory");
    __builtin_amdgcn_s_barrier();
    __builtin_amdgcn_sched_barrier(0);
    if (t <= 4) stage(t + 3);
  }
  wait_vmcnt<5>();
  __builtin_amdgcn_s_barrier();
  __builtin_amdgcn_sched_barrier(0);
  compute(6);
  asm volatile("" ::: "memory");
  __builtin_amdgcn_s_barrier();
  __builtin_amdgcn_sched_barrier(0);
  wait_vmcnt<0>();
  __builtin_amdgcn_s_barrier();
  __builtin_amdgcn_sched_barrier(0);
  compute(7);

  float y[4][4];
  float s1[4] = {0.f, 0.f, 0.f, 0.f}, s2[4] = {0.f, 0.f, 0.f, 0.f};
#pragma unroll
  for (int ni = 0; ni < 4; ++ni) {
    int n = n0w + ni * 16 + lrow;
#pragma unroll
    for (int r = 0; r < 4; ++r) {
      int grow = mtile * 32 + m0w + lk * 4 + r;
      float v = acc[ni][r] + c0[ni] + res[(size_t)grow * kE + n];
      y[ni][r] = v;
      s1[r] += v;
      s2[r] += v * v;
    }
  }
#pragma unroll
  for (int r = 0; r < 4; ++r) {
    for (int off = 1; off < 16; off <<= 1) {
      s1[r] += __shfl_xor(s1[r], off);
      s2[r] += __shfl_xor(s2[r], off);
    }
  }
  __syncthreads();
  if (lrow == 0) {
#pragma unroll
    for (int r = 0; r < 4; ++r) {
      int ridx = m0w + lk * 4 + r;
      st1[wid >> 1][ridx] = s1[r];
      st2[wid >> 1][ridx] = s2[r];
    }
  }
  __syncthreads();
  float colsum[4] = {0.f, 0.f, 0.f, 0.f};
#pragma unroll
  for (int r = 0; r < 4; ++r) {
    int ridx = m0w + lk * 4 + r;
    float t1 = st1[0][ridx] + st1[1][ridx];
    float t2 = st2[0][ridx] + st2[1][ridx];
    float mean = t1 * (1.f / 128.f);
    float var = t2 * (1.f / 128.f) - mean * mean;
    float inv = __frsqrt_rn(var + kEps);
#pragma unroll
    for (int ni = 0; ni < 4; ++ni)
      colsum[ni] += (y[ni][r] - mean) * inv * gg[ni] + bb[ni];
  }
#pragma unroll
  for (int ni = 0; ni < 4; ++ni) {
    colsum[ni] += __shfl_xor(colsum[ni], 16);
    colsum[ni] += __shfl_xor(colsum[ni], 32);
  }
  if (lk == 0) {
#pragma unroll
    for (int ni = 0; ni < 4; ++ni)
      atomicAdd(&red[n0w + ni * 16 + lrow], colsum[ni]);
  }
  __syncthreads();
  int b = mtile >> 5;
  if (tid < 128) atomicAdd(&dout[b * kE + tid], red[tid] * (1.f / 1024.f));
}

// =====================================================================
// MFMA attention v5 (unchanged — proven)
// =====================================================================
__global__ __launch_bounds__(512, 4) void attn_kernel(
    const u16* __restrict__ qb, const u16* __restrict__ kb,
    const u16* __restrict__ vb, const u16* __restrict__ rbT,
    float* __restrict__ o) {
  __shared__ u16 Vsh[16 * 1032];
  __shared__ u16 Pt[8][1280];

  int tid = threadIdx.x;
  int bid = blockIdx.x;
  int quarter = bid >> 7;
  int bb = (bid >> 3) & 15;
  int h = bid & 7;
  size_t base = (size_t)(bb * kH + h) * (kS * kDH);

  for (int j = tid; j < 1024; j += 512) {
    const uint4* src = (const uint4*)(vb + base + j * 16);
    uint4 a = src[0], b = src[1];
    u32 wv[8] = {a.x, a.y, a.z, a.w, b.x, b.y, b.z, b.w};
#pragma unroll
    for (int p = 0; p < 8; ++p) {
      Vsh[(2 * p) * 1032 + j]     = (u16)(wv[p] & 0xFFFFu);
      Vsh[(2 * p + 1) * 1032 + j] = (u16)(wv[p] >> 16);
    }
  }
  __syncthreads();

  int w = tid >> 6, l = tid & 63;
  int lr = l & 15, lg = l >> 4;
  int q32 = l & 31, hi = l >> 5;
  u16* P = Pt[w];
  int q0w = quarter * 256 + w * 32;
  int tbase = (q0w + 992) >> 4;
  const u16* rbh = rbT + (size_t)h * 126 * 512;

  short8v qf = *(const short8v*)(qb + base + (size_t)(q0w + q32) * 16 + hi * 8);
  short8v ones;
#pragma unroll
  for (int e = 0; e < 8; ++e) ones[e] = (short)0x3F80;

  f32x4 acc_e[2], acc_rb[2], acc_l[2];
#pragma unroll
  for (int qt = 0; qt < 2; ++qt) {
    acc_e[qt] = (f32x4){0.f, 0.f, 0.f, 0.f};
    acc_rb[qt] = (f32x4){0.f, 0.f, 0.f, 0.f};
    acc_l[qt] = (f32x4){0.f, 0.f, 0.f, 0.f};
  }
  const f32x16 z16 = {0.f,0.f,0.f,0.f,0.f,0.f,0.f,0.f,0.f,0.f,0.f,0.f,0.f,0.f,0.f,0.f};

  for (int jb = 0; jb < 32; ++jb) {
    short8v kf = *(const short8v*)(kb + base + (size_t)(jb * 32 + q32) * 16 + hi * 8);
    f32x16 s = __builtin_amdgcn_mfma_f32_32x32x16_bf16(kf, qf, z16, 0, 0, 0);
    float ev[16];
#pragma unroll
    for (int r = 0; r < 16; ++r) ev[r] = exp2f(s[r]);
#pragma unroll
    for (int rq = 0; rq < 4; ++rq) {
      u32 p0, p1;
      asm("v_cvt_pk_bf16_f32 %0, %1, %2" : "=v"(p0) : "v"(ev[4 * rq]), "v"(ev[4 * rq + 1]));
      asm("v_cvt_pk_bf16_f32 %0, %1, %2" : "=v"(p1) : "v"(ev[4 * rq + 2]), "v"(ev[4 * rq + 3]));
      *(uint2*)(P + q32 * 40 + rq * 8 + hi * 4) = make_uint2(p0, p1);
    }
    short8v vf = *(const short8v*)(Vsh + lr * 1032 + jb * 32 + lg * 8);
#pragma unroll
    for (int qt = 0; qt < 2; ++qt) {
      short8v pf = *(const short8v*)(P + (qt * 16 + lr) * 40 + lg * 8);
      int t = tbase + qt - 2 * jb;
      short8v rf = *(const short8v*)(rbh + ((size_t)t * 64 + l) * 8);
      acc_e[qt]  = __builtin_amdgcn_mfma_f32_16x16x32_bf16(pf, vf, acc_e[qt], 0, 0, 0);
      acc_l[qt]  = __builtin_amdgcn_mfma_f32_16x16x32_bf16(pf, ones, acc_l[qt], 0, 0, 0);
      acc_rb[qt] = __builtin_amdgcn_mfma_f32_16x16x32_bf16(rf, vf, acc_rb[qt], 0, 0, 0);
    }
  }

#pragma unroll
  for (int qt = 0; qt < 2; ++qt) {
#pragma unroll
    for (int r = 0; r < 4; ++r) {
      int qloc = qt * 16 + lg * 4 + r;
      int row = q0w + qloc;
      o[(size_t)(bb * kS + row) * kE + h * kDH + lr] =
          acc_e[qt][r] / acc_l[qt][r] + acc_rb[qt][r];
    }
  }
}

// ---------------- LN(attn out) + residual + LN1 -> att (f32 + bf16) ----------------
__global__ __launch_bounds__(256) void ln_kernel(
    cfp o, cfp xsrc, cfp lag, cfp lab, cfp l1g, cfp l1b,
    float* __restrict__ att, u16* __restrict__ attb) {
  int row = blockIdx.x * 4 + (threadIdx.x >> 6);
  int lane = threadIdx.x & 63;
  float2 a = ((const float2*)(o + (size_t)row * kE))[lane];
  float sum = a.x + a.y;
  for (int off = 1; off < 64; off <<= 1) sum += __shfl_xor(sum, off);
  float mean = sum * (1.f / 128.f);
  float d0 = a.x - mean, d1 = a.y - mean;
  float ss = d0 * d0 + d1 * d1;
  for (int off = 1; off < 64; off <<= 1) ss += __shfl_xor(ss, off);
  float inv = 1.f / sqrtf(ss * (1.f / 128.f) + kEps);
  float t0 = d0 * inv * lag[2 * lane] + lab[2 * lane];
  float t1 = d1 * inv * lag[2 * lane + 1] + lab[2 * lane + 1];
  float2 xv = ((const float2*)(xsrc + (size_t)row * kE))[lane];
  t0 += xv.x; t1 += xv.y;
  float sum2 = t0 + t1;
  for (int off = 1; off < 64; off <<= 1) sum2 += __shfl_xor(sum2, off);
  float mean2 = sum2 * (1.f / 128.f);
  float e0 = t0 - mean2, e1 = t1 - mean2;
  float ss2 = e0 * e0 + e1 * e1;
  for (int off = 1; off < 64; off <<= 1) ss2 += __shfl_xor(ss2, off);
  float inv2 = 1.f / sqrtf(ss2 * (1.f / 128.f) + kEps);
  float r0 = e0 * inv2 * l1g[2 * lane] + l1b[2 * lane];
  float r1 = e1 * inv2 * l1g[2 * lane + 1] + l1b[2 * lane + 1];
  ((float2*)(att + (size_t)row * kE))[lane] = make_float2(r0, r1);
  ((u32*)attb)[(size_t)row * 64 + lane] = (u32)f2b(r0) | ((u32)f2b(r1) << 16);
}

extern "C" void kernel_launch(void* const* d_in, const int* in_sizes, int n_in,
                              void* d_out, int out_size, void* d_ws, size_t ws_size,
                              hipStream_t stream) {
  const float* wf[27];
  for (int i = 0; i < n_in && i < 27; ++i) wf[i] = (const float*)d_in[i];

  float* ws = (float*)d_ws;
  float* xsrc  = ws;                             // 2,097,152 f32
  float* att   = xsrc + 2097152;                 // 2,097,152 f32
  float* qkv0  = att + 2097152;                  // 3,145,728 (q,k,v bf16)
  float* ext   = qkv0 + 3145728;                 // 1,048,576 (ff1b tail only)
  float* o     = ext + 1048576;                  // 2,097,152
  u16* xpeb    = (u16*)(o + 2097152);            // 2,097,152 u16
  u16* w2b     = xpeb + 2097152;                 // 262,144 u16
  u16* rbT     = w2b + 262144;                   // 516,096 u16
  u16* w2fb    = rbT + 516096;                   // 65,536 u16
  u16* Abuf    = w2fb + 65536;                   // 33,554,432 u16 (67 MB) — dedicated

  u16* qb = (u16*)qkv0;
  u16* kb = qb + 2097152;
  u16* vb = kb + 2097152;
  u16* ff1b = (u16*)qkv0;                        // spans qkv0+ext (dead q/k/v by then)
  u16* attb = xpeb;
  float* doutf = (float*)d_out;

  prep_kernel<<<413, 256, 0, stream>>>(wf[7], w2b, wf[16], rbT, wf[23], w2fb, doutf);

  convstage_kernel<<<16384, 256, 0, stream>>>(
      wf[0], wf[1], wf[2], wf[3], wf[4], wf[5], wf[6], Abuf);
  convgemm_kernel<<<512, 256, 0, stream>>>(
      Abuf, w2b, wf[8], wf[9], wf[10], wf[11], wf[12], xsrc, xpeb);

  gemm_kernel<3, 1, 128, 64><<<dim3(256, 2, 3), 256, 0, stream>>>(
      xpeb, wf[13], nullptr, wf[14], wf[15], qb, nullptr, 0);

  attn_kernel<<<512, 512, 0, stream>>>(qb, kb, vb, rbT, o);
  ln_kernel<<<4096, 256, 0, stream>>>(o, xsrc, wf[17], wf[18], wf[19], wf[20], att, attb);

  gemm_kernel<3, 2, 128, 64><<<dim3(256, 8), 256, 0, stream>>>(
      attb, wf[21], wf[22], nullptr, nullptr, ff1b, nullptr, 0);

  ff2ln_kernel<<<512, 256, 0, stream>>>(ff1b, w2fb, wf[24], wf[25], wf[26], att, doutf);
}

// Round 16
// 131.037 us; speedup vs baseline: 2.0373x; 1.0695x over previous
//
#include <hip/hip_runtime.h>
#include <hip/hip_bf16.h>
#include <math.h>

using bf16 = __hip_bfloat16;
typedef unsigned short u16;
typedef unsigned int u32;
typedef const float* __restrict__ cfp;

typedef __attribute__((ext_vector_type(8))) short short8v;
typedef __attribute__((ext_vector_type(4))) float f32x4;
typedef __attribute__((ext_vector_type(16))) float f32x16;

static constexpr int kS = 1024, kE = 128, kH = 8, kDH = 16, kDFF = 512;
static constexpr float kEps = 1e-5f;

__device__ __forceinline__ float geluf(float x) { return 0.5f * x * (1.f + erff(x * 0.70710678118654752f)); }
// tanh-form GELU: |err| vs erf-form ~1e-3 absolute, overflow-safe
__device__ __forceinline__ float gelu_fast(float x) {
  float x2 = x * x;
  float u2 = 1.5957691216057308f * x * fmaf(0.044715f, x2, 1.f);   // 2*sqrt(2/pi)*(x+0.044715x^3)
  float t = __expf(u2);
  return fmaf(-x, __frcp_rn(t + 1.f), x);                          // x*t/(t+1)
}
__device__ __forceinline__ u16 f2b(float f) {
  u32 u = __float_as_uint(f);
  u32 r = (u + 0x7FFFu + ((u >> 16) & 1u)) >> 16;
  return (u16)r;
}

template<int N> __device__ __forceinline__ void wait_vmcnt() {
  asm volatile("s_waitcnt vmcnt(%0)" :: "n"(N) : "memory");
  __builtin_amdgcn_sched_barrier(0);
}

// ---------------- prep: w2conv->bf16 perm + rbT table + ffw2->bf16 perm + zero d_out ----------------
__global__ __launch_bounds__(256) void prep_kernel(
    cfp w2, u16* __restrict__ w2b, cfp relb, u16* __restrict__ T,
    cfp fw2, u16* __restrict__ w2fb, float* __restrict__ dout) {
  int bid = blockIdx.x;
  if (bid < 128) {
    int n = bid, ck = threadIdx.x;
    const float* src = w2 + (size_t)n * 2048 + (size_t)ck * 8;
    float4 a = *(const float4*)src;
    float4 b = *(const float4*)(src + 4);
    short8v sv;
    sv[0] = (short)f2b(a.x); sv[1] = (short)f2b(a.y);
    sv[2] = (short)f2b(a.z); sv[3] = (short)f2b(a.w);
    sv[4] = (short)f2b(b.x); sv[5] = (short)f2b(b.y);
    sv[6] = (short)f2b(b.z); sv[7] = (short)f2b(b.w);
    int cd = (ck & ~7) | ((ck & 7) ^ (n & 7));
    *(short8v*)(w2b + (size_t)n * 2048 + cd * 8) = sv;
  } else if (bid < 380) {
    int idx = (bid - 128) * 4 + (threadIdx.x >> 6);   // 0..1007 = h*126+t
    int l = threadIdx.x & 63;
    int h = idx / 126, t = idx - h * 126;
    int lr = l & 15, lg = l >> 4;
    short8v v;
#pragma unroll
    for (int e = 0; e < 8; ++e) {
      int ix = 16 * t + 31 + lr - 8 * lg - e;
      v[e] = (short)f2b(relb[ix * 8 + h]);
    }
    *(short8v*)(T + ((size_t)(h * 126 + t) * 64 + l) * 8) = v;
  } else if (bid < 412) {
    int n = (bid - 380) * 4 + (threadIdx.x >> 6);     // 0..127
    int ck = threadIdx.x & 63;
    const float* src = fw2 + (size_t)n * 512 + (size_t)ck * 8;
    float4 a = *(const float4*)src;
    float4 b = *(const float4*)(src + 4);
    short8v sv;
    sv[0] = (short)f2b(a.x); sv[1] = (short)f2b(a.y);
    sv[2] = (short)f2b(a.z); sv[3] = (short)f2b(a.w);
    sv[4] = (short)f2b(b.x); sv[5] = (short)f2b(b.y);
    sv[6] = (short)f2b(b.z); sv[7] = (short)f2b(b.w);
    int cd = (ck & ~7) | ((ck & 7) ^ (n & 7));
    *(short8v*)(w2fb + (size_t)n * 512 + cd * 8) = sv;
  } else {
#pragma unroll
    for (int e = 0; e < 8; ++e) dout[threadIdx.x * 8 + e] = 0.f;
  }
}

// ---------------- conv1+bn1+gelu -> Abuf bf16 [16384][2048], chunk-permuted ----------------
// 8 rows/block; per-thread channel pair constants hoisted; fast gelu; cvt_pk packing.
__global__ __launch_bounds__(256) void convstage_kernel(
    cfp x, cfp w1, cfp c1b, cfp g1, cfp b1, cfp m1, cfp v1,
    u16* __restrict__ Abuf) {
  __shared__ float xs[15][4];
  int row0 = blockIdx.x * 8;
  int b = row0 >> 10, s0 = row0 & 1023;
  int tid = threadIdx.x;
  if (tid < 15) {
    int gs = s0 - 3 + tid;
    float4 xv = (gs >= 0 && gs < kS) ? ((const float4*)x)[b * kS + gs]
                                     : make_float4(0.f, 0.f, 0.f, 0.f);
    xs[tid][0] = xv.x; xs[tid][1] = xv.y; xs[tid][2] = xv.z; xs[tid][3] = xv.w;
  }
  __syncthreads();

  float w[2][8], sc[2], ofs[2], cb[2];
#pragma unroll
  for (int cc = 0; cc < 2; ++cc) {
    int cx = tid * 2 + cc;
#pragma unroll
    for (int t = 0; t < 8; ++t) w[cc][t] = w1[cx * 8 + t];
    sc[cc] = g1[cx] * __frsqrt_rn(v1[cx] + kEps);
    ofs[cc] = b1[cx] - m1[cx] * sc[cc];
    cb[cc] = c1b[cx];
  }

  for (int rl = 0; rl < 8; ++rl) {
    float ev[8];
#pragma unroll
    for (int cc = 0; cc < 2; ++cc) {
#pragma unroll
      for (int rr = 0; rr < 4; ++rr) {
        float h = cb[cc];
#pragma unroll
        for (int t = 0; t < 8; ++t) h += xs[rl + t][rr] * w[cc][t];
        ev[cc * 4 + rr] = gelu_fast(h * sc[cc] + ofs[cc]);
      }
    }
    uint4 pk;
    asm("v_cvt_pk_bf16_f32 %0, %1, %2" : "=v"(pk.x) : "v"(ev[0]), "v"(ev[1]));
    asm("v_cvt_pk_bf16_f32 %0, %1, %2" : "=v"(pk.y) : "v"(ev[2]), "v"(ev[3]));
    asm("v_cvt_pk_bf16_f32 %0, %1, %2" : "=v"(pk.z) : "v"(ev[4]), "v"(ev[5]));
    asm("v_cvt_pk_bf16_f32 %0, %1, %2" : "=v"(pk.w) : "v"(ev[6]), "v"(ev[7]));
    int ck = (tid & ~7) | ((tid & 7) ^ (rl & 7));
    *(uint4*)(Abuf + (size_t)(row0 + rl) * 2048 + ck * 8) = pk;
  }
}

// =====================================================================
// Pipelined conv GEMM (unchanged — proven; grid 512 = 2 blocks/CU)
// =====================================================================
__global__ __launch_bounds__(256, 2) void convgemm_kernel(
    const u16* __restrict__ Abuf, const u16* __restrict__ w2b,
    cfp c2b, cfp g2, cfp b2, cfp m2, cfp v2,
    float* __restrict__ xsrc, u16* __restrict__ xpeb) {
  __shared__ short8v lds[3840];
  const int tid = threadIdx.x;
  const int mtile = blockIdx.x;
  const int wid = tid >> 6, lane = tid & 63;
  const int lrow = lane & 15, lk = lane >> 4;
  const int m0w = (wid & 1) * 16, n0w = (wid >> 1) * 64;

  float scn[4], cc[4], dv[4];
#pragma unroll
  for (int ni = 0; ni < 4; ++ni) {
    int n = n0w + ni * 16 + lrow;
    scn[ni] = g2[n] * __frsqrt_rn(v2[n] + kEps);
    cc[ni] = (c2b[n] - m2[n]) * scn[ni] + b2[n];
    dv[ni] = __expf((float)(n >> 1) * (-0.14391156824963732f)) * 0.125f;
  }

  f32x4 acc[4];
#pragma unroll
  for (int ni = 0; ni < 4; ++ni) acc[ni] = (f32x4){0.f, 0.f, 0.f, 0.f};

  const int q = wid * 64 + lane;
  const u16* aG = Abuf + (size_t)(mtile * 32 + (q >> 3)) * 2048 + (q & 7) * 8;

  auto stage = [&](int t) {
    int buf = t % 3;
    short8v* A = lds + buf * 1280;
    __builtin_amdgcn_global_load_lds(
        (const __attribute__((address_space(1))) void*)(aG + t * 64),
        (__attribute__((address_space(3))) void*)(A + wid * 64), 16, 0, 0);
#pragma unroll
    for (int r = 0; r < 4; ++r) {
      int qq = r * 256 + q;
      const u16* g = w2b + (size_t)(qq >> 3) * 2048 + t * 64 + (qq & 7) * 8;
      __builtin_amdgcn_global_load_lds(
          (const __attribute__((address_space(1))) void*)g,
          (__attribute__((address_space(3))) void*)(A + 256 + r * 256 + wid * 64), 16, 0, 0);
    }
  };

  auto compute = [&](int t) {
    int buf = t % 3;
    const short8v* A = lds + buf * 1280;
    const short8v* B = A + 256;
#pragma unroll
    for (int ks = 0; ks < 2; ++ks) {
      int ar = m0w + lrow;
      u32 ao = ((u32)(ar * 128 + ks * 64 + lk * 16)) ^ ((u32)((ar & 7) << 4));
      short8v af = A[ao >> 4];
#pragma unroll
      for (int ni = 0; ni < 4; ++ni) {
        int br = n0w + ni * 16 + lrow;
        u32 bo = ((u32)(br * 128 + ks * 64 + lk * 16)) ^ ((u32)((br & 7) << 4));
        short8v bf = B[bo >> 4];
        acc[ni] = __builtin_amdgcn_mfma_f32_16x16x32_bf16(af, bf, acc[ni], 0, 0, 0);
      }
    }
  };

  stage(0); stage(1); stage(2);
  for (int t = 0; t < 30; ++t) {
    wait_vmcnt<10>();
    __builtin_amdgcn_s_barrier();
    __builtin_amdgcn_sched_barrier(0);
    compute(t);
    asm volatile("" ::: "memory");
    __builtin_amdgcn_s_barrier();
    __builtin_amdgcn_sched_barrier(0);
    if (t <= 28) stage(t + 3);
  }
  wait_vmcnt<5>();
  __builtin_amdgcn_s_barrier();
  __builtin_amdgcn_sched_barrier(0);
  compute(30);
  asm volatile("" ::: "memory");
  __builtin_amdgcn_s_barrier();
  __builtin_amdgcn_sched_barrier(0);
  wait_vmcnt<0>();
  __builtin_amdgcn_s_barrier();
  __builtin_amdgcn_sched_barrier(0);
  compute(31);

#pragma unroll
  for (int ni = 0; ni < 4; ++ni) {
    int n = n0w + ni * 16 + lrow;
#pragma unroll
    for (int r = 0; r < 4; ++r) {
      int grow = mtile * 32 + m0w + lk * 4 + r;
      float gv = geluf(acc[ni][r] * scn[ni] + cc[ni]);
      xsrc[(size_t)grow * kE + n] = gv;
      int s = grow & 1023;
      float ang = (float)s * dv[ni];
      float pe = (n & 1) ? __cosf(ang) : __sinf(ang);
      xpeb[(size_t)grow * kE + n] = f2b(gv + pe);
    }
  }
}

// =====================================================================
// bf16 MFMA GEMM (QKV / FF1). MODE==1 z==0 (Q) pre-scaled by
// 128^-0.5*log2(e). MODE==2 writes ff1b chunk-permuted for ff2ln.
// =====================================================================
template<int ASRC, int MODE, int KTOT, int BM>
__global__ __launch_bounds__(256, 4) void gemm_kernel(
    const void* __restrict__ Ap, cfp Wf,
    cfp p0, cfp p1, cfp p2,
    void* __restrict__ Out, cfp res, int mbase) {
  constexpr int MI = BM / 32;
  __shared__ short8v Ab[BM * 8];
  __shared__ short8v Bb[512];

  int tid = threadIdx.x;
  int mtile = blockIdx.x, ntile = blockIdx.y;

  cfp Wsel = Wf;
  if (MODE == 1) Wsel = (blockIdx.z == 0) ? Wf : ((blockIdx.z == 1) ? p1 : p2);

  int wid = tid >> 6, lane = tid & 63;
  int m0w = (wid >> 1) * (BM / 2), n0w = (wid & 1) * 32;
  int lrow = lane & 15, lk = lane >> 4;

  f32x4 acc[MI][2];
#pragma unroll
  for (int mi = 0; mi < MI; ++mi)
#pragma unroll
    for (int ni = 0; ni < 2; ++ni) acc[mi][ni] = (f32x4){0.f, 0.f, 0.f, 0.f};

  for (int k0 = 0; k0 < KTOT; k0 += 64) {
    __syncthreads();
#pragma unroll
    for (int c = 0; c < BM / 32; ++c) {
      int chunk = tid + 256 * c;
      int row = chunk >> 3, kc = chunk & 7;
      int arow = mtile * BM + row;
      u32 off = ((u32)(row * 128 + kc * 16)) ^ ((u32)((row & 7) << 4));
      const u16* As = (const u16*)Ap + (size_t)arow * KTOT + k0 + kc * 8;
      Ab[off >> 4] = *(const short8v*)As;
    }
#pragma unroll
    for (int c = 0; c < 2; ++c) {
      int chunk = tid + 256 * c;
      int row = chunk >> 3, kc = chunk & 7;
      const float* Wp = Wsel + (size_t)(ntile * 64 + row) * KTOT + k0 + kc * 8;
      float4 xa = *(const float4*)Wp;
      float4 xb = *(const float4*)(Wp + 4);
      short8v sv;
      sv[0] = (short)f2b(xa.x); sv[1] = (short)f2b(xa.y);
      sv[2] = (short)f2b(xa.z); sv[3] = (short)f2b(xa.w);
      sv[4] = (short)f2b(xb.x); sv[5] = (short)f2b(xb.y);
      sv[6] = (short)f2b(xb.z); sv[7] = (short)f2b(xb.w);
      u32 off = ((u32)(row * 128 + kc * 16)) ^ ((u32)((row & 7) << 4));
      Bb[off >> 4] = sv;
    }
    __syncthreads();
#pragma unroll
    for (int ks = 0; ks < 2; ++ks) {
      short8v af[MI], bfr[2];
#pragma unroll
      for (int mi = 0; mi < MI; ++mi) {
        int row = m0w + mi * 16 + lrow;
        u32 off = ((u32)(row * 128 + ks * 64 + lk * 16)) ^ ((u32)((row & 7) << 4));
        af[mi] = Ab[off >> 4];
      }
#pragma unroll
      for (int ni = 0; ni < 2; ++ni) {
        int row = n0w + ni * 16 + lrow;
        u32 off = ((u32)(row * 128 + ks * 64 + lk * 16)) ^ ((u32)((row & 7) << 4));
        bfr[ni] = Bb[off >> 4];
      }
#pragma unroll
      for (int mi = 0; mi < MI; ++mi)
#pragma unroll
        for (int ni = 0; ni < 2; ++ni)
          acc[mi][ni] = __builtin_amdgcn_mfma_f32_16x16x32_bf16(af[mi], bfr[ni], acc[mi][ni], 0, 0, 0);
    }
  }

  const float qsc = 0.088388347648318447f * 1.4426950408889634f;
#pragma unroll
  for (int ni = 0; ni < 2; ++ni) {
    int n = ntile * 64 + n0w + ni * 16 + lrow;
    float c0 = 0.f;
    if (MODE == 2) c0 = p0[n];
#pragma unroll
    for (int mi = 0; mi < MI; ++mi) {
#pragma unroll
      for (int r = 0; r < 4; ++r) {
        int grow = mbase + mtile * BM + m0w + mi * 16 + lk * 4 + r;
        float val = acc[mi][ni][r];
        if (MODE == 1) {
          if (blockIdx.z == 0) val *= qsc;
          int s = grow & 1023, b_ = grow >> 10;
          u16* ob = (u16*)Out + (size_t)blockIdx.z * 2097152;
          ob[(((size_t)(b_ * kH + (n >> 4))) * kS + s) * kDH + (n & 15)] = f2b(val);
        } else if (MODE == 2) {
          int np = (n & ~56) | ((((n >> 3) ^ grow) & 7) << 3);
          ((u16*)Out)[(size_t)grow * kDFF + np] = f2b(fmaxf(val + c0, 0.f));
        }
      }
    }
  }
}

// =====================================================================
// FF2 pipelined + fused bias/residual/LN2/GAP epilogue (proven)
// =====================================================================
__global__ __launch_bounds__(256, 2) void ff2ln_kernel(
    const u16* __restrict__ Abuf, const u16* __restrict__ w2fb,
    cfp fb2, cfp l2g, cfp l2b, cfp res, float* __restrict__ dout) {
  __shared__ short8v lds[3840];
  __shared__ float st1[2][32], st2[2][32];
  __shared__ float red[128];
  const int tid = threadIdx.x;
  const int mtile = blockIdx.x;
  const int wid = tid >> 6, lane = tid & 63;
  const int lrow = lane & 15, lk = lane >> 4;
  const int m0w = (wid & 1) * 16, n0w = (wid >> 1) * 64;
  if (tid < 128) red[tid] = 0.f;

  float c0[4], gg[4], bb[4];
#pragma unroll
  for (int ni = 0; ni < 4; ++ni) {
    int n = n0w + ni * 16 + lrow;
    c0[ni] = fb2[n]; gg[ni] = l2g[n]; bb[ni] = l2b[n];
  }

  f32x4 acc[4];
#pragma unroll
  for (int ni = 0; ni < 4; ++ni) acc[ni] = (f32x4){0.f, 0.f, 0.f, 0.f};

  const int q = wid * 64 + lane;
  const u16* aG = Abuf + (size_t)(mtile * 32 + (q >> 3)) * 512 + (q & 7) * 8;

  auto stage = [&](int t) {
    int buf = t % 3;
    short8v* A = lds + buf * 1280;
    __builtin_amdgcn_global_load_lds(
        (const __attribute__((address_space(1))) void*)(aG + t * 64),
        (__attribute__((address_space(3))) void*)(A + wid * 64), 16, 0, 0);
#pragma unroll
    for (int r = 0; r < 4; ++r) {
      int qq = r * 256 + q;
      const u16* g = w2fb + (size_t)(qq >> 3) * 512 + t * 64 + (qq & 7) * 8;
      __builtin_amdgcn_global_load_lds(
          (const __attribute__((address_space(1))) void*)g,
          (__attribute__((address_space(3))) void*)(A + 256 + r * 256 + wid * 64), 16, 0, 0);
    }
  };

  auto compute = [&](int t) {
    int buf = t % 3;
    const short8v* A = lds + buf * 1280;
    const short8v* B = A + 256;
#pragma unroll
    for (int ks = 0; ks < 2; ++ks) {
      int ar = m0w + lrow;
      u32 ao = ((u32)(ar * 128 + ks * 64 + lk * 16)) ^ ((u32)((ar & 7) << 4));
      short8v af = A[ao >> 4];
#pragma unroll
      for (int ni = 0; ni < 4; ++ni) {
        int br = n0w + ni * 16 + lrow;
        u32 bo = ((u32)(br * 128 + ks * 64 + lk * 16)) ^ ((u32)((br & 7) << 4));
        short8v bf = B[bo >> 4];
        acc[ni] = __builtin_amdgcn_mfma_f32_16x16x32_bf16(af, bf, acc[ni], 0, 0, 0);
      }
    }
  };

  stage(0); stage(1); stage(2);
  for (int t = 0; t < 6; ++t) {
    wait_vmcnt<10>();
    __builtin_amdgcn_s_barrier();
    __builtin_amdgcn_sched_barrier(0);
    compute(t);
    asm volatile("" ::: "memory");
    __builtin_amdgcn_s_barrier();
    __builtin_amdgcn_sched_barrier(0);
    if (t <= 4) stage(t + 3);
  }
  wait_vmcnt<5>();
  __builtin_amdgcn_s_barrier();
  __builtin_amdgcn_sched_barrier(0);
  compute(6);
  asm volatile("" ::: "memory");
  __builtin_amdgcn_s_barrier();
  __builtin_amdgcn_sched_barrier(0);
  wait_vmcnt<0>();
  __builtin_amdgcn_s_barrier();
  __builtin_amdgcn_sched_barrier(0);
  compute(7);

  float y[4][4];
  float s1[4] = {0.f, 0.f, 0.f, 0.f}, s2[4] = {0.f, 0.f, 0.f, 0.f};
#pragma unroll
  for (int ni = 0; ni < 4; ++ni) {
    int n = n0w + ni * 16 + lrow;
#pragma unroll
    for (int r = 0; r < 4; ++r) {
      int grow = mtile * 32 + m0w + lk * 4 + r;
      float v = acc[ni][r] + c0[ni] + res[(size_t)grow * kE + n];
      y[ni][r] = v;
      s1[r] += v;
      s2[r] += v * v;
    }
  }
#pragma unroll
  for (int r = 0; r < 4; ++r) {
    for (int off = 1; off < 16; off <<= 1) {
      s1[r] += __shfl_xor(s1[r], off);
      s2[r] += __shfl_xor(s2[r], off);
    }
  }
  __syncthreads();
  if (lrow == 0) {
#pragma unroll
    for (int r = 0; r < 4; ++r) {
      int ridx = m0w + lk * 4 + r;
      st1[wid >> 1][ridx] = s1[r];
      st2[wid >> 1][ridx] = s2[r];
    }
  }
  __syncthreads();
  float colsum[4] = {0.f, 0.f, 0.f, 0.f};
#pragma unroll
  for (int r = 0; r < 4; ++r) {
    int ridx = m0w + lk * 4 + r;
    float t1 = st1[0][ridx] + st1[1][ridx];
    float t2 = st2[0][ridx] + st2[1][ridx];
    float mean = t1 * (1.f / 128.f);
    float var = t2 * (1.f / 128.f) - mean * mean;
    float inv = __frsqrt_rn(var + kEps);
#pragma unroll
    for (int ni = 0; ni < 4; ++ni)
      colsum[ni] += (y[ni][r] - mean) * inv * gg[ni] + bb[ni];
  }
#pragma unroll
  for (int ni = 0; ni < 4; ++ni) {
    colsum[ni] += __shfl_xor(colsum[ni], 16);
    colsum[ni] += __shfl_xor(colsum[ni], 32);
  }
  if (lk == 0) {
#pragma unroll
    for (int ni = 0; ni < 4; ++ni)
      atomicAdd(&red[n0w + ni * 16 + lrow], colsum[ni]);
  }
  __syncthreads();
  int b = mtile >> 5;
  if (tid < 128) atomicAdd(&dout[b * kE + tid], red[tid] * (1.f / 1024.f));
}

// =====================================================================
// MFMA attention v5 (unchanged — proven)
// =====================================================================
__global__ __launch_bounds__(512, 4) void attn_kernel(
    const u16* __restrict__ qb, const u16* __restrict__ kb,
    const u16* __restrict__ vb, const u16* __restrict__ rbT,
    float* __restrict__ o) {
  __shared__ u16 Vsh[16 * 1032];
  __shared__ u16 Pt[8][1280];

  int tid = threadIdx.x;
  int bid = blockIdx.x;
  int quarter = bid >> 7;
  int bb = (bid >> 3) & 15;
  int h = bid & 7;
  size_t base = (size_t)(bb * kH + h) * (kS * kDH);

  for (int j = tid; j < 1024; j += 512) {
    const uint4* src = (const uint4*)(vb + base + j * 16);
    uint4 a = src[0], b = src[1];
    u32 wv[8] = {a.x, a.y, a.z, a.w, b.x, b.y, b.z, b.w};
#pragma unroll
    for (int p = 0; p < 8; ++p) {
      Vsh[(2 * p) * 1032 + j]     = (u16)(wv[p] & 0xFFFFu);
      Vsh[(2 * p + 1) * 1032 + j] = (u16)(wv[p] >> 16);
    }
  }
  __syncthreads();

  int w = tid >> 6, l = tid & 63;
  int lr = l & 15, lg = l >> 4;
  int q32 = l & 31, hi = l >> 5;
  u16* P = Pt[w];
  int q0w = quarter * 256 + w * 32;
  int tbase = (q0w + 992) >> 4;
  const u16* rbh = rbT + (size_t)h * 126 * 512;

  short8v qf = *(const short8v*)(qb + base + (size_t)(q0w + q32) * 16 + hi * 8);
  short8v ones;
#pragma unroll
  for (int e = 0; e < 8; ++e) ones[e] = (short)0x3F80;

  f32x4 acc_e[2], acc_rb[2], acc_l[2];
#pragma unroll
  for (int qt = 0; qt < 2; ++qt) {
    acc_e[qt] = (f32x4){0.f, 0.f, 0.f, 0.f};
    acc_rb[qt] = (f32x4){0.f, 0.f, 0.f, 0.f};
    acc_l[qt] = (f32x4){0.f, 0.f, 0.f, 0.f};
  }
  const f32x16 z16 = {0.f,0.f,0.f,0.f,0.f,0.f,0.f,0.f,0.f,0.f,0.f,0.f,0.f,0.f,0.f,0.f};

  for (int jb = 0; jb < 32; ++jb) {
    short8v kf = *(const short8v*)(kb + base + (size_t)(jb * 32 + q32) * 16 + hi * 8);
    f32x16 s = __builtin_amdgcn_mfma_f32_32x32x16_bf16(kf, qf, z16, 0, 0, 0);
    float ev[16];
#pragma unroll
    for (int r = 0; r < 16; ++r) ev[r] = exp2f(s[r]);
#pragma unroll
    for (int rq = 0; rq < 4; ++rq) {
      u32 p0, p1;
      asm("v_cvt_pk_bf16_f32 %0, %1, %2" : "=v"(p0) : "v"(ev[4 * rq]), "v"(ev[4 * rq + 1]));
      asm("v_cvt_pk_bf16_f32 %0, %1, %2" : "=v"(p1) : "v"(ev[4 * rq + 2]), "v"(ev[4 * rq + 3]));
      *(uint2*)(P + q32 * 40 + rq * 8 + hi * 4) = make_uint2(p0, p1);
    }
    short8v vf = *(const short8v*)(Vsh + lr * 1032 + jb * 32 + lg * 8);
#pragma unroll
    for (int qt = 0; qt < 2; ++qt) {
      short8v pf = *(const short8v*)(P + (qt * 16 + lr) * 40 + lg * 8);
      int t = tbase + qt - 2 * jb;
      short8v rf = *(const short8v*)(rbh + ((size_t)t * 64 + l) * 8);
      acc_e[qt]  = __builtin_amdgcn_mfma_f32_16x16x32_bf16(pf, vf, acc_e[qt], 0, 0, 0);
      acc_l[qt]  = __builtin_amdgcn_mfma_f32_16x16x32_bf16(pf, ones, acc_l[qt], 0, 0, 0);
      acc_rb[qt] = __builtin_amdgcn_mfma_f32_16x16x32_bf16(rf, vf, acc_rb[qt], 0, 0, 0);
    }
  }

#pragma unroll
  for (int qt = 0; qt < 2; ++qt) {
#pragma unroll
    for (int r = 0; r < 4; ++r) {
      int qloc = qt * 16 + lg * 4 + r;
      int row = q0w + qloc;
      o[(size_t)(bb * kS + row) * kE + h * kDH + lr] =
          acc_e[qt][r] / acc_l[qt][r] + acc_rb[qt][r];
    }
  }
}

// ---------------- LN(attn out) + residual + LN1 -> att (f32 + bf16) ----------------
__global__ __launch_bounds__(256) void ln_kernel(
    cfp o, cfp xsrc, cfp lag, cfp lab, cfp l1g, cfp l1b,
    float* __restrict__ att, u16* __restrict__ attb) {
  int row = blockIdx.x * 4 + (threadIdx.x >> 6);
  int lane = threadIdx.x & 63;
  float2 a = ((const float2*)(o + (size_t)row * kE))[lane];
  float sum = a.x + a.y;
  for (int off = 1; off < 64; off <<= 1) sum += __shfl_xor(sum, off);
  float mean = sum * (1.f / 128.f);
  float d0 = a.x - mean, d1 = a.y - mean;
  float ss = d0 * d0 + d1 * d1;
  for (int off = 1; off < 64; off <<= 1) ss += __shfl_xor(ss, off);
  float inv = 1.f / sqrtf(ss * (1.f / 128.f) + kEps);
  float t0 = d0 * inv * lag[2 * lane] + lab[2 * lane];
  float t1 = d1 * inv * lag[2 * lane + 1] + lab[2 * lane + 1];
  float2 xv = ((const float2*)(xsrc + (size_t)row * kE))[lane];
  t0 += xv.x; t1 += xv.y;
  float sum2 = t0 + t1;
  for (int off = 1; off < 64; off <<= 1) sum2 += __shfl_xor(sum2, off);
  float mean2 = sum2 * (1.f / 128.f);
  float e0 = t0 - mean2, e1 = t1 - mean2;
  float ss2 = e0 * e0 + e1 * e1;
  for (int off = 1; off < 64; off <<= 1) ss2 += __shfl_xor(ss2, off);
  float inv2 = 1.f / sqrtf(ss2 * (1.f / 128.f) + kEps);
  float r0 = e0 * inv2 * l1g[2 * lane] + l1b[2 * lane];
  float r1 = e1 * inv2 * l1g[2 * lane + 1] + l1b[2 * lane + 1];
  ((float2*)(att + (size_t)row * kE))[lane] = make_float2(r0, r1);
  ((u32*)attb)[(size_t)row * 64 + lane] = (u32)f2b(r0) | ((u32)f2b(r1) << 16);
}

extern "C" void kernel_launch(void* const* d_in, const int* in_sizes, int n_in,
                              void* d_out, int out_size, void* d_ws, size_t ws_size,
                              hipStream_t stream) {
  const float* wf[27];
  for (int i = 0; i < n_in && i < 27; ++i) wf[i] = (const float*)d_in[i];

  float* ws = (float*)d_ws;
  float* xsrc  = ws;                             // 2,097,152 f32
  float* att   = xsrc + 2097152;                 // 2,097,152 f32
  float* qkv0  = att + 2097152;                  // 3,145,728 (q,k,v bf16)
  float* ext   = qkv0 + 3145728;                 // 1,048,576 (ff1b tail only)
  float* o     = ext + 1048576;                  // 2,097,152
  u16* xpeb    = (u16*)(o + 2097152);            // 2,097,152 u16
  u16* w2b     = xpeb + 2097152;                 // 262,144 u16
  u16* rbT     = w2b + 262144;                   // 516,096 u16
  u16* w2fb    = rbT + 516096;                   // 65,536 u16
  u16* Abuf    = w2fb + 65536;                   // 33,554,432 u16 (67 MB) — dedicated

  u16* qb = (u16*)qkv0;
  u16* kb = qb + 2097152;
  u16* vb = kb + 2097152;
  u16* ff1b = (u16*)qkv0;                        // spans qkv0+ext (dead q/k/v by then)
  u16* attb = xpeb;
  float* doutf = (float*)d_out;

  prep_kernel<<<413, 256, 0, stream>>>(wf[7], w2b, wf[16], rbT, wf[23], w2fb, doutf);

  convstage_kernel<<<2048, 256, 0, stream>>>(
      wf[0], wf[1], wf[2], wf[3], wf[4], wf[5], wf[6], Abuf);
  convgemm_kernel<<<512, 256, 0, stream>>>(
      Abuf, w2b, wf[8], wf[9], wf[10], wf[11], wf[12], xsrc, xpeb);

  gemm_kernel<3, 1, 128, 64><<<dim3(256, 2, 3), 256, 0, stream>>>(
      xpeb, wf[13], nullptr, wf[14], wf[15], qb, nullptr, 0);

  attn_kernel<<<512, 512, 0, stream>>>(qb, kb, vb, rbT, o);
  ln_kernel<<<4096, 256, 0, stream>>>(o, xsrc, wf[17], wf[18], wf[19], wf[20], att, attb);

  gemm_kernel<3, 2, 128, 64><<<dim3(256, 8), 256, 0, stream>>>(
      attb, wf[21], wf[22], nullptr, nullptr, ff1b, nullptr, 0);

  ff2ln_kernel<<<512, 256, 0, stream>>>(ff1b, w2fb, wf[24], wf[25], wf[26], att, doutf);
}

// Round 17
// 130.796 us; speedup vs baseline: 2.0411x; 1.0018x over previous
//
#include <hip/hip_runtime.h>
#include <hip/hip_bf16.h>
#include <math.h>

using bf16 = __hip_bfloat16;
typedef unsigned short u16;
typedef unsigned int u32;
typedef const float* __restrict__ cfp;
typedef const u16* __restrict__ cbu;

typedef __attribute__((ext_vector_type(8))) short short8v;
typedef __attribute__((ext_vector_type(4))) float f32x4;
typedef __attribute__((ext_vector_type(16))) float f32x16;

static constexpr int kS = 1024, kE = 128, kH = 8, kDH = 16, kDFF = 512;
static constexpr float kEps = 1e-5f;

__device__ __forceinline__ float geluf(float x) { return 0.5f * x * (1.f + erff(x * 0.70710678118654752f)); }
__device__ __forceinline__ float gelu_fast(float x) {
  float x2 = x * x;
  float u2 = 1.5957691216057308f * x * fmaf(0.044715f, x2, 1.f);
  float t = __expf(u2);
  return fmaf(-x, __frcp_rn(t + 1.f), x);
}
__device__ __forceinline__ u16 f2b(float f) {
  u32 u = __float_as_uint(f);
  u32 r = (u + 0x7FFFu + ((u >> 16) & 1u)) >> 16;
  return (u16)r;
}

template<int N> __device__ __forceinline__ void wait_vmcnt() {
  asm volatile("s_waitcnt vmcnt(%0)" :: "n"(N) : "memory");
  __builtin_amdgcn_sched_barrier(0);
}

// ---------------- prep: weight bf16 conversions + rbT table + zero d_out ----------------
__global__ __launch_bounds__(256) void prep_kernel(
    cfp w2, u16* __restrict__ w2b, cfp relb, u16* __restrict__ T,
    cfp fw2, u16* __restrict__ w2fb, float* __restrict__ dout,
    cfp wq, cfp wk, cfp wv, u16* __restrict__ wqkvb,
    cfp fw1, u16* __restrict__ w1fb) {
  int bid = blockIdx.x;
  if (bid < 128) {
    int n = bid, ck = threadIdx.x;
    const float* src = w2 + (size_t)n * 2048 + (size_t)ck * 8;
    float4 a = *(const float4*)src;
    float4 b = *(const float4*)(src + 4);
    short8v sv;
    sv[0] = (short)f2b(a.x); sv[1] = (short)f2b(a.y);
    sv[2] = (short)f2b(a.z); sv[3] = (short)f2b(a.w);
    sv[4] = (short)f2b(b.x); sv[5] = (short)f2b(b.y);
    sv[6] = (short)f2b(b.z); sv[7] = (short)f2b(b.w);
    int cd = (ck & ~7) | ((ck & 7) ^ (n & 7));
    *(short8v*)(w2b + (size_t)n * 2048 + cd * 8) = sv;
  } else if (bid < 380) {
    int idx = (bid - 128) * 4 + (threadIdx.x >> 6);   // 0..1007 = h*126+t
    int l = threadIdx.x & 63;
    int h = idx / 126, t = idx - h * 126;
    int lr = l & 15, lg = l >> 4;
    short8v v;
#pragma unroll
    for (int e = 0; e < 8; ++e) {
      int ix = 16 * t + 31 + lr - 8 * lg - e;
      v[e] = (short)f2b(relb[ix * 8 + h]);
    }
    *(short8v*)(T + ((size_t)(h * 126 + t) * 64 + l) * 8) = v;
  } else if (bid < 412) {
    int n = (bid - 380) * 4 + (threadIdx.x >> 6);     // 0..127
    int ck = threadIdx.x & 63;
    const float* src = fw2 + (size_t)n * 512 + (size_t)ck * 8;
    float4 a = *(const float4*)src;
    float4 b = *(const float4*)(src + 4);
    short8v sv;
    sv[0] = (short)f2b(a.x); sv[1] = (short)f2b(a.y);
    sv[2] = (short)f2b(a.z); sv[3] = (short)f2b(a.w);
    sv[4] = (short)f2b(b.x); sv[5] = (short)f2b(b.y);
    sv[6] = (short)f2b(b.z); sv[7] = (short)f2b(b.w);
    int cd = (ck & ~7) | ((ck & 7) ^ (n & 7));
    *(short8v*)(w2fb + (size_t)n * 512 + cd * 8) = sv;
  } else if (bid < 413) {
#pragma unroll
    for (int e = 0; e < 8; ++e) dout[threadIdx.x * 8 + e] = 0.f;
  } else if (bid < 437) {
    // wq/wk/wv -> bf16, row-major (3 x 16384)
    int g = (bid - 413) * 256 + threadIdx.x;          // chunk of 8, 0..6143
    int z = g >> 11, local = g & 2047;
    const float* src = ((z == 0) ? wq : (z == 1) ? wk : wv) + (size_t)local * 8;
    float4 a = *(const float4*)src;
    float4 b = *(const float4*)(src + 4);
    short8v sv;
    sv[0] = (short)f2b(a.x); sv[1] = (short)f2b(a.y);
    sv[2] = (short)f2b(a.z); sv[3] = (short)f2b(a.w);
    sv[4] = (short)f2b(b.x); sv[5] = (short)f2b(b.y);
    sv[6] = (short)f2b(b.z); sv[7] = (short)f2b(b.w);
    *(short8v*)(wqkvb + (size_t)z * 16384 + local * 8) = sv;
  } else {
    // ff w1 -> bf16, row-major (65536)
    int g = (bid - 437) * 256 + threadIdx.x;          // 0..8191
    const float* src = fw1 + (size_t)g * 8;
    float4 a = *(const float4*)src;
    float4 b = *(const float4*)(src + 4);
    short8v sv;
    sv[0] = (short)f2b(a.x); sv[1] = (short)f2b(a.y);
    sv[2] = (short)f2b(a.z); sv[3] = (short)f2b(a.w);
    sv[4] = (short)f2b(b.x); sv[5] = (short)f2b(b.y);
    sv[6] = (short)f2b(b.z); sv[7] = (short)f2b(b.w);
    *(short8v*)(w1fb + (size_t)g * 8) = sv;
  }
}

// ---------------- conv1+bn1+gelu -> Abuf bf16 [16384][2048], chunk-permuted ----------------
__global__ __launch_bounds__(256) void convstage_kernel(
    cfp x, cfp w1, cfp c1b, cfp g1, cfp b1, cfp m1, cfp v1,
    u16* __restrict__ Abuf) {
  __shared__ float xs[15][4];
  int row0 = blockIdx.x * 8;
  int b = row0 >> 10, s0 = row0 & 1023;
  int tid = threadIdx.x;
  if (tid < 15) {
    int gs = s0 - 3 + tid;
    float4 xv = (gs >= 0 && gs < kS) ? ((const float4*)x)[b * kS + gs]
                                     : make_float4(0.f, 0.f, 0.f, 0.f);
    xs[tid][0] = xv.x; xs[tid][1] = xv.y; xs[tid][2] = xv.z; xs[tid][3] = xv.w;
  }
  __syncthreads();

  float w[2][8], sc[2], ofs[2], cb[2];
#pragma unroll
  for (int cc = 0; cc < 2; ++cc) {
    int cx = tid * 2 + cc;
#pragma unroll
    for (int t = 0; t < 8; ++t) w[cc][t] = w1[cx * 8 + t];
    sc[cc] = g1[cx] * __frsqrt_rn(v1[cx] + kEps);
    ofs[cc] = b1[cx] - m1[cx] * sc[cc];
    cb[cc] = c1b[cx];
  }

  for (int rl = 0; rl < 8; ++rl) {
    float ev[8];
#pragma unroll
    for (int cc = 0; cc < 2; ++cc) {
#pragma unroll
      for (int rr = 0; rr < 4; ++rr) {
        float h = cb[cc];
#pragma unroll
        for (int t = 0; t < 8; ++t) h += xs[rl + t][rr] * w[cc][t];
        ev[cc * 4 + rr] = gelu_fast(h * sc[cc] + ofs[cc]);
      }
    }
    uint4 pk;
    asm("v_cvt_pk_bf16_f32 %0, %1, %2" : "=v"(pk.x) : "v"(ev[0]), "v"(ev[1]));
    asm("v_cvt_pk_bf16_f32 %0, %1, %2" : "=v"(pk.y) : "v"(ev[2]), "v"(ev[3]));
    asm("v_cvt_pk_bf16_f32 %0, %1, %2" : "=v"(pk.z) : "v"(ev[4]), "v"(ev[5]));
    asm("v_cvt_pk_bf16_f32 %0, %1, %2" : "=v"(pk.w) : "v"(ev[6]), "v"(ev[7]));
    int ck = (tid & ~7) | ((tid & 7) ^ (rl & 7));
    *(uint4*)(Abuf + (size_t)(row0 + rl) * 2048 + ck * 8) = pk;
  }
}

// =====================================================================
// Pipelined conv GEMM (unchanged — proven; grid 512 = 2 blocks/CU)
// =====================================================================
__global__ __launch_bounds__(256, 2) void convgemm_kernel(
    const u16* __restrict__ Abuf, const u16* __restrict__ w2b,
    cfp c2b, cfp g2, cfp b2, cfp m2, cfp v2,
    float* __restrict__ xsrc, u16* __restrict__ xpeb) {
  __shared__ short8v lds[3840];
  const int tid = threadIdx.x;
  const int mtile = blockIdx.x;
  const int wid = tid >> 6, lane = tid & 63;
  const int lrow = lane & 15, lk = lane >> 4;
  const int m0w = (wid & 1) * 16, n0w = (wid >> 1) * 64;

  float scn[4], cc[4], dv[4];
#pragma unroll
  for (int ni = 0; ni < 4; ++ni) {
    int n = n0w + ni * 16 + lrow;
    scn[ni] = g2[n] * __frsqrt_rn(v2[n] + kEps);
    cc[ni] = (c2b[n] - m2[n]) * scn[ni] + b2[n];
    dv[ni] = __expf((float)(n >> 1) * (-0.14391156824963732f)) * 0.125f;
  }

  f32x4 acc[4];
#pragma unroll
  for (int ni = 0; ni < 4; ++ni) acc[ni] = (f32x4){0.f, 0.f, 0.f, 0.f};

  const int q = wid * 64 + lane;
  const u16* aG = Abuf + (size_t)(mtile * 32 + (q >> 3)) * 2048 + (q & 7) * 8;

  auto stage = [&](int t) {
    int buf = t % 3;
    short8v* A = lds + buf * 1280;
    __builtin_amdgcn_global_load_lds(
        (const __attribute__((address_space(1))) void*)(aG + t * 64),
        (__attribute__((address_space(3))) void*)(A + wid * 64), 16, 0, 0);
#pragma unroll
    for (int r = 0; r < 4; ++r) {
      int qq = r * 256 + q;
      const u16* g = w2b + (size_t)(qq >> 3) * 2048 + t * 64 + (qq & 7) * 8;
      __builtin_amdgcn_global_load_lds(
          (const __attribute__((address_space(1))) void*)g,
          (__attribute__((address_space(3))) void*)(A + 256 + r * 256 + wid * 64), 16, 0, 0);
    }
  };

  auto compute = [&](int t) {
    int buf = t % 3;
    const short8v* A = lds + buf * 1280;
    const short8v* B = A + 256;
#pragma unroll
    for (int ks = 0; ks < 2; ++ks) {
      int ar = m0w + lrow;
      u32 ao = ((u32)(ar * 128 + ks * 64 + lk * 16)) ^ ((u32)((ar & 7) << 4));
      short8v af = A[ao >> 4];
#pragma unroll
      for (int ni = 0; ni < 4; ++ni) {
        int br = n0w + ni * 16 + lrow;
        u32 bo = ((u32)(br * 128 + ks * 64 + lk * 16)) ^ ((u32)((br & 7) << 4));
        short8v bf = B[bo >> 4];
        acc[ni] = __builtin_amdgcn_mfma_f32_16x16x32_bf16(af, bf, acc[ni], 0, 0, 0);
      }
    }
  };

  stage(0); stage(1); stage(2);
  for (int t = 0; t < 30; ++t) {
    wait_vmcnt<10>();
    __builtin_amdgcn_s_barrier();
    __builtin_amdgcn_sched_barrier(0);
    compute(t);
    asm volatile("" ::: "memory");
    __builtin_amdgcn_s_barrier();
    __builtin_amdgcn_sched_barrier(0);
    if (t <= 28) stage(t + 3);
  }
  wait_vmcnt<5>();
  __builtin_amdgcn_s_barrier();
  __builtin_amdgcn_sched_barrier(0);
  compute(30);
  asm volatile("" ::: "memory");
  __builtin_amdgcn_s_barrier();
  __builtin_amdgcn_sched_barrier(0);
  wait_vmcnt<0>();
  __builtin_amdgcn_s_barrier();
  __builtin_amdgcn_sched_barrier(0);
  compute(31);

#pragma unroll
  for (int ni = 0; ni < 4; ++ni) {
    int n = n0w + ni * 16 + lrow;
#pragma unroll
    for (int r = 0; r < 4; ++r) {
      int grow = mtile * 32 + m0w + lk * 4 + r;
      float gv = geluf(acc[ni][r] * scn[ni] + cc[ni]);
      xsrc[(size_t)grow * kE + n] = gv;
      int s = grow & 1023;
      float ang = (float)s * dv[ni];
      float pe = (n & 1) ? __cosf(ang) : __sinf(ang);
      xpeb[(size_t)grow * kE + n] = f2b(gv + pe);
    }
  }
}

// =====================================================================
// bf16 MFMA GEMM (QKV / FF1) — B matrices now pre-converted bf16.
// MODE==1 z==0 (Q) pre-scaled by 128^-0.5*log2(e).
// MODE==2 writes ff1b chunk-permuted for ff2ln.
// =====================================================================
template<int ASRC, int MODE, int KTOT, int BM>
__global__ __launch_bounds__(256, 4) void gemm_kernel(
    const void* __restrict__ Ap, cbu Wf,
    cfp p0, cbu p1, cbu p2,
    void* __restrict__ Out, cfp res, int mbase) {
  constexpr int MI = BM / 32;
  __shared__ short8v Ab[BM * 8];
  __shared__ short8v Bb[512];

  int tid = threadIdx.x;
  int mtile = blockIdx.x, ntile = blockIdx.y;

  cbu Wsel = Wf;
  if (MODE == 1) Wsel = (blockIdx.z == 0) ? Wf : ((blockIdx.z == 1) ? p1 : p2);

  int wid = tid >> 6, lane = tid & 63;
  int m0w = (wid >> 1) * (BM / 2), n0w = (wid & 1) * 32;
  int lrow = lane & 15, lk = lane >> 4;

  f32x4 acc[MI][2];
#pragma unroll
  for (int mi = 0; mi < MI; ++mi)
#pragma unroll
    for (int ni = 0; ni < 2; ++ni) acc[mi][ni] = (f32x4){0.f, 0.f, 0.f, 0.f};

  for (int k0 = 0; k0 < KTOT; k0 += 64) {
    __syncthreads();
#pragma unroll
    for (int c = 0; c < BM / 32; ++c) {
      int chunk = tid + 256 * c;
      int row = chunk >> 3, kc = chunk & 7;
      int arow = mtile * BM + row;
      u32 off = ((u32)(row * 128 + kc * 16)) ^ ((u32)((row & 7) << 4));
      const u16* As = (const u16*)Ap + (size_t)arow * KTOT + k0 + kc * 8;
      Ab[off >> 4] = *(const short8v*)As;
    }
#pragma unroll
    for (int c = 0; c < 2; ++c) {
      int chunk = tid + 256 * c;
      int row = chunk >> 3, kc = chunk & 7;
      const u16* Wp = Wsel + (size_t)(ntile * 64 + row) * KTOT + k0 + kc * 8;
      u32 off = ((u32)(row * 128 + kc * 16)) ^ ((u32)((row & 7) << 4));
      Bb[off >> 4] = *(const short8v*)Wp;
    }
    __syncthreads();
#pragma unroll
    for (int ks = 0; ks < 2; ++ks) {
      short8v af[MI], bfr[2];
#pragma unroll
      for (int mi = 0; mi < MI; ++mi) {
        int row = m0w + mi * 16 + lrow;
        u32 off = ((u32)(row * 128 + ks * 64 + lk * 16)) ^ ((u32)((row & 7) << 4));
        af[mi] = Ab[off >> 4];
      }
#pragma unroll
      for (int ni = 0; ni < 2; ++ni) {
        int row = n0w + ni * 16 + lrow;
        u32 off = ((u32)(row * 128 + ks * 64 + lk * 16)) ^ ((u32)((row & 7) << 4));
        bfr[ni] = Bb[off >> 4];
      }
#pragma unroll
      for (int mi = 0; mi < MI; ++mi)
#pragma unroll
        for (int ni = 0; ni < 2; ++ni)
          acc[mi][ni] = __builtin_amdgcn_mfma_f32_16x16x32_bf16(af[mi], bfr[ni], acc[mi][ni], 0, 0, 0);
    }
  }

  const float qsc = 0.088388347648318447f * 1.4426950408889634f;
#pragma unroll
  for (int ni = 0; ni < 2; ++ni) {
    int n = ntile * 64 + n0w + ni * 16 + lrow;
    float c0 = 0.f;
    if (MODE == 2) c0 = p0[n];
#pragma unroll
    for (int mi = 0; mi < MI; ++mi) {
#pragma unroll
      for (int r = 0; r < 4; ++r) {
        int grow = mbase + mtile * BM + m0w + mi * 16 + lk * 4 + r;
        float val = acc[mi][ni][r];
        if (MODE == 1) {
          if (blockIdx.z == 0) val *= qsc;
          int s = grow & 1023, b_ = grow >> 10;
          u16* ob = (u16*)Out + (size_t)blockIdx.z * 2097152;
          ob[(((size_t)(b_ * kH + (n >> 4))) * kS + s) * kDH + (n & 15)] = f2b(val);
        } else if (MODE == 2) {
          int np = (n & ~56) | ((((n >> 3) ^ grow) & 7) << 3);
          ((u16*)Out)[(size_t)grow * kDFF + np] = f2b(fmaxf(val + c0, 0.f));
        }
      }
    }
  }
}

// =====================================================================
// FF2 pipelined + fused bias/residual/LN2/GAP epilogue (proven)
// =====================================================================
__global__ __launch_bounds__(256, 2) void ff2ln_kernel(
    const u16* __restrict__ Abuf, const u16* __restrict__ w2fb,
    cfp fb2, cfp l2g, cfp l2b, cfp res, float* __restrict__ dout) {
  __shared__ short8v lds[3840];
  __shared__ float st1[2][32], st2[2][32];
  __shared__ float red[128];
  const int tid = threadIdx.x;
  const int mtile = blockIdx.x;
  const int wid = tid >> 6, lane = tid & 63;
  const int lrow = lane & 15, lk = lane >> 4;
  const int m0w = (wid & 1) * 16, n0w = (wid >> 1) * 64;
  if (tid < 128) red[tid] = 0.f;

  float c0[4], gg[4], bb[4];
#pragma unroll
  for (int ni = 0; ni < 4; ++ni) {
    int n = n0w + ni * 16 + lrow;
    c0[ni] = fb2[n]; gg[ni] = l2g[n]; bb[ni] = l2b[n];
  }

  f32x4 acc[4];
#pragma unroll
  for (int ni = 0; ni < 4; ++ni) acc[ni] = (f32x4){0.f, 0.f, 0.f, 0.f};

  const int q = wid * 64 + lane;
  const u16* aG = Abuf + (size_t)(mtile * 32 + (q >> 3)) * 512 + (q & 7) * 8;

  auto stage = [&](int t) {
    int buf = t % 3;
    short8v* A = lds + buf * 1280;
    __builtin_amdgcn_global_load_lds(
        (const __attribute__((address_space(1))) void*)(aG + t * 64),
        (__attribute__((address_space(3))) void*)(A + wid * 64), 16, 0, 0);
#pragma unroll
    for (int r = 0; r < 4; ++r) {
      int qq = r * 256 + q;
      const u16* g = w2fb + (size_t)(qq >> 3) * 512 + t * 64 + (qq & 7) * 8;
      __builtin_amdgcn_global_load_lds(
          (const __attribute__((address_space(1))) void*)g,
          (__attribute__((address_space(3))) void*)(A + 256 + r * 256 + wid * 64), 16, 0, 0);
    }
  };

  auto compute = [&](int t) {
    int buf = t % 3;
    const short8v* A = lds + buf * 1280;
    const short8v* B = A + 256;
#pragma unroll
    for (int ks = 0; ks < 2; ++ks) {
      int ar = m0w + lrow;
      u32 ao = ((u32)(ar * 128 + ks * 64 + lk * 16)) ^ ((u32)((ar & 7) << 4));
      short8v af = A[ao >> 4];
#pragma unroll
      for (int ni = 0; ni < 4; ++ni) {
        int br = n0w + ni * 16 + lrow;
        u32 bo = ((u32)(br * 128 + ks * 64 + lk * 16)) ^ ((u32)((br & 7) << 4));
        short8v bf = B[bo >> 4];
        acc[ni] = __builtin_amdgcn_mfma_f32_16x16x32_bf16(af, bf, acc[ni], 0, 0, 0);
      }
    }
  };

  stage(0); stage(1); stage(2);
  for (int t = 0; t < 6; ++t) {
    wait_vmcnt<10>();
    __builtin_amdgcn_s_barrier();
    __builtin_amdgcn_sched_barrier(0);
    compute(t);
    asm volatile("" ::: "memory");
    __builtin_amdgcn_s_barrier();
    __builtin_amdgcn_sched_barrier(0);
    if (t <= 4) stage(t + 3);
  }
  wait_vmcnt<5>();
  __builtin_amdgcn_s_barrier();
  __builtin_amdgcn_sched_barrier(0);
  compute(6);
  asm volatile("" ::: "memory");
  __builtin_amdgcn_s_barrier();
  __builtin_amdgcn_sched_barrier(0);
  wait_vmcnt<0>();
  __builtin_amdgcn_s_barrier();
  __builtin_amdgcn_sched_barrier(0);
  compute(7);

  float y[4][4];
  float s1[4] = {0.f, 0.f, 0.f, 0.f}, s2[4] = {0.f, 0.f, 0.f, 0.f};
#pragma unroll
  for (int ni = 0; ni < 4; ++ni) {
    int n = n0w + ni * 16 + lrow;
#pragma unroll
    for (int r = 0; r < 4; ++r) {
      int grow = mtile * 32 + m0w + lk * 4 + r;
      float v = acc[ni][r] + c0[ni] + res[(size_t)grow * kE + n];
      y[ni][r] = v;
      s1[r] += v;
      s2[r] += v * v;
    }
  }
#pragma unroll
  for (int r = 0; r < 4; ++r) {
    for (int off = 1; off < 16; off <<= 1) {
      s1[r] += __shfl_xor(s1[r], off);
      s2[r] += __shfl_xor(s2[r], off);
    }
  }
  __syncthreads();
  if (lrow == 0) {
#pragma unroll
    for (int r = 0; r < 4; ++r) {
      int ridx = m0w + lk * 4 + r;
      st1[wid >> 1][ridx] = s1[r];
      st2[wid >> 1][ridx] = s2[r];
    }
  }
  __syncthreads();
  float colsum[4] = {0.f, 0.f, 0.f, 0.f};
#pragma unroll
  for (int r = 0; r < 4; ++r) {
    int ridx = m0w + lk * 4 + r;
    float t1 = st1[0][ridx] + st1[1][ridx];
    float t2 = st2[0][ridx] + st2[1][ridx];
    float mean = t1 * (1.f / 128.f);
    float var = t2 * (1.f / 128.f) - mean * mean;
    float inv = __frsqrt_rn(var + kEps);
#pragma unroll
    for (int ni = 0; ni < 4; ++ni)
      colsum[ni] += (y[ni][r] - mean) * inv * gg[ni] + bb[ni];
  }
#pragma unroll
  for (int ni = 0; ni < 4; ++ni) {
    colsum[ni] += __shfl_xor(colsum[ni], 16);
    colsum[ni] += __shfl_xor(colsum[ni], 32);
  }
  if (lk == 0) {
#pragma unroll
    for (int ni = 0; ni < 4; ++ni)
      atomicAdd(&red[n0w + ni * 16 + lrow], colsum[ni]);
  }
  __syncthreads();
  int b = mtile >> 5;
  if (tid < 128) atomicAdd(&dout[b * kE + tid], red[tid] * (1.f / 1024.f));
}

// =====================================================================
// MFMA attention v6: 2-deep jb software pipeline (double-buffered P).
// QK(jb+1) issued before PV(jb) to break the serial dependency chain.
// =====================================================================
__global__ __launch_bounds__(512, 2) void attn_kernel(
    const u16* __restrict__ qb, const u16* __restrict__ kb,
    const u16* __restrict__ vb, const u16* __restrict__ rbT,
    float* __restrict__ o) {
  __shared__ u16 Vsh[16 * 1032];
  __shared__ u16 Pt[8][2560];    // 2 buffers x [32 q][40 k-stride]

  int tid = threadIdx.x;
  int bid = blockIdx.x;
  int quarter = bid >> 7;
  int bb = (bid >> 3) & 15;
  int h = bid & 7;
  size_t base = (size_t)(bb * kH + h) * (kS * kDH);

  for (int j = tid; j < 1024; j += 512) {
    const uint4* src = (const uint4*)(vb + base + j * 16);
    uint4 a = src[0], b = src[1];
    u32 wv[8] = {a.x, a.y, a.z, a.w, b.x, b.y, b.z, b.w};
#pragma unroll
    for (int p = 0; p < 8; ++p) {
      Vsh[(2 * p) * 1032 + j]     = (u16)(wv[p] & 0xFFFFu);
      Vsh[(2 * p + 1) * 1032 + j] = (u16)(wv[p] >> 16);
    }
  }
  __syncthreads();

  int w = tid >> 6, l = tid & 63;
  int lr = l & 15, lg = l >> 4;
  int q32 = l & 31, hi = l >> 5;
  u16* P = Pt[w];
  int q0w = quarter * 256 + w * 32;
  int tbase = (q0w + 992) >> 4;
  const u16* rbh = rbT + (size_t)h * 126 * 512;

  short8v qf = *(const short8v*)(qb + base + (size_t)(q0w + q32) * 16 + hi * 8);
  short8v ones;
#pragma unroll
  for (int e = 0; e < 8; ++e) ones[e] = (short)0x3F80;

  f32x4 acc_e[2], acc_rb[2], acc_l[2];
#pragma unroll
  for (int qt = 0; qt < 2; ++qt) {
    acc_e[qt] = (f32x4){0.f, 0.f, 0.f, 0.f};
    acc_rb[qt] = (f32x4){0.f, 0.f, 0.f, 0.f};
    acc_l[qt] = (f32x4){0.f, 0.f, 0.f, 0.f};
  }
  const f32x16 z16 = {0.f,0.f,0.f,0.f,0.f,0.f,0.f,0.f,0.f,0.f,0.f,0.f,0.f,0.f,0.f,0.f};

  auto expand_store = [&](const f32x16& s, int bufoff) {
    float ev[16];
#pragma unroll
    for (int r = 0; r < 16; ++r) ev[r] = exp2f(s[r]);
#pragma unroll
    for (int rq = 0; rq < 4; ++rq) {
      u32 p0, p1;
      asm("v_cvt_pk_bf16_f32 %0, %1, %2" : "=v"(p0) : "v"(ev[4 * rq]), "v"(ev[4 * rq + 1]));
      asm("v_cvt_pk_bf16_f32 %0, %1, %2" : "=v"(p1) : "v"(ev[4 * rq + 2]), "v"(ev[4 * rq + 3]));
      *(uint2*)(P + bufoff + q32 * 40 + rq * 8 + hi * 4) = make_uint2(p0, p1);
    }
  };

  // prologue: jb = 0
  {
    short8v kf = *(const short8v*)(kb + base + (size_t)(0 * 32 + q32) * 16 + hi * 8);
    f32x16 s = __builtin_amdgcn_mfma_f32_32x32x16_bf16(kf, qf, z16, 0, 0, 0);
    expand_store(s, 0);
  }

  for (int jb = 0; jb < 32; ++jb) {
    int cur = (jb & 1) * 1280;
    f32x16 s2;
    if (jb < 31) {
      short8v kf2 = *(const short8v*)(kb + base + (size_t)((jb + 1) * 32 + q32) * 16 + hi * 8);
      s2 = __builtin_amdgcn_mfma_f32_32x32x16_bf16(kf2, qf, z16, 0, 0, 0);
    }
    short8v vf = *(const short8v*)(Vsh + lr * 1032 + jb * 32 + lg * 8);
#pragma unroll
    for (int qt = 0; qt < 2; ++qt) {
      short8v pf = *(const short8v*)(P + cur + (qt * 16 + lr) * 40 + lg * 8);
      int t = tbase + qt - 2 * jb;
      short8v rf = *(const short8v*)(rbh + ((size_t)t * 64 + l) * 8);
      acc_e[qt]  = __builtin_amdgcn_mfma_f32_16x16x32_bf16(pf, vf, acc_e[qt], 0, 0, 0);
      acc_l[qt]  = __builtin_amdgcn_mfma_f32_16x16x32_bf16(pf, ones, acc_l[qt], 0, 0, 0);
      acc_rb[qt] = __builtin_amdgcn_mfma_f32_16x16x32_bf16(rf, vf, acc_rb[qt], 0, 0, 0);
    }
    if (jb < 31) expand_store(s2, 1280 - cur);
  }

#pragma unroll
  for (int qt = 0; qt < 2; ++qt) {
#pragma unroll
    for (int r = 0; r < 4; ++r) {
      int qloc = qt * 16 + lg * 4 + r;
      int row = q0w + qloc;
      o[(size_t)(bb * kS + row) * kE + h * kDH + lr] =
          acc_e[qt][r] / acc_l[qt][r] + acc_rb[qt][r];
    }
  }
}

// ---------------- LN(attn out) + residual + LN1 -> att (f32 + bf16) ----------------
__global__ __launch_bounds__(256) void ln_kernel(
    cfp o, cfp xsrc, cfp lag, cfp lab, cfp l1g, cfp l1b,
    float* __restrict__ att, u16* __restrict__ attb) {
  int row = blockIdx.x * 4 + (threadIdx.x >> 6);
  int lane = threadIdx.x & 63;
  float2 a = ((const float2*)(o + (size_t)row * kE))[lane];
  float sum = a.x + a.y;
  for (int off = 1; off < 64; off <<= 1) sum += __shfl_xor(sum, off);
  float mean = sum * (1.f / 128.f);
  float d0 = a.x - mean, d1 = a.y - mean;
  float ss = d0 * d0 + d1 * d1;
  for (int off = 1; off < 64; off <<= 1) ss += __shfl_xor(ss, off);
  float inv = 1.f / sqrtf(ss * (1.f / 128.f) + kEps);
  float t0 = d0 * inv * lag[2 * lane] + lab[2 * lane];
  float t1 = d1 * inv * lag[2 * lane + 1] + lab[2 * lane + 1];
  float2 xv = ((const float2*)(xsrc + (size_t)row * kE))[lane];
  t0 += xv.x; t1 += xv.y;
  float sum2 = t0 + t1;
  for (int off = 1; off < 64; off <<= 1) sum2 += __shfl_xor(sum2, off);
  float mean2 = sum2 * (1.f / 128.f);
  float e0 = t0 - mean2, e1 = t1 - mean2;
  float ss2 = e0 * e0 + e1 * e1;
  for (int off = 1; off < 64; off <<= 1) ss2 += __shfl_xor(ss2, off);
  float inv2 = 1.f / sqrtf(ss2 * (1.f / 128.f) + kEps);
  float r0 = e0 * inv2 * l1g[2 * lane] + l1b[2 * lane];
  float r1 = e1 * inv2 * l1g[2 * lane + 1] + l1b[2 * lane + 1];
  ((float2*)(att + (size_t)row * kE))[lane] = make_float2(r0, r1);
  ((u32*)attb)[(size_t)row * 64 + lane] = (u32)f2b(r0) | ((u32)f2b(r1) << 16);
}

extern "C" void kernel_launch(void* const* d_in, const int* in_sizes, int n_in,
                              void* d_out, int out_size, void* d_ws, size_t ws_size,
                              hipStream_t stream) {
  const float* wf[27];
  for (int i = 0; i < n_in && i < 27; ++i) wf[i] = (const float*)d_in[i];

  float* ws = (float*)d_ws;
  float* xsrc  = ws;                             // 2,097,152 f32
  float* att   = xsrc + 2097152;                 // 2,097,152 f32
  float* qkv0  = att + 2097152;                  // 3,145,728 (q,k,v bf16)
  float* ext   = qkv0 + 3145728;                 // 1,048,576 (ff1b tail only)
  float* o     = ext + 1048576;                  // 2,097,152
  u16* xpeb    = (u16*)(o + 2097152);            // 2,097,152 u16
  u16* w2b     = xpeb + 2097152;                 // 262,144 u16
  u16* rbT     = w2b + 262144;                   // 516,096 u16
  u16* w2fb    = rbT + 516096;                   // 65,536 u16
  u16* Abuf    = w2fb + 65536;                   // 33,554,432 u16 (67 MB)
  u16* wqkvb   = Abuf + 33554432;                // 49,152 u16 (wq,wk,wv bf16)
  u16* w1fb    = wqkvb + 49152;                  // 65,536 u16 (ff w1 bf16)

  u16* qb = (u16*)qkv0;
  u16* kb = qb + 2097152;
  u16* vb = kb + 2097152;
  u16* ff1b = (u16*)qkv0;                        // spans qkv0+ext (dead q/k/v by then)
  u16* attb = xpeb;
  float* doutf = (float*)d_out;

  prep_kernel<<<469, 256, 0, stream>>>(wf[7], w2b, wf[16], rbT, wf[23], w2fb, doutf,
                                       wf[13], wf[14], wf[15], wqkvb, wf[21], w1fb);

  convstage_kernel<<<2048, 256, 0, stream>>>(
      wf[0], wf[1], wf[2], wf[3], wf[4], wf[5], wf[6], Abuf);
  convgemm_kernel<<<512, 256, 0, stream>>>(
      Abuf, w2b, wf[8], wf[9], wf[10], wf[11], wf[12], xsrc, xpeb);

  gemm_kernel<3, 1, 128, 64><<<dim3(256, 2, 3), 256, 0, stream>>>(
      xpeb, wqkvb, nullptr, wqkvb + 16384, wqkvb + 32768, qb, nullptr, 0);

  attn_kernel<<<512, 512, 0, stream>>>(qb, kb, vb, rbT, o);
  ln_kernel<<<4096, 256, 0, stream>>>(o, xsrc, wf[17], wf[18], wf[19], wf[20], att, attb);

  gemm_kernel<3, 2, 128, 64><<<dim3(256, 8), 256, 0, stream>>>(
      attb, w1fb, wf[22], nullptr, nullptr, ff1b, nullptr, 0);

  ff2ln_kernel<<<512, 256, 0, stream>>>(ff1b, w2fb, wf[24], wf[25], wf[26], att, doutf);
}

// Round 18
// 130.013 us; speedup vs baseline: 2.0534x; 1.0060x over previous
//
#include <hip/hip_runtime.h>
#include <hip/hip_bf16.h>
#include <math.h>

using bf16 = __hip_bfloat16;
typedef unsigned short u16;
typedef unsigned int u32;
typedef const float* __restrict__ cfp;
typedef const u16* __restrict__ cbu;

typedef __attribute__((ext_vector_type(8))) short short8v;
typedef __attribute__((ext_vector_type(4))) float f32x4;
typedef __attribute__((ext_vector_type(16))) float f32x16;

static constexpr int kS = 1024, kE = 128, kH = 8, kDH = 16, kDFF = 512;
static constexpr float kEps = 1e-5f;

__device__ __forceinline__ float geluf(float x) { return 0.5f * x * (1.f + erff(x * 0.70710678118654752f)); }
__device__ __forceinline__ float gelu_fast(float x) {
  float x2 = x * x;
  float u2 = 1.5957691216057308f * x * fmaf(0.044715f, x2, 1.f);
  float t = __expf(u2);
  return fmaf(-x, __frcp_rn(t + 1.f), x);
}
__device__ __forceinline__ u16 f2b(float f) {
  u32 u = __float_as_uint(f);
  u32 r = (u + 0x7FFFu + ((u >> 16) & 1u)) >> 16;
  return (u16)r;
}

template<int N> __device__ __forceinline__ void wait_vmcnt() {
  asm volatile("s_waitcnt vmcnt(%0)" :: "n"(N) : "memory");
  __builtin_amdgcn_sched_barrier(0);
}

// ---------------- prep: weight bf16 conversions + rbT table + zero d_out ----------------
__global__ __launch_bounds__(256) void prep_kernel(
    cfp w2, u16* __restrict__ w2b, cfp relb, u16* __restrict__ T,
    cfp fw2, u16* __restrict__ w2fb, float* __restrict__ dout,
    cfp wq, cfp wk, cfp wv, u16* __restrict__ wqkvb,
    cfp fw1, u16* __restrict__ w1fb) {
  int bid = blockIdx.x;
  if (bid < 128) {
    int n = bid, ck = threadIdx.x;
    const float* src = w2 + (size_t)n * 2048 + (size_t)ck * 8;
    float4 a = *(const float4*)src;
    float4 b = *(const float4*)(src + 4);
    short8v sv;
    sv[0] = (short)f2b(a.x); sv[1] = (short)f2b(a.y);
    sv[2] = (short)f2b(a.z); sv[3] = (short)f2b(a.w);
    sv[4] = (short)f2b(b.x); sv[5] = (short)f2b(b.y);
    sv[6] = (short)f2b(b.z); sv[7] = (short)f2b(b.w);
    int cd = (ck & ~7) | ((ck & 7) ^ (n & 7));
    *(short8v*)(w2b + (size_t)n * 2048 + cd * 8) = sv;
  } else if (bid < 380) {
    int idx = (bid - 128) * 4 + (threadIdx.x >> 6);   // 0..1007 = h*126+t
    int l = threadIdx.x & 63;
    int h = idx / 126, t = idx - h * 126;
    int lr = l & 15, lg = l >> 4;
    short8v v;
#pragma unroll
    for (int e = 0; e < 8; ++e) {
      int ix = 16 * t + 31 + lr - 8 * lg - e;
      v[e] = (short)f2b(relb[ix * 8 + h]);
    }
    *(short8v*)(T + ((size_t)(h * 126 + t) * 64 + l) * 8) = v;
  } else if (bid < 412) {
    int n = (bid - 380) * 4 + (threadIdx.x >> 6);     // 0..127
    int ck = threadIdx.x & 63;
    const float* src = fw2 + (size_t)n * 512 + (size_t)ck * 8;
    float4 a = *(const float4*)src;
    float4 b = *(const float4*)(src + 4);
    short8v sv;
    sv[0] = (short)f2b(a.x); sv[1] = (short)f2b(a.y);
    sv[2] = (short)f2b(a.z); sv[3] = (short)f2b(a.w);
    sv[4] = (short)f2b(b.x); sv[5] = (short)f2b(b.y);
    sv[6] = (short)f2b(b.z); sv[7] = (short)f2b(b.w);
    int cd = (ck & ~7) | ((ck & 7) ^ (n & 7));
    *(short8v*)(w2fb + (size_t)n * 512 + cd * 8) = sv;
  } else if (bid < 413) {
#pragma unroll
    for (int e = 0; e < 8; ++e) dout[threadIdx.x * 8 + e] = 0.f;
  } else if (bid < 437) {
    int g = (bid - 413) * 256 + threadIdx.x;          // chunk of 8, 0..6143
    int z = g >> 11, local = g & 2047;
    const float* src = ((z == 0) ? wq : (z == 1) ? wk : wv) + (size_t)local * 8;
    float4 a = *(const float4*)src;
    float4 b = *(const float4*)(src + 4);
    short8v sv;
    sv[0] = (short)f2b(a.x); sv[1] = (short)f2b(a.y);
    sv[2] = (short)f2b(a.z); sv[3] = (short)f2b(a.w);
    sv[4] = (short)f2b(b.x); sv[5] = (short)f2b(b.y);
    sv[6] = (short)f2b(b.z); sv[7] = (short)f2b(b.w);
    *(short8v*)(wqkvb + (size_t)z * 16384 + local * 8) = sv;
  } else {
    int g = (bid - 437) * 256 + threadIdx.x;          // 0..8191
    const float* src = fw1 + (size_t)g * 8;
    float4 a = *(const float4*)src;
    float4 b = *(const float4*)(src + 4);
    short8v sv;
    sv[0] = (short)f2b(a.x); sv[1] = (short)f2b(a.y);
    sv[2] = (short)f2b(a.z); sv[3] = (short)f2b(a.w);
    sv[4] = (short)f2b(b.x); sv[5] = (short)f2b(b.y);
    sv[6] = (short)f2b(b.z); sv[7] = (short)f2b(b.w);
    *(short8v*)(w1fb + (size_t)g * 8) = sv;
  }
}

// ---------------- conv1+bn1+gelu -> Abuf bf16 [16384][2048], chunk-permuted ----------------
__global__ __launch_bounds__(256) void convstage_kernel(
    cfp x, cfp w1, cfp c1b, cfp g1, cfp b1, cfp m1, cfp v1,
    u16* __restrict__ Abuf) {
  __shared__ float xs[15][4];
  int row0 = blockIdx.x * 8;
  int b = row0 >> 10, s0 = row0 & 1023;
  int tid = threadIdx.x;
  if (tid < 15) {
    int gs = s0 - 3 + tid;
    float4 xv = (gs >= 0 && gs < kS) ? ((const float4*)x)[b * kS + gs]
                                     : make_float4(0.f, 0.f, 0.f, 0.f);
    xs[tid][0] = xv.x; xs[tid][1] = xv.y; xs[tid][2] = xv.z; xs[tid][3] = xv.w;
  }
  __syncthreads();

  float w[2][8], sc[2], ofs[2], cb[2];
#pragma unroll
  for (int cc = 0; cc < 2; ++cc) {
    int cx = tid * 2 + cc;
#pragma unroll
    for (int t = 0; t < 8; ++t) w[cc][t] = w1[cx * 8 + t];
    sc[cc] = g1[cx] * __frsqrt_rn(v1[cx] + kEps);
    ofs[cc] = b1[cx] - m1[cx] * sc[cc];
    cb[cc] = c1b[cx];
  }

  for (int rl = 0; rl < 8; ++rl) {
    float ev[8];
#pragma unroll
    for (int cc = 0; cc < 2; ++cc) {
#pragma unroll
      for (int rr = 0; rr < 4; ++rr) {
        float h = cb[cc];
#pragma unroll
        for (int t = 0; t < 8; ++t) h += xs[rl + t][rr] * w[cc][t];
        ev[cc * 4 + rr] = gelu_fast(h * sc[cc] + ofs[cc]);
      }
    }
    uint4 pk;
    asm("v_cvt_pk_bf16_f32 %0, %1, %2" : "=v"(pk.x) : "v"(ev[0]), "v"(ev[1]));
    asm("v_cvt_pk_bf16_f32 %0, %1, %2" : "=v"(pk.y) : "v"(ev[2]), "v"(ev[3]));
    asm("v_cvt_pk_bf16_f32 %0, %1, %2" : "=v"(pk.z) : "v"(ev[4]), "v"(ev[5]));
    asm("v_cvt_pk_bf16_f32 %0, %1, %2" : "=v"(pk.w) : "v"(ev[6]), "v"(ev[7]));
    int ck = (tid & ~7) | ((tid & 7) ^ (rl & 7));
    *(uint4*)(Abuf + (size_t)(row0 + rl) * 2048 + ck * 8) = pk;
  }
}

// =====================================================================
// Pipelined conv GEMM (unchanged — proven; grid 512 = 2 blocks/CU)
// =====================================================================
__global__ __launch_bounds__(256, 2) void convgemm_kernel(
    const u16* __restrict__ Abuf, const u16* __restrict__ w2b,
    cfp c2b, cfp g2, cfp b2, cfp m2, cfp v2,
    float* __restrict__ xsrc, u16* __restrict__ xpeb) {
  __shared__ short8v lds[3840];
  const int tid = threadIdx.x;
  const int mtile = blockIdx.x;
  const int wid = tid >> 6, lane = tid & 63;
  const int lrow = lane & 15, lk = lane >> 4;
  const int m0w = (wid & 1) * 16, n0w = (wid >> 1) * 64;

  float scn[4], cc[4], dv[4];
#pragma unroll
  for (int ni = 0; ni < 4; ++ni) {
    int n = n0w + ni * 16 + lrow;
    scn[ni] = g2[n] * __frsqrt_rn(v2[n] + kEps);
    cc[ni] = (c2b[n] - m2[n]) * scn[ni] + b2[n];
    dv[ni] = __expf((float)(n >> 1) * (-0.14391156824963732f)) * 0.125f;
  }

  f32x4 acc[4];
#pragma unroll
  for (int ni = 0; ni < 4; ++ni) acc[ni] = (f32x4){0.f, 0.f, 0.f, 0.f};

  const int q = wid * 64 + lane;
  const u16* aG = Abuf + (size_t)(mtile * 32 + (q >> 3)) * 2048 + (q & 7) * 8;

  auto stage = [&](int t) {
    int buf = t % 3;
    short8v* A = lds + buf * 1280;
    __builtin_amdgcn_global_load_lds(
        (const __attribute__((address_space(1))) void*)(aG + t * 64),
        (__attribute__((address_space(3))) void*)(A + wid * 64), 16, 0, 0);
#pragma unroll
    for (int r = 0; r < 4; ++r) {
      int qq = r * 256 + q;
      const u16* g = w2b + (size_t)(qq >> 3) * 2048 + t * 64 + (qq & 7) * 8;
      __builtin_amdgcn_global_load_lds(
          (const __attribute__((address_space(1))) void*)g,
          (__attribute__((address_space(3))) void*)(A + 256 + r * 256 + wid * 64), 16, 0, 0);
    }
  };

  auto compute = [&](int t) {
    int buf = t % 3;
    const short8v* A = lds + buf * 1280;
    const short8v* B = A + 256;
#pragma unroll
    for (int ks = 0; ks < 2; ++ks) {
      int ar = m0w + lrow;
      u32 ao = ((u32)(ar * 128 + ks * 64 + lk * 16)) ^ ((u32)((ar & 7) << 4));
      short8v af = A[ao >> 4];
#pragma unroll
      for (int ni = 0; ni < 4; ++ni) {
        int br = n0w + ni * 16 + lrow;
        u32 bo = ((u32)(br * 128 + ks * 64 + lk * 16)) ^ ((u32)((br & 7) << 4));
        short8v bf = B[bo >> 4];
        acc[ni] = __builtin_amdgcn_mfma_f32_16x16x32_bf16(af, bf, acc[ni], 0, 0, 0);
      }
    }
  };

  stage(0); stage(1); stage(2);
  for (int t = 0; t < 30; ++t) {
    wait_vmcnt<10>();
    __builtin_amdgcn_s_barrier();
    __builtin_amdgcn_sched_barrier(0);
    compute(t);
    asm volatile("" ::: "memory");
    __builtin_amdgcn_s_barrier();
    __builtin_amdgcn_sched_barrier(0);
    if (t <= 28) stage(t + 3);
  }
  wait_vmcnt<5>();
  __builtin_amdgcn_s_barrier();
  __builtin_amdgcn_sched_barrier(0);
  compute(30);
  asm volatile("" ::: "memory");
  __builtin_amdgcn_s_barrier();
  __builtin_amdgcn_sched_barrier(0);
  wait_vmcnt<0>();
  __builtin_amdgcn_s_barrier();
  __builtin_amdgcn_sched_barrier(0);
  compute(31);

#pragma unroll
  for (int ni = 0; ni < 4; ++ni) {
    int n = n0w + ni * 16 + lrow;
#pragma unroll
    for (int r = 0; r < 4; ++r) {
      int grow = mtile * 32 + m0w + lk * 4 + r;
      float gv = geluf(acc[ni][r] * scn[ni] + cc[ni]);
      xsrc[(size_t)grow * kE + n] = gv;
      int s = grow & 1023;
      float ang = (float)s * dv[ni];
      float pe = (n & 1) ? __cosf(ang) : __sinf(ang);
      xpeb[(size_t)grow * kE + n] = f2b(gv + pe);
    }
  }
}

// =====================================================================
// bf16 MFMA GEMM (QKV / FF1) — B matrices pre-converted bf16.
// =====================================================================
template<int ASRC, int MODE, int KTOT, int BM>
__global__ __launch_bounds__(256, 4) void gemm_kernel(
    const void* __restrict__ Ap, cbu Wf,
    cfp p0, cbu p1, cbu p2,
    void* __restrict__ Out, cfp res, int mbase) {
  constexpr int MI = BM / 32;
  __shared__ short8v Ab[BM * 8];
  __shared__ short8v Bb[512];

  int tid = threadIdx.x;
  int mtile = blockIdx.x, ntile = blockIdx.y;

  cbu Wsel = Wf;
  if (MODE == 1) Wsel = (blockIdx.z == 0) ? Wf : ((blockIdx.z == 1) ? p1 : p2);

  int wid = tid >> 6, lane = tid & 63;
  int m0w = (wid >> 1) * (BM / 2), n0w = (wid & 1) * 32;
  int lrow = lane & 15, lk = lane >> 4;

  f32x4 acc[MI][2];
#pragma unroll
  for (int mi = 0; mi < MI; ++mi)
#pragma unroll
    for (int ni = 0; ni < 2; ++ni) acc[mi][ni] = (f32x4){0.f, 0.f, 0.f, 0.f};

  for (int k0 = 0; k0 < KTOT; k0 += 64) {
    __syncthreads();
#pragma unroll
    for (int c = 0; c < BM / 32; ++c) {
      int chunk = tid + 256 * c;
      int row = chunk >> 3, kc = chunk & 7;
      int arow = mtile * BM + row;
      u32 off = ((u32)(row * 128 + kc * 16)) ^ ((u32)((row & 7) << 4));
      const u16* As = (const u16*)Ap + (size_t)arow * KTOT + k0 + kc * 8;
      Ab[off >> 4] = *(const short8v*)As;
    }
#pragma unroll
    for (int c = 0; c < 2; ++c) {
      int chunk = tid + 256 * c;
      int row = chunk >> 3, kc = chunk & 7;
      const u16* Wp = Wsel + (size_t)(ntile * 64 + row) * KTOT + k0 + kc * 8;
      u32 off = ((u32)(row * 128 + kc * 16)) ^ ((u32)((row & 7) << 4));
      Bb[off >> 4] = *(const short8v*)Wp;
    }
    __syncthreads();
#pragma unroll
    for (int ks = 0; ks < 2; ++ks) {
      short8v af[MI], bfr[2];
#pragma unroll
      for (int mi = 0; mi < MI; ++mi) {
        int row = m0w + mi * 16 + lrow;
        u32 off = ((u32)(row * 128 + ks * 64 + lk * 16)) ^ ((u32)((row & 7) << 4));
        af[mi] = Ab[off >> 4];
      }
#pragma unroll
      for (int ni = 0; ni < 2; ++ni) {
        int row = n0w + ni * 16 + lrow;
        u32 off = ((u32)(row * 128 + ks * 64 + lk * 16)) ^ ((u32)((row & 7) << 4));
        bfr[ni] = Bb[off >> 4];
      }
#pragma unroll
      for (int mi = 0; mi < MI; ++mi)
#pragma unroll
        for (int ni = 0; ni < 2; ++ni)
          acc[mi][ni] = __builtin_amdgcn_mfma_f32_16x16x32_bf16(af[mi], bfr[ni], acc[mi][ni], 0, 0, 0);
    }
  }

  const float qsc = 0.088388347648318447f * 1.4426950408889634f;
#pragma unroll
  for (int ni = 0; ni < 2; ++ni) {
    int n = ntile * 64 + n0w + ni * 16 + lrow;
    float c0 = 0.f;
    if (MODE == 2) c0 = p0[n];
#pragma unroll
    for (int mi = 0; mi < MI; ++mi) {
#pragma unroll
      for (int r = 0; r < 4; ++r) {
        int grow = mbase + mtile * BM + m0w + mi * 16 + lk * 4 + r;
        float val = acc[mi][ni][r];
        if (MODE == 1) {
          if (blockIdx.z == 0) val *= qsc;
          int s = grow & 1023, b_ = grow >> 10;
          u16* ob = (u16*)Out + (size_t)blockIdx.z * 2097152;
          ob[(((size_t)(b_ * kH + (n >> 4))) * kS + s) * kDH + (n & 15)] = f2b(val);
        } else if (MODE == 2) {
          int np = (n & ~56) | ((((n >> 3) ^ grow) & 7) << 3);
          ((u16*)Out)[(size_t)grow * kDFF + np] = f2b(fmaxf(val + c0, 0.f));
        }
      }
    }
  }
}

// =====================================================================
// FF2 pipelined + fused bias/residual/LN2/GAP epilogue (proven)
// =====================================================================
__global__ __launch_bounds__(256, 2) void ff2ln_kernel(
    const u16* __restrict__ Abuf, const u16* __restrict__ w2fb,
    cfp fb2, cfp l2g, cfp l2b, cfp res, float* __restrict__ dout) {
  __shared__ short8v lds[3840];
  __shared__ float st1[2][32], st2[2][32];
  __shared__ float red[128];
  const int tid = threadIdx.x;
  const int mtile = blockIdx.x;
  const int wid = tid >> 6, lane = tid & 63;
  const int lrow = lane & 15, lk = lane >> 4;
  const int m0w = (wid & 1) * 16, n0w = (wid >> 1) * 64;
  if (tid < 128) red[tid] = 0.f;

  float c0[4], gg[4], bb[4];
#pragma unroll
  for (int ni = 0; ni < 4; ++ni) {
    int n = n0w + ni * 16 + lrow;
    c0[ni] = fb2[n]; gg[ni] = l2g[n]; bb[ni] = l2b[n];
  }

  f32x4 acc[4];
#pragma unroll
  for (int ni = 0; ni < 4; ++ni) acc[ni] = (f32x4){0.f, 0.f, 0.f, 0.f};

  const int q = wid * 64 + lane;
  const u16* aG = Abuf + (size_t)(mtile * 32 + (q >> 3)) * 512 + (q & 7) * 8;

  auto stage = [&](int t) {
    int buf = t % 3;
    short8v* A = lds + buf * 1280;
    __builtin_amdgcn_global_load_lds(
        (const __attribute__((address_space(1))) void*)(aG + t * 64),
        (__attribute__((address_space(3))) void*)(A + wid * 64), 16, 0, 0);
#pragma unroll
    for (int r = 0; r < 4; ++r) {
      int qq = r * 256 + q;
      const u16* g = w2fb + (size_t)(qq >> 3) * 512 + t * 64 + (qq & 7) * 8;
      __builtin_amdgcn_global_load_lds(
          (const __attribute__((address_space(1))) void*)g,
          (__attribute__((address_space(3))) void*)(A + 256 + r * 256 + wid * 64), 16, 0, 0);
    }
  };

  auto compute = [&](int t) {
    int buf = t % 3;
    const short8v* A = lds + buf * 1280;
    const short8v* B = A + 256;
#pragma unroll
    for (int ks = 0; ks < 2; ++ks) {
      int ar = m0w + lrow;
      u32 ao = ((u32)(ar * 128 + ks * 64 + lk * 16)) ^ ((u32)((ar & 7) << 4));
      short8v af = A[ao >> 4];
#pragma unroll
      for (int ni = 0; ni < 4; ++ni) {
        int br = n0w + ni * 16 + lrow;
        u32 bo = ((u32)(br * 128 + ks * 64 + lk * 16)) ^ ((u32)((br & 7) << 4));
        short8v bf = B[bo >> 4];
        acc[ni] = __builtin_amdgcn_mfma_f32_16x16x32_bf16(af, bf, acc[ni], 0, 0, 0);
      }
    }
  };

  stage(0); stage(1); stage(2);
  for (int t = 0; t < 6; ++t) {
    wait_vmcnt<10>();
    __builtin_amdgcn_s_barrier();
    __builtin_amdgcn_sched_barrier(0);
    compute(t);
    asm volatile("" ::: "memory");
    __builtin_amdgcn_s_barrier();
    __builtin_amdgcn_sched_barrier(0);
    if (t <= 4) stage(t + 3);
  }
  wait_vmcnt<5>();
  __builtin_amdgcn_s_barrier();
  __builtin_amdgcn_sched_barrier(0);
  compute(6);
  asm volatile("" ::: "memory");
  __builtin_amdgcn_s_barrier();
  __builtin_amdgcn_sched_barrier(0);
  wait_vmcnt<0>();
  __builtin_amdgcn_s_barrier();
  __builtin_amdgcn_sched_barrier(0);
  compute(7);

  float y[4][4];
  float s1[4] = {0.f, 0.f, 0.f, 0.f}, s2[4] = {0.f, 0.f, 0.f, 0.f};
#pragma unroll
  for (int ni = 0; ni < 4; ++ni) {
    int n = n0w + ni * 16 + lrow;
#pragma unroll
    for (int r = 0; r < 4; ++r) {
      int grow = mtile * 32 + m0w + lk * 4 + r;
      float v = acc[ni][r] + c0[ni] + res[(size_t)grow * kE + n];
      y[ni][r] = v;
      s1[r] += v;
      s2[r] += v * v;
    }
  }
#pragma unroll
  for (int r = 0; r < 4; ++r) {
    for (int off = 1; off < 16; off <<= 1) {
      s1[r] += __shfl_xor(s1[r], off);
      s2[r] += __shfl_xor(s2[r], off);
    }
  }
  __syncthreads();
  if (lrow == 0) {
#pragma unroll
    for (int r = 0; r < 4; ++r) {
      int ridx = m0w + lk * 4 + r;
      st1[wid >> 1][ridx] = s1[r];
      st2[wid >> 1][ridx] = s2[r];
    }
  }
  __syncthreads();
  float colsum[4] = {0.f, 0.f, 0.f, 0.f};
#pragma unroll
  for (int r = 0; r < 4; ++r) {
    int ridx = m0w + lk * 4 + r;
    float t1 = st1[0][ridx] + st1[1][ridx];
    float t2 = st2[0][ridx] + st2[1][ridx];
    float mean = t1 * (1.f / 128.f);
    float var = t2 * (1.f / 128.f) - mean * mean;
    float inv = __frsqrt_rn(var + kEps);
#pragma unroll
    for (int ni = 0; ni < 4; ++ni)
      colsum[ni] += (y[ni][r] - mean) * inv * gg[ni] + bb[ni];
  }
#pragma unroll
  for (int ni = 0; ni < 4; ++ni) {
    colsum[ni] += __shfl_xor(colsum[ni], 16);
    colsum[ni] += __shfl_xor(colsum[ni], 32);
  }
  if (lk == 0) {
#pragma unroll
    for (int ni = 0; ni < 4; ++ni)
      atomicAdd(&red[n0w + ni * 16 + lrow], colsum[ni]);
  }
  __syncthreads();
  int b = mtile >> 5;
  if (tid < 128) atomicAdd(&dout[b * kE + tid], red[tid] * (1.f / 1024.f));
}

// =====================================================================
// MFMA attention v7: v5 body + 1-deep register prefetch of kf/rf
// (global-load latency rotation; pointer-stride addressing).
// =====================================================================
__global__ __launch_bounds__(512, 2) void attn_kernel(
    const u16* __restrict__ qb, const u16* __restrict__ kb,
    const u16* __restrict__ vb, const u16* __restrict__ rbT,
    float* __restrict__ o) {
  __shared__ u16 Vsh[16 * 1032];
  __shared__ u16 Pt[8][1280];

  int tid = threadIdx.x;
  int bid = blockIdx.x;
  int quarter = bid >> 7;
  int bb = (bid >> 3) & 15;
  int h = bid & 7;
  size_t base = (size_t)(bb * kH + h) * (kS * kDH);

  for (int j = tid; j < 1024; j += 512) {
    const uint4* src = (const uint4*)(vb + base + j * 16);
    uint4 a = src[0], b = src[1];
    u32 wv[8] = {a.x, a.y, a.z, a.w, b.x, b.y, b.z, b.w};
#pragma unroll
    for (int p = 0; p < 8; ++p) {
      Vsh[(2 * p) * 1032 + j]     = (u16)(wv[p] & 0xFFFFu);
      Vsh[(2 * p + 1) * 1032 + j] = (u16)(wv[p] >> 16);
    }
  }
  __syncthreads();

  int w = tid >> 6, l = tid & 63;
  int lr = l & 15, lg = l >> 4;
  int q32 = l & 31, hi = l >> 5;
  u16* P = Pt[w];
  int q0w = quarter * 256 + w * 32;
  int tbase = (q0w + 992) >> 4;
  const u16* rbh = rbT + (size_t)h * 126 * 512;

  short8v qf = *(const short8v*)(qb + base + (size_t)(q0w + q32) * 16 + hi * 8);
  short8v ones;
#pragma unroll
  for (int e = 0; e < 8; ++e) ones[e] = (short)0x3F80;

  f32x4 acc_e[2], acc_rb[2], acc_l[2];
#pragma unroll
  for (int qt = 0; qt < 2; ++qt) {
    acc_e[qt] = (f32x4){0.f, 0.f, 0.f, 0.f};
    acc_rb[qt] = (f32x4){0.f, 0.f, 0.f, 0.f};
    acc_l[qt] = (f32x4){0.f, 0.f, 0.f, 0.f};
  }
  const f32x16 z16 = {0.f,0.f,0.f,0.f,0.f,0.f,0.f,0.f,0.f,0.f,0.f,0.f,0.f,0.f,0.f,0.f};

  // pointer bases (constant per-iteration strides)
  const u16* kfp = kb + base + (size_t)q32 * 16 + hi * 8;          // += 512 u16 / jb
  const u16* rfp = rbh + (size_t)tbase * 512 + l * 8;              // -= 1024 u16 / jb

  short8v kf_c = *(const short8v*)kfp;
  short8v rf0_c = *(const short8v*)rfp;
  short8v rf1_c = *(const short8v*)(rfp + 512);

  for (int jb = 0; jb < 32; ++jb) {
    short8v kf_n, rf0_n, rf1_n;
    if (jb < 31) {
      kf_n = *(const short8v*)(kfp + (size_t)(jb + 1) * 512);
      const u16* rp = rfp - (size_t)(jb + 1) * 1024;
      rf0_n = *(const short8v*)rp;
      rf1_n = *(const short8v*)(rp + 512);
    }
    f32x16 s = __builtin_amdgcn_mfma_f32_32x32x16_bf16(kf_c, qf, z16, 0, 0, 0);
    float ev[16];
#pragma unroll
    for (int r = 0; r < 16; ++r) ev[r] = exp2f(s[r]);
#pragma unroll
    for (int rq = 0; rq < 4; ++rq) {
      u32 p0, p1;
      asm("v_cvt_pk_bf16_f32 %0, %1, %2" : "=v"(p0) : "v"(ev[4 * rq]), "v"(ev[4 * rq + 1]));
      asm("v_cvt_pk_bf16_f32 %0, %1, %2" : "=v"(p1) : "v"(ev[4 * rq + 2]), "v"(ev[4 * rq + 3]));
      *(uint2*)(P + q32 * 40 + rq * 8 + hi * 4) = make_uint2(p0, p1);
    }
    short8v vf = *(const short8v*)(Vsh + lr * 1032 + jb * 32 + lg * 8);
    {
      short8v pf0 = *(const short8v*)(P + lr * 40 + lg * 8);
      acc_e[0]  = __builtin_amdgcn_mfma_f32_16x16x32_bf16(pf0, vf, acc_e[0], 0, 0, 0);
      acc_l[0]  = __builtin_amdgcn_mfma_f32_16x16x32_bf16(pf0, ones, acc_l[0], 0, 0, 0);
      acc_rb[0] = __builtin_amdgcn_mfma_f32_16x16x32_bf16(rf0_c, vf, acc_rb[0], 0, 0, 0);
      short8v pf1 = *(const short8v*)(P + (16 + lr) * 40 + lg * 8);
      acc_e[1]  = __builtin_amdgcn_mfma_f32_16x16x32_bf16(pf1, vf, acc_e[1], 0, 0, 0);
      acc_l[1]  = __builtin_amdgcn_mfma_f32_16x16x32_bf16(pf1, ones, acc_l[1], 0, 0, 0);
      acc_rb[1] = __builtin_amdgcn_mfma_f32_16x16x32_bf16(rf1_c, vf, acc_rb[1], 0, 0, 0);
    }
    if (jb < 31) {
      kf_c = kf_n; rf0_c = rf0_n; rf1_c = rf1_n;
    }
  }

#pragma unroll
  for (int qt = 0; qt < 2; ++qt) {
#pragma unroll
    for (int r = 0; r < 4; ++r) {
      int qloc = qt * 16 + lg * 4 + r;
      int row = q0w + qloc;
      o[(size_t)(bb * kS + row) * kE + h * kDH + lr] =
          acc_e[qt][r] / acc_l[qt][r] + acc_rb[qt][r];
    }
  }
}

// ---------------- LN(attn out) + residual + LN1 -> att (f32 + bf16) ----------------
__global__ __launch_bounds__(256) void ln_kernel(
    cfp o, cfp xsrc, cfp lag, cfp lab, cfp l1g, cfp l1b,
    float* __restrict__ att, u16* __restrict__ attb) {
  int row = blockIdx.x * 4 + (threadIdx.x >> 6);
  int lane = threadIdx.x & 63;
  float2 a = ((const float2*)(o + (size_t)row * kE))[lane];
  float sum = a.x + a.y;
  for (int off = 1; off < 64; off <<= 1) sum += __shfl_xor(sum, off);
  float mean = sum * (1.f / 128.f);
  float d0 = a.x - mean, d1 = a.y - mean;
  float ss = d0 * d0 + d1 * d1;
  for (int off = 1; off < 64; off <<= 1) ss += __shfl_xor(ss, off);
  float inv = 1.f / sqrtf(ss * (1.f / 128.f) + kEps);
  float t0 = d0 * inv * lag[2 * lane] + lab[2 * lane];
  float t1 = d1 * inv * lag[2 * lane + 1] + lab[2 * lane + 1];
  float2 xv = ((const float2*)(xsrc + (size_t)row * kE))[lane];
  t0 += xv.x; t1 += xv.y;
  float sum2 = t0 + t1;
  for (int off = 1; off < 64; off <<= 1) sum2 += __shfl_xor(sum2, off);
  float mean2 = sum2 * (1.f / 128.f);
  float e0 = t0 - mean2, e1 = t1 - mean2;
  float ss2 = e0 * e0 + e1 * e1;
  for (int off = 1; off < 64; off <<= 1) ss2 += __shfl_xor(ss2, off);
  float inv2 = 1.f / sqrtf(ss2 * (1.f / 128.f) + kEps);
  float r0 = e0 * inv2 * l1g[2 * lane] + l1b[2 * lane];
  float r1 = e1 * inv2 * l1g[2 * lane + 1] + l1b[2 * lane + 1];
  ((float2*)(att + (size_t)row * kE))[lane] = make_float2(r0, r1);
  ((u32*)attb)[(size_t)row * 64 + lane] = (u32)f2b(r0) | ((u32)f2b(r1) << 16);
}

extern "C" void kernel_launch(void* const* d_in, const int* in_sizes, int n_in,
                              void* d_out, int out_size, void* d_ws, size_t ws_size,
                              hipStream_t stream) {
  const float* wf[27];
  for (int i = 0; i < n_in && i < 27; ++i) wf[i] = (const float*)d_in[i];

  float* ws = (float*)d_ws;
  float* xsrc  = ws;                             // 2,097,152 f32
  float* att   = xsrc + 2097152;                 // 2,097,152 f32
  float* qkv0  = att + 2097152;                  // 3,145,728 (q,k,v bf16)
  float* ext   = qkv0 + 3145728;                 // 1,048,576 (ff1b tail only)
  float* o     = ext + 1048576;                  // 2,097,152
  u16* xpeb    = (u16*)(o + 2097152);            // 2,097,152 u16
  u16* w2b     = xpeb + 2097152;                 // 262,144 u16
  u16* rbT     = w2b + 262144;                   // 516,096 u16
  u16* w2fb    = rbT + 516096;                   // 65,536 u16
  u16* Abuf    = w2fb + 65536;                   // 33,554,432 u16 (67 MB)
  u16* wqkvb   = Abuf + 33554432;                // 49,152 u16
  u16* w1fb    = wqkvb + 49152;                  // 65,536 u16

  u16* qb = (u16*)qkv0;
  u16* kb = qb + 2097152;
  u16* vb = kb + 2097152;
  u16* ff1b = (u16*)qkv0;
  u16* attb = xpeb;
  float* doutf = (float*)d_out;

  prep_kernel<<<469, 256, 0, stream>>>(wf[7], w2b, wf[16], rbT, wf[23], w2fb, doutf,
                                       wf[13], wf[14], wf[15], wqkvb, wf[21], w1fb);

  convstage_kernel<<<2048, 256, 0, stream>>>(
      wf[0], wf[1], wf[2], wf[3], wf[4], wf[5], wf[6], Abuf);
  convgemm_kernel<<<512, 256, 0, stream>>>(
      Abuf, w2b, wf[8], wf[9], wf[10], wf[11], wf[12], xsrc, xpeb);

  gemm_kernel<3, 1, 128, 64><<<dim3(256, 2, 3), 256, 0, stream>>>(
      xpeb, wqkvb, nullptr, wqkvb + 16384, wqkvb + 32768, qb, nullptr, 0);

  attn_kernel<<<512, 512, 0, stream>>>(qb, kb, vb, rbT, o);
  ln_kernel<<<4096, 256, 0, stream>>>(o, xsrc, wf[17], wf[18], wf[19], wf[20], att, attb);

  gemm_kernel<3, 2, 128, 64><<<dim3(256, 8), 256, 0, stream>>>(
      attb, w1fb, wf[22], nullptr, nullptr, ff1b, nullptr, 0);

  ff2ln_kernel<<<512, 256, 0, stream>>>(ff1b, w2fb, wf[24], wf[25], wf[26], att, doutf);
}

// Round 19
// 115.009 us; speedup vs baseline: 2.3213x; 1.1305x over previous
//
#include <hip/hip_runtime.h>
#include <hip/hip_bf16.h>
#include <math.h>

using bf16 = __hip_bfloat16;
typedef unsigned short u16;
typedef unsigned int u32;
typedef const float* __restrict__ cfp;
typedef const u16* __restrict__ cbu;

typedef __attribute__((ext_vector_type(8))) short short8v;
typedef __attribute__((ext_vector_type(4))) float f32x4;
typedef __attribute__((ext_vector_type(16))) float f32x16;

static constexpr int kS = 1024, kE = 128, kH = 8, kDH = 16, kDFF = 512;
static constexpr float kEps = 1e-5f;

__device__ __forceinline__ float geluf(float x) { return 0.5f * x * (1.f + erff(x * 0.70710678118654752f)); }
__device__ __forceinline__ float gelu_fast(float x) {
  float x2 = x * x;
  float u2 = 1.5957691216057308f * x * fmaf(0.044715f, x2, 1.f);
  float t = __expf(u2);
  return fmaf(-x, __frcp_rn(t + 1.f), x);
}
__device__ __forceinline__ u16 f2b(float f) {
  u32 u = __float_as_uint(f);
  u32 r = (u + 0x7FFFu + ((u >> 16) & 1u)) >> 16;
  return (u16)r;
}

template<int N> __device__ __forceinline__ void wait_vmcnt() {
  asm volatile("s_waitcnt vmcnt(%0)" :: "n"(N) : "memory");
  __builtin_amdgcn_sched_barrier(0);
}

// ---------------- prep: weight bf16 conversions + rbT table + zero d_out ----------------
__global__ __launch_bounds__(256) void prep_kernel(
    cfp w2, u16* __restrict__ w2b, cfp relb, u16* __restrict__ T,
    cfp fw2, u16* __restrict__ w2fb, float* __restrict__ dout,
    cfp wq, cfp wk, cfp wv, u16* __restrict__ wqkvb,
    cfp fw1, u16* __restrict__ w1fb) {
  int bid = blockIdx.x;
  if (bid < 128) {
    int n = bid, ck = threadIdx.x;
    const float* src = w2 + (size_t)n * 2048 + (size_t)ck * 8;
    float4 a = *(const float4*)src;
    float4 b = *(const float4*)(src + 4);
    short8v sv;
    sv[0] = (short)f2b(a.x); sv[1] = (short)f2b(a.y);
    sv[2] = (short)f2b(a.z); sv[3] = (short)f2b(a.w);
    sv[4] = (short)f2b(b.x); sv[5] = (short)f2b(b.y);
    sv[6] = (short)f2b(b.z); sv[7] = (short)f2b(b.w);
    int cd = (ck & ~7) | ((ck & 7) ^ (n & 7));
    *(short8v*)(w2b + (size_t)n * 2048 + cd * 8) = sv;
  } else if (bid < 380) {
    int idx = (bid - 128) * 4 + (threadIdx.x >> 6);   // 0..1007 = h*126+t
    int l = threadIdx.x & 63;
    int h = idx / 126, t = idx - h * 126;
    int lr = l & 15, lg = l >> 4;
    short8v v;
#pragma unroll
    for (int e = 0; e < 8; ++e) {
      int ix = 16 * t + 31 + lr - 8 * lg - e;
      v[e] = (short)f2b(relb[ix * 8 + h]);
    }
    *(short8v*)(T + ((size_t)(h * 126 + t) * 64 + l) * 8) = v;
  } else if (bid < 412) {
    int n = (bid - 380) * 4 + (threadIdx.x >> 6);     // 0..127
    int ck = threadIdx.x & 63;
    const float* src = fw2 + (size_t)n * 512 + (size_t)ck * 8;
    float4 a = *(const float4*)src;
    float4 b = *(const float4*)(src + 4);
    short8v sv;
    sv[0] = (short)f2b(a.x); sv[1] = (short)f2b(a.y);
    sv[2] = (short)f2b(a.z); sv[3] = (short)f2b(a.w);
    sv[4] = (short)f2b(b.x); sv[5] = (short)f2b(b.y);
    sv[6] = (short)f2b(b.z); sv[7] = (short)f2b(b.w);
    int cd = (ck & ~7) | ((ck & 7) ^ (n & 7));
    *(short8v*)(w2fb + (size_t)n * 512 + cd * 8) = sv;
  } else if (bid < 413) {
#pragma unroll
    for (int e = 0; e < 8; ++e) dout[threadIdx.x * 8 + e] = 0.f;
  } else if (bid < 437) {
    int g = (bid - 413) * 256 + threadIdx.x;          // chunk of 8, 0..6143
    int z = g >> 11, local = g & 2047;
    const float* src = ((z == 0) ? wq : (z == 1) ? wk : wv) + (size_t)local * 8;
    float4 a = *(const float4*)src;
    float4 b = *(const float4*)(src + 4);
    short8v sv;
    sv[0] = (short)f2b(a.x); sv[1] = (short)f2b(a.y);
    sv[2] = (short)f2b(a.z); sv[3] = (short)f2b(a.w);
    sv[4] = (short)f2b(b.x); sv[5] = (short)f2b(b.y);
    sv[6] = (short)f2b(b.z); sv[7] = (short)f2b(b.w);
    *(short8v*)(wqkvb + (size_t)z * 16384 + local * 8) = sv;
  } else {
    int g = (bid - 437) * 256 + threadIdx.x;          // 0..8191
    const float* src = fw1 + (size_t)g * 8;
    float4 a = *(const float4*)src;
    float4 b = *(const float4*)(src + 4);
    short8v sv;
    sv[0] = (short)f2b(a.x); sv[1] = (short)f2b(a.y);
    sv[2] = (short)f2b(a.z); sv[3] = (short)f2b(a.w);
    sv[4] = (short)f2b(b.x); sv[5] = (short)f2b(b.y);
    sv[6] = (short)f2b(b.z); sv[7] = (short)f2b(b.w);
    *(short8v*)(w1fb + (size_t)g * 8) = sv;
  }
}

// ---------------- conv1+bn1+gelu -> Abuf bf16 [16384][2048], chunk-permuted ----------------
__global__ __launch_bounds__(256) void convstage_kernel(
    cfp x, cfp w1, cfp c1b, cfp g1, cfp b1, cfp m1, cfp v1,
    u16* __restrict__ Abuf) {
  __shared__ float xs[15][4];
  int row0 = blockIdx.x * 8;
  int b = row0 >> 10, s0 = row0 & 1023;
  int tid = threadIdx.x;
  if (tid < 15) {
    int gs = s0 - 3 + tid;
    float4 xv = (gs >= 0 && gs < kS) ? ((const float4*)x)[b * kS + gs]
                                     : make_float4(0.f, 0.f, 0.f, 0.f);
    xs[tid][0] = xv.x; xs[tid][1] = xv.y; xs[tid][2] = xv.z; xs[tid][3] = xv.w;
  }
  __syncthreads();

  float w[2][8], sc[2], ofs[2], cb[2];
#pragma unroll
  for (int cc = 0; cc < 2; ++cc) {
    int cx = tid * 2 + cc;
#pragma unroll
    for (int t = 0; t < 8; ++t) w[cc][t] = w1[cx * 8 + t];
    sc[cc] = g1[cx] * __frsqrt_rn(v1[cx] + kEps);
    ofs[cc] = b1[cx] - m1[cx] * sc[cc];
    cb[cc] = c1b[cx];
  }

  for (int rl = 0; rl < 8; ++rl) {
    float ev[8];
#pragma unroll
    for (int cc = 0; cc < 2; ++cc) {
#pragma unroll
      for (int rr = 0; rr < 4; ++rr) {
        float h = cb[cc];
#pragma unroll
        for (int t = 0; t < 8; ++t) h += xs[rl + t][rr] * w[cc][t];
        ev[cc * 4 + rr] = gelu_fast(h * sc[cc] + ofs[cc]);
      }
    }
    uint4 pk;
    asm("v_cvt_pk_bf16_f32 %0, %1, %2" : "=v"(pk.x) : "v"(ev[0]), "v"(ev[1]));
    asm("v_cvt_pk_bf16_f32 %0, %1, %2" : "=v"(pk.y) : "v"(ev[2]), "v"(ev[3]));
    asm("v_cvt_pk_bf16_f32 %0, %1, %2" : "=v"(pk.z) : "v"(ev[4]), "v"(ev[5]));
    asm("v_cvt_pk_bf16_f32 %0, %1, %2" : "=v"(pk.w) : "v"(ev[6]), "v"(ev[7]));
    int ck = (tid & ~7) | ((tid & 7) ^ (rl & 7));
    *(uint4*)(Abuf + (size_t)(row0 + rl) * 2048 + ck * 8) = pk;
  }
}

// =====================================================================
// Pipelined conv GEMM (unchanged — proven; grid 512 = 2 blocks/CU)
// =====================================================================
__global__ __launch_bounds__(256, 2) void convgemm_kernel(
    const u16* __restrict__ Abuf, const u16* __restrict__ w2b,
    cfp c2b, cfp g2, cfp b2, cfp m2, cfp v2,
    float* __restrict__ xsrc, u16* __restrict__ xpeb) {
  __shared__ short8v lds[3840];
  const int tid = threadIdx.x;
  const int mtile = blockIdx.x;
  const int wid = tid >> 6, lane = tid & 63;
  const int lrow = lane & 15, lk = lane >> 4;
  const int m0w = (wid & 1) * 16, n0w = (wid >> 1) * 64;

  float scn[4], cc[4], dv[4];
#pragma unroll
  for (int ni = 0; ni < 4; ++ni) {
    int n = n0w + ni * 16 + lrow;
    scn[ni] = g2[n] * __frsqrt_rn(v2[n] + kEps);
    cc[ni] = (c2b[n] - m2[n]) * scn[ni] + b2[n];
    dv[ni] = __expf((float)(n >> 1) * (-0.14391156824963732f)) * 0.125f;
  }

  f32x4 acc[4];
#pragma unroll
  for (int ni = 0; ni < 4; ++ni) acc[ni] = (f32x4){0.f, 0.f, 0.f, 0.f};

  const int q = wid * 64 + lane;
  const u16* aG = Abuf + (size_t)(mtile * 32 + (q >> 3)) * 2048 + (q & 7) * 8;

  auto stage = [&](int t) {
    int buf = t % 3;
    short8v* A = lds + buf * 1280;
    __builtin_amdgcn_global_load_lds(
        (const __attribute__((address_space(1))) void*)(aG + t * 64),
        (__attribute__((address_space(3))) void*)(A + wid * 64), 16, 0, 0);
#pragma unroll
    for (int r = 0; r < 4; ++r) {
      int qq = r * 256 + q;
      const u16* g = w2b + (size_t)(qq >> 3) * 2048 + t * 64 + (qq & 7) * 8;
      __builtin_amdgcn_global_load_lds(
          (const __attribute__((address_space(1))) void*)g,
          (__attribute__((address_space(3))) void*)(A + 256 + r * 256 + wid * 64), 16, 0, 0);
    }
  };

  auto compute = [&](int t) {
    int buf = t % 3;
    const short8v* A = lds + buf * 1280;
    const short8v* B = A + 256;
#pragma unroll
    for (int ks = 0; ks < 2; ++ks) {
      int ar = m0w + lrow;
      u32 ao = ((u32)(ar * 128 + ks * 64 + lk * 16)) ^ ((u32)((ar & 7) << 4));
      short8v af = A[ao >> 4];
#pragma unroll
      for (int ni = 0; ni < 4; ++ni) {
        int br = n0w + ni * 16 + lrow;
        u32 bo = ((u32)(br * 128 + ks * 64 + lk * 16)) ^ ((u32)((br & 7) << 4));
        short8v bf = B[bo >> 4];
        acc[ni] = __builtin_amdgcn_mfma_f32_16x16x32_bf16(af, bf, acc[ni], 0, 0, 0);
      }
    }
  };

  stage(0); stage(1); stage(2);
  for (int t = 0; t < 30; ++t) {
    wait_vmcnt<10>();
    __builtin_amdgcn_s_barrier();
    __builtin_amdgcn_sched_barrier(0);
    compute(t);
    asm volatile("" ::: "memory");
    __builtin_amdgcn_s_barrier();
    __builtin_amdgcn_sched_barrier(0);
    if (t <= 28) stage(t + 3);
  }
  wait_vmcnt<5>();
  __builtin_amdgcn_s_barrier();
  __builtin_amdgcn_sched_barrier(0);
  compute(30);
  asm volatile("" ::: "memory");
  __builtin_amdgcn_s_barrier();
  __builtin_amdgcn_sched_barrier(0);
  wait_vmcnt<0>();
  __builtin_amdgcn_s_barrier();
  __builtin_amdgcn_sched_barrier(0);
  compute(31);

#pragma unroll
  for (int ni = 0; ni < 4; ++ni) {
    int n = n0w + ni * 16 + lrow;
#pragma unroll
    for (int r = 0; r < 4; ++r) {
      int grow = mtile * 32 + m0w + lk * 4 + r;
      float gv = geluf(acc[ni][r] * scn[ni] + cc[ni]);
      xsrc[(size_t)grow * kE + n] = gv;
      int s = grow & 1023;
      float ang = (float)s * dv[ni];
      float pe = (n & 1) ? __cosf(ang) : __sinf(ang);
      xpeb[(size_t)grow * kE + n] = f2b(gv + pe);
    }
  }
}

// =====================================================================
// bf16 MFMA GEMM (QKV / FF1) — B matrices pre-converted bf16.
// =====================================================================
template<int ASRC, int MODE, int KTOT, int BM>
__global__ __launch_bounds__(256, 4) void gemm_kernel(
    const void* __restrict__ Ap, cbu Wf,
    cfp p0, cbu p1, cbu p2,
    void* __restrict__ Out, cfp res, int mbase) {
  constexpr int MI = BM / 32;
  __shared__ short8v Ab[BM * 8];
  __shared__ short8v Bb[512];

  int tid = threadIdx.x;
  int mtile = blockIdx.x, ntile = blockIdx.y;

  cbu Wsel = Wf;
  if (MODE == 1) Wsel = (blockIdx.z == 0) ? Wf : ((blockIdx.z == 1) ? p1 : p2);

  int wid = tid >> 6, lane = tid & 63;
  int m0w = (wid >> 1) * (BM / 2), n0w = (wid & 1) * 32;
  int lrow = lane & 15, lk = lane >> 4;

  f32x4 acc[MI][2];
#pragma unroll
  for (int mi = 0; mi < MI; ++mi)
#pragma unroll
    for (int ni = 0; ni < 2; ++ni) acc[mi][ni] = (f32x4){0.f, 0.f, 0.f, 0.f};

  for (int k0 = 0; k0 < KTOT; k0 += 64) {
    __syncthreads();
#pragma unroll
    for (int c = 0; c < BM / 32; ++c) {
      int chunk = tid + 256 * c;
      int row = chunk >> 3, kc = chunk & 7;
      int arow = mtile * BM + row;
      u32 off = ((u32)(row * 128 + kc * 16)) ^ ((u32)((row & 7) << 4));
      const u16* As = (const u16*)Ap + (size_t)arow * KTOT + k0 + kc * 8;
      Ab[off >> 4] = *(const short8v*)As;
    }
#pragma unroll
    for (int c = 0; c < 2; ++c) {
      int chunk = tid + 256 * c;
      int row = chunk >> 3, kc = chunk & 7;
      const u16* Wp = Wsel + (size_t)(ntile * 64 + row) * KTOT + k0 + kc * 8;
      u32 off = ((u32)(row * 128 + kc * 16)) ^ ((u32)((row & 7) << 4));
      Bb[off >> 4] = *(const short8v*)Wp;
    }
    __syncthreads();
#pragma unroll
    for (int ks = 0; ks < 2; ++ks) {
      short8v af[MI], bfr[2];
#pragma unroll
      for (int mi = 0; mi < MI; ++mi) {
        int row = m0w + mi * 16 + lrow;
        u32 off = ((u32)(row * 128 + ks * 64 + lk * 16)) ^ ((u32)((row & 7) << 4));
        af[mi] = Ab[off >> 4];
      }
#pragma unroll
      for (int ni = 0; ni < 2; ++ni) {
        int row = n0w + ni * 16 + lrow;
        u32 off = ((u32)(row * 128 + ks * 64 + lk * 16)) ^ ((u32)((row & 7) << 4));
        bfr[ni] = Bb[off >> 4];
      }
#pragma unroll
      for (int mi = 0; mi < MI; ++mi)
#pragma unroll
        for (int ni = 0; ni < 2; ++ni)
          acc[mi][ni] = __builtin_amdgcn_mfma_f32_16x16x32_bf16(af[mi], bfr[ni], acc[mi][ni], 0, 0, 0);
    }
  }

  const float qsc = 0.088388347648318447f * 1.4426950408889634f;
#pragma unroll
  for (int ni = 0; ni < 2; ++ni) {
    int n = ntile * 64 + n0w + ni * 16 + lrow;
    float c0 = 0.f;
    if (MODE == 2) c0 = p0[n];
#pragma unroll
    for (int mi = 0; mi < MI; ++mi) {
#pragma unroll
      for (int r = 0; r < 4; ++r) {
        int grow = mbase + mtile * BM + m0w + mi * 16 + lk * 4 + r;
        float val = acc[mi][ni][r];
        if (MODE == 1) {
          if (blockIdx.z == 0) val *= qsc;
          int s = grow & 1023, b_ = grow >> 10;
          u16* ob = (u16*)Out + (size_t)blockIdx.z * 2097152;
          ob[(((size_t)(b_ * kH + (n >> 4))) * kS + s) * kDH + (n & 15)] = f2b(val);
        } else if (MODE == 2) {
          int np = (n & ~56) | ((((n >> 3) ^ grow) & 7) << 3);
          ((u16*)Out)[(size_t)grow * kDFF + np] = f2b(fmaxf(val + c0, 0.f));
        }
      }
    }
  }
}

// =====================================================================
// FF2 pipelined + fused bias/residual/LN2/GAP epilogue (proven)
// =====================================================================
__global__ __launch_bounds__(256, 2) void ff2ln_kernel(
    const u16* __restrict__ Abuf, const u16* __restrict__ w2fb,
    cfp fb2, cfp l2g, cfp l2b, cfp res, float* __restrict__ dout) {
  __shared__ short8v lds[3840];
  __shared__ float st1[2][32], st2[2][32];
  __shared__ float red[128];
  const int tid = threadIdx.x;
  const int mtile = blockIdx.x;
  const int wid = tid >> 6, lane = tid & 63;
  const int lrow = lane & 15, lk = lane >> 4;
  const int m0w = (wid & 1) * 16, n0w = (wid >> 1) * 64;
  if (tid < 128) red[tid] = 0.f;

  float c0[4], gg[4], bb[4];
#pragma unroll
  for (int ni = 0; ni < 4; ++ni) {
    int n = n0w + ni * 16 + lrow;
    c0[ni] = fb2[n]; gg[ni] = l2g[n]; bb[ni] = l2b[n];
  }

  f32x4 acc[4];
#pragma unroll
  for (int ni = 0; ni < 4; ++ni) acc[ni] = (f32x4){0.f, 0.f, 0.f, 0.f};

  const int q = wid * 64 + lane;
  const u16* aG = Abuf + (size_t)(mtile * 32 + (q >> 3)) * 512 + (q & 7) * 8;

  auto stage = [&](int t) {
    int buf = t % 3;
    short8v* A = lds + buf * 1280;
    __builtin_amdgcn_global_load_lds(
        (const __attribute__((address_space(1))) void*)(aG + t * 64),
        (__attribute__((address_space(3))) void*)(A + wid * 64), 16, 0, 0);
#pragma unroll
    for (int r = 0; r < 4; ++r) {
      int qq = r * 256 + q;
      const u16* g = w2fb + (size_t)(qq >> 3) * 512 + t * 64 + (qq & 7) * 8;
      __builtin_amdgcn_global_load_lds(
          (const __attribute__((address_space(1))) void*)g,
          (__attribute__((address_space(3))) void*)(A + 256 + r * 256 + wid * 64), 16, 0, 0);
    }
  };

  auto compute = [&](int t) {
    int buf = t % 3;
    const short8v* A = lds + buf * 1280;
    const short8v* B = A + 256;
#pragma unroll
    for (int ks = 0; ks < 2; ++ks) {
      int ar = m0w + lrow;
      u32 ao = ((u32)(ar * 128 + ks * 64 + lk * 16)) ^ ((u32)((ar & 7) << 4));
      short8v af = A[ao >> 4];
#pragma unroll
      for (int ni = 0; ni < 4; ++ni) {
        int br = n0w + ni * 16 + lrow;
        u32 bo = ((u32)(br * 128 + ks * 64 + lk * 16)) ^ ((u32)((br & 7) << 4));
        short8v bf = B[bo >> 4];
        acc[ni] = __builtin_amdgcn_mfma_f32_16x16x32_bf16(af, bf, acc[ni], 0, 0, 0);
      }
    }
  };

  stage(0); stage(1); stage(2);
  for (int t = 0; t < 6; ++t) {
    wait_vmcnt<10>();
    __builtin_amdgcn_s_barrier();
    __builtin_amdgcn_sched_barrier(0);
    compute(t);
    asm volatile("" ::: "memory");
    __builtin_amdgcn_s_barrier();
    __builtin_amdgcn_sched_barrier(0);
    if (t <= 4) stage(t + 3);
  }
  wait_vmcnt<5>();
  __builtin_amdgcn_s_barrier();
  __builtin_amdgcn_sched_barrier(0);
  compute(6);
  asm volatile("" ::: "memory");
  __builtin_amdgcn_s_barrier();
  __builtin_amdgcn_sched_barrier(0);
  wait_vmcnt<0>();
  __builtin_amdgcn_s_barrier();
  __builtin_amdgcn_sched_barrier(0);
  compute(7);

  float y[4][4];
  float s1[4] = {0.f, 0.f, 0.f, 0.f}, s2[4] = {0.f, 0.f, 0.f, 0.f};
#pragma unroll
  for (int ni = 0; ni < 4; ++ni) {
    int n = n0w + ni * 16 + lrow;
#pragma unroll
    for (int r = 0; r < 4; ++r) {
      int grow = mtile * 32 + m0w + lk * 4 + r;
      float v = acc[ni][r] + c0[ni] + res[(size_t)grow * kE + n];
      y[ni][r] = v;
      s1[r] += v;
      s2[r] += v * v;
    }
  }
#pragma unroll
  for (int r = 0; r < 4; ++r) {
    for (int off = 1; off < 16; off <<= 1) {
      s1[r] += __shfl_xor(s1[r], off);
      s2[r] += __shfl_xor(s2[r], off);
    }
  }
  __syncthreads();
  if (lrow == 0) {
#pragma unroll
    for (int r = 0; r < 4; ++r) {
      int ridx = m0w + lk * 4 + r;
      st1[wid >> 1][ridx] = s1[r];
      st2[wid >> 1][ridx] = s2[r];
    }
  }
  __syncthreads();
  float colsum[4] = {0.f, 0.f, 0.f, 0.f};
#pragma unroll
  for (int r = 0; r < 4; ++r) {
    int ridx = m0w + lk * 4 + r;
    float t1 = st1[0][ridx] + st1[1][ridx];
    float t2 = st2[0][ridx] + st2[1][ridx];
    float mean = t1 * (1.f / 128.f);
    float var = t2 * (1.f / 128.f) - mean * mean;
    float inv = __frsqrt_rn(var + kEps);
#pragma unroll
    for (int ni = 0; ni < 4; ++ni)
      colsum[ni] += (y[ni][r] - mean) * inv * gg[ni] + bb[ni];
  }
#pragma unroll
  for (int ni = 0; ni < 4; ++ni) {
    colsum[ni] += __shfl_xor(colsum[ni], 16);
    colsum[ni] += __shfl_xor(colsum[ni], 32);
  }
  if (lk == 0) {
#pragma unroll
    for (int ni = 0; ni < 4; ++ni)
      atomicAdd(&red[n0w + ni * 16 + lrow], colsum[ni]);
  }
  __syncthreads();
  int b = mtile >> 5;
  if (tid < 128) atomicAdd(&dout[b * kE + tid], red[tid] * (1.f / 1024.f));
}

// =====================================================================
// MFMA attention v8: v7 body with raw v_exp_f32 (exp2f was libm-expanded
// and dominated VALU issue — ~10 insts/call).
// =====================================================================
__global__ __launch_bounds__(512, 2) void attn_kernel(
    const u16* __restrict__ qb, const u16* __restrict__ kb,
    const u16* __restrict__ vb, const u16* __restrict__ rbT,
    float* __restrict__ o) {
  __shared__ u16 Vsh[16 * 1032];
  __shared__ u16 Pt[8][1280];

  int tid = threadIdx.x;
  int bid = blockIdx.x;
  int quarter = bid >> 7;
  int bb = (bid >> 3) & 15;
  int h = bid & 7;
  size_t base = (size_t)(bb * kH + h) * (kS * kDH);

  for (int j = tid; j < 1024; j += 512) {
    const uint4* src = (const uint4*)(vb + base + j * 16);
    uint4 a = src[0], b = src[1];
    u32 wv[8] = {a.x, a.y, a.z, a.w, b.x, b.y, b.z, b.w};
#pragma unroll
    for (int p = 0; p < 8; ++p) {
      Vsh[(2 * p) * 1032 + j]     = (u16)(wv[p] & 0xFFFFu);
      Vsh[(2 * p + 1) * 1032 + j] = (u16)(wv[p] >> 16);
    }
  }
  __syncthreads();

  int w = tid >> 6, l = tid & 63;
  int lr = l & 15, lg = l >> 4;
  int q32 = l & 31, hi = l >> 5;
  u16* P = Pt[w];
  int q0w = quarter * 256 + w * 32;
  int tbase = (q0w + 992) >> 4;
  const u16* rbh = rbT + (size_t)h * 126 * 512;

  short8v qf = *(const short8v*)(qb + base + (size_t)(q0w + q32) * 16 + hi * 8);
  short8v ones;
#pragma unroll
  for (int e = 0; e < 8; ++e) ones[e] = (short)0x3F80;

  f32x4 acc_e[2], acc_rb[2], acc_l[2];
#pragma unroll
  for (int qt = 0; qt < 2; ++qt) {
    acc_e[qt] = (f32x4){0.f, 0.f, 0.f, 0.f};
    acc_rb[qt] = (f32x4){0.f, 0.f, 0.f, 0.f};
    acc_l[qt] = (f32x4){0.f, 0.f, 0.f, 0.f};
  }
  const f32x16 z16 = {0.f,0.f,0.f,0.f,0.f,0.f,0.f,0.f,0.f,0.f,0.f,0.f,0.f,0.f,0.f,0.f};

  const u16* kfp = kb + base + (size_t)q32 * 16 + hi * 8;
  const u16* rfp = rbh + (size_t)tbase * 512 + l * 8;

  short8v kf_c = *(const short8v*)kfp;
  short8v rf0_c = *(const short8v*)rfp;
  short8v rf1_c = *(const short8v*)(rfp + 512);

  for (int jb = 0; jb < 32; ++jb) {
    short8v kf_n, rf0_n, rf1_n;
    if (jb < 31) {
      kf_n = *(const short8v*)(kfp + (size_t)(jb + 1) * 512);
      const u16* rp = rfp - (size_t)(jb + 1) * 1024;
      rf0_n = *(const short8v*)rp;
      rf1_n = *(const short8v*)(rp + 512);
    }
    f32x16 s = __builtin_amdgcn_mfma_f32_32x32x16_bf16(kf_c, qf, z16, 0, 0, 0);
    float ev[16];
#pragma unroll
    for (int r = 0; r < 16; ++r) ev[r] = __builtin_amdgcn_exp2f(s[r]);
#pragma unroll
    for (int rq = 0; rq < 4; ++rq) {
      u32 p0, p1;
      asm("v_cvt_pk_bf16_f32 %0, %1, %2" : "=v"(p0) : "v"(ev[4 * rq]), "v"(ev[4 * rq + 1]));
      asm("v_cvt_pk_bf16_f32 %0, %1, %2" : "=v"(p1) : "v"(ev[4 * rq + 2]), "v"(ev[4 * rq + 3]));
      *(uint2*)(P + q32 * 40 + rq * 8 + hi * 4) = make_uint2(p0, p1);
    }
    short8v vf = *(const short8v*)(Vsh + lr * 1032 + jb * 32 + lg * 8);
    {
      short8v pf0 = *(const short8v*)(P + lr * 40 + lg * 8);
      acc_e[0]  = __builtin_amdgcn_mfma_f32_16x16x32_bf16(pf0, vf, acc_e[0], 0, 0, 0);
      acc_l[0]  = __builtin_amdgcn_mfma_f32_16x16x32_bf16(pf0, ones, acc_l[0], 0, 0, 0);
      acc_rb[0] = __builtin_amdgcn_mfma_f32_16x16x32_bf16(rf0_c, vf, acc_rb[0], 0, 0, 0);
      short8v pf1 = *(const short8v*)(P + (16 + lr) * 40 + lg * 8);
      acc_e[1]  = __builtin_amdgcn_mfma_f32_16x16x32_bf16(pf1, vf, acc_e[1], 0, 0, 0);
      acc_l[1]  = __builtin_amdgcn_mfma_f32_16x16x32_bf16(pf1, ones, acc_l[1], 0, 0, 0);
      acc_rb[1] = __builtin_amdgcn_mfma_f32_16x16x32_bf16(rf1_c, vf, acc_rb[1], 0, 0, 0);
    }
    if (jb < 31) {
      kf_c = kf_n; rf0_c = rf0_n; rf1_c = rf1_n;
    }
  }

#pragma unroll
  for (int qt = 0; qt < 2; ++qt) {
#pragma unroll
    for (int r = 0; r < 4; ++r) {
      int qloc = qt * 16 + lg * 4 + r;
      int row = q0w + qloc;
      o[(size_t)(bb * kS + row) * kE + h * kDH + lr] =
          acc_e[qt][r] / acc_l[qt][r] + acc_rb[qt][r];
    }
  }
}

// ---------------- LN(attn out) + residual + LN1 -> att (f32 + bf16) ----------------
__global__ __launch_bounds__(256) void ln_kernel(
    cfp o, cfp xsrc, cfp lag, cfp lab, cfp l1g, cfp l1b,
    float* __restrict__ att, u16* __restrict__ attb) {
  int row = blockIdx.x * 4 + (threadIdx.x >> 6);
  int lane = threadIdx.x & 63;
  float2 a = ((const float2*)(o + (size_t)row * kE))[lane];
  float sum = a.x + a.y;
  for (int off = 1; off < 64; off <<= 1) sum += __shfl_xor(sum, off);
  float mean = sum * (1.f / 128.f);
  float d0 = a.x - mean, d1 = a.y - mean;
  float ss = d0 * d0 + d1 * d1;
  for (int off = 1; off < 64; off <<= 1) ss += __shfl_xor(ss, off);
  float inv = 1.f / sqrtf(ss * (1.f / 128.f) + kEps);
  float t0 = d0 * inv * lag[2 * lane] + lab[2 * lane];
  float t1 = d1 * inv * lag[2 * lane + 1] + lab[2 * lane + 1];
  float2 xv = ((const float2*)(xsrc + (size_t)row * kE))[lane];
  t0 += xv.x; t1 += xv.y;
  float sum2 = t0 + t1;
  for (int off = 1; off < 64; off <<= 1) sum2 += __shfl_xor(sum2, off);
  float mean2 = sum2 * (1.f / 128.f);
  float e0 = t0 - mean2, e1 = t1 - mean2;
  float ss2 = e0 * e0 + e1 * e1;
  for (int off = 1; off < 64; off <<= 1) ss2 += __shfl_xor(ss2, off);
  float inv2 = 1.f / sqrtf(ss2 * (1.f / 128.f) + kEps);
  float r0 = e0 * inv2 * l1g[2 * lane] + l1b[2 * lane];
  float r1 = e1 * inv2 * l1g[2 * lane + 1] + l1b[2 * lane + 1];
  ((float2*)(att + (size_t)row * kE))[lane] = make_float2(r0, r1);
  ((u32*)attb)[(size_t)row * 64 + lane] = (u32)f2b(r0) | ((u32)f2b(r1) << 16);
}

extern "C" void kernel_launch(void* const* d_in, const int* in_sizes, int n_in,
                              void* d_out, int out_size, void* d_ws, size_t ws_size,
                              hipStream_t stream) {
  const float* wf[27];
  for (int i = 0; i < n_in && i < 27; ++i) wf[i] = (const float*)d_in[i];

  float* ws = (float*)d_ws;
  float* xsrc  = ws;                             // 2,097,152 f32
  float* att   = xsrc + 2097152;                 // 2,097,152 f32
  float* qkv0  = att + 2097152;                  // 3,145,728 (q,k,v bf16)
  float* ext   = qkv0 + 3145728;                 // 1,048,576 (ff1b tail only)
  float* o     = ext + 1048576;                  // 2,097,152
  u16* xpeb    = (u16*)(o + 2097152);            // 2,097,152 u16
  u16* w2b     = xpeb + 2097152;                 // 262,144 u16
  u16* rbT     = w2b + 262144;                   // 516,096 u16
  u16* w2fb    = rbT + 516096;                   // 65,536 u16
  u16* Abuf    = w2fb + 65536;                   // 33,554,432 u16 (67 MB)
  u16* wqkvb   = Abuf + 33554432;                // 49,152 u16
  u16* w1fb    = wqkvb + 49152;                  // 65,536 u16

  u16* qb = (u16*)qkv0;
  u16* kb = qb + 2097152;
  u16* vb = kb + 2097152;
  u16* ff1b = (u16*)qkv0;
  u16* attb = xpeb;
  float* doutf = (float*)d_out;

  prep_kernel<<<469, 256, 0, stream>>>(wf[7], w2b, wf[16], rbT, wf[23], w2fb, doutf,
                                       wf[13], wf[14], wf[15], wqkvb, wf[21], w1fb);

  convstage_kernel<<<2048, 256, 0, stream>>>(
      wf[0], wf[1], wf[2], wf[3], wf[4], wf[5], wf[6], Abuf);
  convgemm_kernel<<<512, 256, 0, stream>>>(
      Abuf, w2b, wf[8], wf[9], wf[10], wf[11], wf[12], xsrc, xpeb);

  gemm_kernel<3, 1, 128, 64><<<dim3(256, 2, 3), 256, 0, stream>>>(
      xpeb, wqkvb, nullptr, wqkvb + 16384, wqkvb + 32768, qb, nullptr, 0);

  attn_kernel<<<512, 512, 0, stream>>>(qb, kb, vb, rbT, o);
  ln_kernel<<<4096, 256, 0, stream>>>(o, xsrc, wf[17], wf[18], wf[19], wf[20], att, attb);

  gemm_kernel<3, 2, 128, 64><<<dim3(256, 8), 256, 0, stream>>>(
      attb, w1fb, wf[22], nullptr, nullptr, ff1b, nullptr, 0);

  ff2ln_kernel<<<512, 256, 0, stream>>>(ff1b, w2fb, wf[24], wf[25], wf[26], att, doutf);
}

// Round 20
// 109.403 us; speedup vs baseline: 2.4402x; 1.0512x over previous
//
#include <hip/hip_runtime.h>
#include <hip/hip_bf16.h>
#include <math.h>

using bf16 = __hip_bfloat16;
typedef unsigned short u16;
typedef unsigned int u32;
typedef const float* __restrict__ cfp;
typedef const u16* __restrict__ cbu;

typedef __attribute__((ext_vector_type(8))) short short8v;
typedef __attribute__((ext_vector_type(4))) float f32x4;
typedef __attribute__((ext_vector_type(16))) float f32x16;

static constexpr int kS = 1024, kE = 128, kH = 8, kDH = 16, kDFF = 512;
static constexpr float kEps = 1e-5f;

__device__ __forceinline__ float geluf(float x) { return 0.5f * x * (1.f + erff(x * 0.70710678118654752f)); }
__device__ __forceinline__ float gelu_fast(float x) {
  float x2 = x * x;
  float u2 = 1.5957691216057308f * x * fmaf(0.044715f, x2, 1.f);
  float t = __expf(u2);
  return fmaf(-x, __frcp_rn(t + 1.f), x);
}
__device__ __forceinline__ u16 f2b(float f) {
  u32 u = __float_as_uint(f);
  u32 r = (u + 0x7FFFu + ((u >> 16) & 1u)) >> 16;
  return (u16)r;
}

template<int N> __device__ __forceinline__ void wait_vmcnt() {
  asm volatile("s_waitcnt vmcnt(%0)" :: "n"(N) : "memory");
  __builtin_amdgcn_sched_barrier(0);
}

// =====================================================================
// setup: conv1+bn1+gelu staging (blocks 0..2047) + weight conversions,
// rbT table, d_out zeroing (blocks 2048..2516). Independent outputs.
// =====================================================================
__global__ __launch_bounds__(256) void setup_kernel(
    cfp x, cfp w1, cfp c1b, cfp g1, cfp b1, cfp m1, cfp v1, u16* __restrict__ Abuf,
    cfp w2, u16* __restrict__ w2b, cfp relb, u16* __restrict__ T,
    cfp fw2, u16* __restrict__ w2fb, float* __restrict__ dout,
    cfp wq, cfp wk, cfp wv, u16* __restrict__ wqkvb,
    cfp fw1, u16* __restrict__ w1fb) {
  int tid = threadIdx.x;
  if (blockIdx.x < 2048) {
    __shared__ float xs[15][4];
    int row0 = blockIdx.x * 8;
    int b = row0 >> 10, s0 = row0 & 1023;
    if (tid < 15) {
      int gs = s0 - 3 + tid;
      float4 xv = (gs >= 0 && gs < kS) ? ((const float4*)x)[b * kS + gs]
                                       : make_float4(0.f, 0.f, 0.f, 0.f);
      xs[tid][0] = xv.x; xs[tid][1] = xv.y; xs[tid][2] = xv.z; xs[tid][3] = xv.w;
    }
    __syncthreads();

    float w[2][8], sc[2], ofs[2], cb[2];
#pragma unroll
    for (int cc = 0; cc < 2; ++cc) {
      int cx = tid * 2 + cc;
#pragma unroll
      for (int t = 0; t < 8; ++t) w[cc][t] = w1[cx * 8 + t];
      sc[cc] = g1[cx] * __frsqrt_rn(v1[cx] + kEps);
      ofs[cc] = b1[cx] - m1[cx] * sc[cc];
      cb[cc] = c1b[cx];
    }

    for (int rl = 0; rl < 8; ++rl) {
      float ev[8];
#pragma unroll
      for (int cc = 0; cc < 2; ++cc) {
#pragma unroll
        for (int rr = 0; rr < 4; ++rr) {
          float h = cb[cc];
#pragma unroll
          for (int t = 0; t < 8; ++t) h += xs[rl + t][rr] * w[cc][t];
          ev[cc * 4 + rr] = gelu_fast(h * sc[cc] + ofs[cc]);
        }
      }
      uint4 pk;
      asm("v_cvt_pk_bf16_f32 %0, %1, %2" : "=v"(pk.x) : "v"(ev[0]), "v"(ev[1]));
      asm("v_cvt_pk_bf16_f32 %0, %1, %2" : "=v"(pk.y) : "v"(ev[2]), "v"(ev[3]));
      asm("v_cvt_pk_bf16_f32 %0, %1, %2" : "=v"(pk.z) : "v"(ev[4]), "v"(ev[5]));
      asm("v_cvt_pk_bf16_f32 %0, %1, %2" : "=v"(pk.w) : "v"(ev[6]), "v"(ev[7]));
      int ck = (tid & ~7) | ((tid & 7) ^ (rl & 7));
      *(uint4*)(Abuf + (size_t)(row0 + rl) * 2048 + ck * 8) = pk;
    }
    return;
  }

  int bid = blockIdx.x - 2048;
  if (bid < 128) {
    int n = bid, ck = tid;
    const float* src = w2 + (size_t)n * 2048 + (size_t)ck * 8;
    float4 a = *(const float4*)src;
    float4 b = *(const float4*)(src + 4);
    short8v sv;
    sv[0] = (short)f2b(a.x); sv[1] = (short)f2b(a.y);
    sv[2] = (short)f2b(a.z); sv[3] = (short)f2b(a.w);
    sv[4] = (short)f2b(b.x); sv[5] = (short)f2b(b.y);
    sv[6] = (short)f2b(b.z); sv[7] = (short)f2b(b.w);
    int cd = (ck & ~7) | ((ck & 7) ^ (n & 7));
    *(short8v*)(w2b + (size_t)n * 2048 + cd * 8) = sv;
  } else if (bid < 380) {
    int idx = (bid - 128) * 4 + (tid >> 6);           // 0..1007 = h*126+t
    int l = tid & 63;
    int h = idx / 126, t = idx - h * 126;
    int lr = l & 15, lg = l >> 4;
    short8v v;
#pragma unroll
    for (int e = 0; e < 8; ++e) {
      int ix = 16 * t + 31 + lr - 8 * lg - e;
      v[e] = (short)f2b(relb[ix * 8 + h]);
    }
    *(short8v*)(T + ((size_t)(h * 126 + t) * 64 + l) * 8) = v;
  } else if (bid < 412) {
    int n = (bid - 380) * 4 + (tid >> 6);             // 0..127
    int ck = tid & 63;
    const float* src = fw2 + (size_t)n * 512 + (size_t)ck * 8;
    float4 a = *(const float4*)src;
    float4 b = *(const float4*)(src + 4);
    short8v sv;
    sv[0] = (short)f2b(a.x); sv[1] = (short)f2b(a.y);
    sv[2] = (short)f2b(a.z); sv[3] = (short)f2b(a.w);
    sv[4] = (short)f2b(b.x); sv[5] = (short)f2b(b.y);
    sv[6] = (short)f2b(b.z); sv[7] = (short)f2b(b.w);
    int cd = (ck & ~7) | ((ck & 7) ^ (n & 7));
    *(short8v*)(w2fb + (size_t)n * 512 + cd * 8) = sv;
  } else if (bid < 413) {
#pragma unroll
    for (int e = 0; e < 8; ++e) dout[tid * 8 + e] = 0.f;
  } else if (bid < 437) {
    int g = (bid - 413) * 256 + tid;                  // chunk of 8, 0..6143
    int z = g >> 11, local = g & 2047;
    const float* src = ((z == 0) ? wq : (z == 1) ? wk : wv) + (size_t)local * 8;
    float4 a = *(const float4*)src;
    float4 b = *(const float4*)(src + 4);
    short8v sv;
    sv[0] = (short)f2b(a.x); sv[1] = (short)f2b(a.y);
    sv[2] = (short)f2b(a.z); sv[3] = (short)f2b(a.w);
    sv[4] = (short)f2b(b.x); sv[5] = (short)f2b(b.y);
    sv[6] = (short)f2b(b.z); sv[7] = (short)f2b(b.w);
    *(short8v*)(wqkvb + (size_t)z * 16384 + local * 8) = sv;
  } else {
    int g = (bid - 437) * 256 + tid;                  // 0..8191
    const float* src = fw1 + (size_t)g * 8;
    float4 a = *(const float4*)src;
    float4 b = *(const float4*)(src + 4);
    short8v sv;
    sv[0] = (short)f2b(a.x); sv[1] = (short)f2b(a.y);
    sv[2] = (short)f2b(a.z); sv[3] = (short)f2b(a.w);
    sv[4] = (short)f2b(b.x); sv[5] = (short)f2b(b.y);
    sv[6] = (short)f2b(b.z); sv[7] = (short)f2b(b.w);
    *(short8v*)(w1fb + (size_t)g * 8) = sv;
  }
}

// =====================================================================
// Pipelined conv GEMM (unchanged — proven; grid 512 = 2 blocks/CU)
// =====================================================================
__global__ __launch_bounds__(256, 2) void convgemm_kernel(
    const u16* __restrict__ Abuf, const u16* __restrict__ w2b,
    cfp c2b, cfp g2, cfp b2, cfp m2, cfp v2,
    float* __restrict__ xsrc, u16* __restrict__ xpeb) {
  __shared__ short8v lds[3840];
  const int tid = threadIdx.x;
  const int mtile = blockIdx.x;
  const int wid = tid >> 6, lane = tid & 63;
  const int lrow = lane & 15, lk = lane >> 4;
  const int m0w = (wid & 1) * 16, n0w = (wid >> 1) * 64;

  float scn[4], cc[4], dv[4];
#pragma unroll
  for (int ni = 0; ni < 4; ++ni) {
    int n = n0w + ni * 16 + lrow;
    scn[ni] = g2[n] * __frsqrt_rn(v2[n] + kEps);
    cc[ni] = (c2b[n] - m2[n]) * scn[ni] + b2[n];
    dv[ni] = __expf((float)(n >> 1) * (-0.14391156824963732f)) * 0.125f;
  }

  f32x4 acc[4];
#pragma unroll
  for (int ni = 0; ni < 4; ++ni) acc[ni] = (f32x4){0.f, 0.f, 0.f, 0.f};

  const int q = wid * 64 + lane;
  const u16* aG = Abuf + (size_t)(mtile * 32 + (q >> 3)) * 2048 + (q & 7) * 8;

  auto stage = [&](int t) {
    int buf = t % 3;
    short8v* A = lds + buf * 1280;
    __builtin_amdgcn_global_load_lds(
        (const __attribute__((address_space(1))) void*)(aG + t * 64),
        (__attribute__((address_space(3))) void*)(A + wid * 64), 16, 0, 0);
#pragma unroll
    for (int r = 0; r < 4; ++r) {
      int qq = r * 256 + q;
      const u16* g = w2b + (size_t)(qq >> 3) * 2048 + t * 64 + (qq & 7) * 8;
      __builtin_amdgcn_global_load_lds(
          (const __attribute__((address_space(1))) void*)g,
          (__attribute__((address_space(3))) void*)(A + 256 + r * 256 + wid * 64), 16, 0, 0);
    }
  };

  auto compute = [&](int t) {
    int buf = t % 3;
    const short8v* A = lds + buf * 1280;
    const short8v* B = A + 256;
#pragma unroll
    for (int ks = 0; ks < 2; ++ks) {
      int ar = m0w + lrow;
      u32 ao = ((u32)(ar * 128 + ks * 64 + lk * 16)) ^ ((u32)((ar & 7) << 4));
      short8v af = A[ao >> 4];
#pragma unroll
      for (int ni = 0; ni < 4; ++ni) {
        int br = n0w + ni * 16 + lrow;
        u32 bo = ((u32)(br * 128 + ks * 64 + lk * 16)) ^ ((u32)((br & 7) << 4));
        short8v bf = B[bo >> 4];
        acc[ni] = __builtin_amdgcn_mfma_f32_16x16x32_bf16(af, bf, acc[ni], 0, 0, 0);
      }
    }
  };

  stage(0); stage(1); stage(2);
  for (int t = 0; t < 30; ++t) {
    wait_vmcnt<10>();
    __builtin_amdgcn_s_barrier();
    __builtin_amdgcn_sched_barrier(0);
    compute(t);
    asm volatile("" ::: "memory");
    __builtin_amdgcn_s_barrier();
    __builtin_amdgcn_sched_barrier(0);
    if (t <= 28) stage(t + 3);
  }
  wait_vmcnt<5>();
  __builtin_amdgcn_s_barrier();
  __builtin_amdgcn_sched_barrier(0);
  compute(30);
  asm volatile("" ::: "memory");
  __builtin_amdgcn_s_barrier();
  __builtin_amdgcn_sched_barrier(0);
  wait_vmcnt<0>();
  __builtin_amdgcn_s_barrier();
  __builtin_amdgcn_sched_barrier(0);
  compute(31);

#pragma unroll
  for (int ni = 0; ni < 4; ++ni) {
    int n = n0w + ni * 16 + lrow;
#pragma unroll
    for (int r = 0; r < 4; ++r) {
      int grow = mtile * 32 + m0w + lk * 4 + r;
      float gv = geluf(acc[ni][r] * scn[ni] + cc[ni]);
      xsrc[(size_t)grow * kE + n] = gv;
      int s = grow & 1023;
      float ang = (float)s * dv[ni];
      float pe = (n & 1) ? __cosf(ang) : __sinf(ang);
      xpeb[(size_t)grow * kE + n] = f2b(gv + pe);
    }
  }
}

// =====================================================================
// bf16 MFMA GEMM (QKV / FF1) — B matrices pre-converted bf16.
// =====================================================================
template<int ASRC, int MODE, int KTOT, int BM>
__global__ __launch_bounds__(256, 4) void gemm_kernel(
    const void* __restrict__ Ap, cbu Wf,
    cfp p0, cbu p1, cbu p2,
    void* __restrict__ Out, cfp res, int mbase) {
  constexpr int MI = BM / 32;
  __shared__ short8v Ab[BM * 8];
  __shared__ short8v Bb[512];

  int tid = threadIdx.x;
  int mtile = blockIdx.x, ntile = blockIdx.y;

  cbu Wsel = Wf;
  if (MODE == 1) Wsel = (blockIdx.z == 0) ? Wf : ((blockIdx.z == 1) ? p1 : p2);

  int wid = tid >> 6, lane = tid & 63;
  int m0w = (wid >> 1) * (BM / 2), n0w = (wid & 1) * 32;
  int lrow = lane & 15, lk = lane >> 4;

  f32x4 acc[MI][2];
#pragma unroll
  for (int mi = 0; mi < MI; ++mi)
#pragma unroll
    for (int ni = 0; ni < 2; ++ni) acc[mi][ni] = (f32x4){0.f, 0.f, 0.f, 0.f};

  for (int k0 = 0; k0 < KTOT; k0 += 64) {
    __syncthreads();
#pragma unroll
    for (int c = 0; c < BM / 32; ++c) {
      int chunk = tid + 256 * c;
      int row = chunk >> 3, kc = chunk & 7;
      int arow = mtile * BM + row;
      u32 off = ((u32)(row * 128 + kc * 16)) ^ ((u32)((row & 7) << 4));
      const u16* As = (const u16*)Ap + (size_t)arow * KTOT + k0 + kc * 8;
      Ab[off >> 4] = *(const short8v*)As;
    }
#pragma unroll
    for (int c = 0; c < 2; ++c) {
      int chunk = tid + 256 * c;
      int row = chunk >> 3, kc = chunk & 7;
      const u16* Wp = Wsel + (size_t)(ntile * 64 + row) * KTOT + k0 + kc * 8;
      u32 off = ((u32)(row * 128 + kc * 16)) ^ ((u32)((row & 7) << 4));
      Bb[off >> 4] = *(const short8v*)Wp;
    }
    __syncthreads();
#pragma unroll
    for (int ks = 0; ks < 2; ++ks) {
      short8v af[MI], bfr[2];
#pragma unroll
      for (int mi = 0; mi < MI; ++mi) {
        int row = m0w + mi * 16 + lrow;
        u32 off = ((u32)(row * 128 + ks * 64 + lk * 16)) ^ ((u32)((row & 7) << 4));
        af[mi] = Ab[off >> 4];
      }
#pragma unroll
      for (int ni = 0; ni < 2; ++ni) {
        int row = n0w + ni * 16 + lrow;
        u32 off = ((u32)(row * 128 + ks * 64 + lk * 16)) ^ ((u32)((row & 7) << 4));
        bfr[ni] = Bb[off >> 4];
      }
#pragma unroll
      for (int mi = 0; mi < MI; ++mi)
#pragma unroll
        for (int ni = 0; ni < 2; ++ni)
          acc[mi][ni] = __builtin_amdgcn_mfma_f32_16x16x32_bf16(af[mi], bfr[ni], acc[mi][ni], 0, 0, 0);
    }
  }

  const float qsc = 0.088388347648318447f * 1.4426950408889634f;
#pragma unroll
  for (int ni = 0; ni < 2; ++ni) {
    int n = ntile * 64 + n0w + ni * 16 + lrow;
    float c0 = 0.f;
    if (MODE == 2) c0 = p0[n];
#pragma unroll
    for (int mi = 0; mi < MI; ++mi) {
#pragma unroll
      for (int r = 0; r < 4; ++r) {
        int grow = mbase + mtile * BM + m0w + mi * 16 + lk * 4 + r;
        float val = acc[mi][ni][r];
        if (MODE == 1) {
          if (blockIdx.z == 0) val *= qsc;
          int s = grow & 1023, b_ = grow >> 10;
          u16* ob = (u16*)Out + (size_t)blockIdx.z * 2097152;
          ob[(((size_t)(b_ * kH + (n >> 4))) * kS + s) * kDH + (n & 15)] = f2b(val);
        } else if (MODE == 2) {
          int np = (n & ~56) | ((((n >> 3) ^ grow) & 7) << 3);
          ((u16*)Out)[(size_t)grow * kDFF + np] = f2b(fmaxf(val + c0, 0.f));
        }
      }
    }
  }
}

// =====================================================================
// FF2 pipelined + fused bias/residual/LN2/GAP epilogue (proven)
// =====================================================================
__global__ __launch_bounds__(256, 2) void ff2ln_kernel(
    const u16* __restrict__ Abuf, const u16* __restrict__ w2fb,
    cfp fb2, cfp l2g, cfp l2b, cfp res, float* __restrict__ dout) {
  __shared__ short8v lds[3840];
  __shared__ float st1[2][32], st2[2][32];
  __shared__ float red[128];
  const int tid = threadIdx.x;
  const int mtile = blockIdx.x;
  const int wid = tid >> 6, lane = tid & 63;
  const int lrow = lane & 15, lk = lane >> 4;
  const int m0w = (wid & 1) * 16, n0w = (wid >> 1) * 64;
  if (tid < 128) red[tid] = 0.f;

  float c0[4], gg[4], bb[4];
#pragma unroll
  for (int ni = 0; ni < 4; ++ni) {
    int n = n0w + ni * 16 + lrow;
    c0[ni] = fb2[n]; gg[ni] = l2g[n]; bb[ni] = l2b[n];
  }

  f32x4 acc[4];
#pragma unroll
  for (int ni = 0; ni < 4; ++ni) acc[ni] = (f32x4){0.f, 0.f, 0.f, 0.f};

  const int q = wid * 64 + lane;
  const u16* aG = Abuf + (size_t)(mtile * 32 + (q >> 3)) * 512 + (q & 7) * 8;

  auto stage = [&](int t) {
    int buf = t % 3;
    short8v* A = lds + buf * 1280;
    __builtin_amdgcn_global_load_lds(
        (const __attribute__((address_space(1))) void*)(aG + t * 64),
        (__attribute__((address_space(3))) void*)(A + wid * 64), 16, 0, 0);
#pragma unroll
    for (int r = 0; r < 4; ++r) {
      int qq = r * 256 + q;
      const u16* g = w2fb + (size_t)(qq >> 3) * 512 + t * 64 + (qq & 7) * 8;
      __builtin_amdgcn_global_load_lds(
          (const __attribute__((address_space(1))) void*)g,
          (__attribute__((address_space(3))) void*)(A + 256 + r * 256 + wid * 64), 16, 0, 0);
    }
  };

  auto compute = [&](int t) {
    int buf = t % 3;
    const short8v* A = lds + buf * 1280;
    const short8v* B = A + 256;
#pragma unroll
    for (int ks = 0; ks < 2; ++ks) {
      int ar = m0w + lrow;
      u32 ao = ((u32)(ar * 128 + ks * 64 + lk * 16)) ^ ((u32)((ar & 7) << 4));
      short8v af = A[ao >> 4];
#pragma unroll
      for (int ni = 0; ni < 4; ++ni) {
        int br = n0w + ni * 16 + lrow;
        u32 bo = ((u32)(br * 128 + ks * 64 + lk * 16)) ^ ((u32)((br & 7) << 4));
        short8v bf = B[bo >> 4];
        acc[ni] = __builtin_amdgcn_mfma_f32_16x16x32_bf16(af, bf, acc[ni], 0, 0, 0);
      }
    }
  };

  stage(0); stage(1); stage(2);
  for (int t = 0; t < 6; ++t) {
    wait_vmcnt<10>();
    __builtin_amdgcn_s_barrier();
    __builtin_amdgcn_sched_barrier(0);
    compute(t);
    asm volatile("" ::: "memory");
    __builtin_amdgcn_s_barrier();
    __builtin_amdgcn_sched_barrier(0);
    if (t <= 4) stage(t + 3);
  }
  wait_vmcnt<5>();
  __builtin_amdgcn_s_barrier();
  __builtin_amdgcn_sched_barrier(0);
  compute(6);
  asm volatile("" ::: "memory");
  __builtin_amdgcn_s_barrier();
  __builtin_amdgcn_sched_barrier(0);
  wait_vmcnt<0>();
  __builtin_amdgcn_s_barrier();
  __builtin_amdgcn_sched_barrier(0);
  compute(7);

  float y[4][4];
  float s1[4] = {0.f, 0.f, 0.f, 0.f}, s2[4] = {0.f, 0.f, 0.f, 0.f};
#pragma unroll
  for (int ni = 0; ni < 4; ++ni) {
    int n = n0w + ni * 16 + lrow;
#pragma unroll
    for (int r = 0; r < 4; ++r) {
      int grow = mtile * 32 + m0w + lk * 4 + r;
      float v = acc[ni][r] + c0[ni] + res[(size_t)grow * kE + n];
      y[ni][r] = v;
      s1[r] += v;
      s2[r] += v * v;
    }
  }
#pragma unroll
  for (int r = 0; r < 4; ++r) {
    for (int off = 1; off < 16; off <<= 1) {
      s1[r] += __shfl_xor(s1[r], off);
      s2[r] += __shfl_xor(s2[r], off);
    }
  }
  __syncthreads();
  if (lrow == 0) {
#pragma unroll
    for (int r = 0; r < 4; ++r) {
      int ridx = m0w + lk * 4 + r;
      st1[wid >> 1][ridx] = s1[r];
      st2[wid >> 1][ridx] = s2[r];
    }
  }
  __syncthreads();
  float colsum[4] = {0.f, 0.f, 0.f, 0.f};
#pragma unroll
  for (int r = 0; r < 4; ++r) {
    int ridx = m0w + lk * 4 + r;
    float t1 = st1[0][ridx] + st1[1][ridx];
    float t2 = st2[0][ridx] + st2[1][ridx];
    float mean = t1 * (1.f / 128.f);
    float var = t2 * (1.f / 128.f) - mean * mean;
    float inv = __frsqrt_rn(var + kEps);
#pragma unroll
    for (int ni = 0; ni < 4; ++ni)
      colsum[ni] += (y[ni][r] - mean) * inv * gg[ni] + bb[ni];
  }
#pragma unroll
  for (int ni = 0; ni < 4; ++ni) {
    colsum[ni] += __shfl_xor(colsum[ni], 16);
    colsum[ni] += __shfl_xor(colsum[ni], 32);
  }
  if (lk == 0) {
#pragma unroll
    for (int ni = 0; ni < 4; ++ni)
      atomicAdd(&red[n0w + ni * 16 + lrow], colsum[ni]);
  }
  __syncthreads();
  int b = mtile >> 5;
  if (tid < 128) atomicAdd(&dout[b * kE + tid], red[tid] * (1.f / 1024.f));
}

// =====================================================================
// MFMA attention v9: v8 body + P chunk swizzle (write rq^((q32>>3)&3),
// read lg^((row>>3)&3)) to break 4-way P-write bank conflicts.
// =====================================================================
__global__ __launch_bounds__(512, 2) void attn_kernel(
    const u16* __restrict__ qb, const u16* __restrict__ kb,
    const u16* __restrict__ vb, const u16* __restrict__ rbT,
    float* __restrict__ o) {
  __shared__ u16 Vsh[16 * 1032];
  __shared__ u16 Pt[8][1280];

  int tid = threadIdx.x;
  int bid = blockIdx.x;
  int quarter = bid >> 7;
  int bb = (bid >> 3) & 15;
  int h = bid & 7;
  size_t base = (size_t)(bb * kH + h) * (kS * kDH);

  for (int j = tid; j < 1024; j += 512) {
    const uint4* src = (const uint4*)(vb + base + j * 16);
    uint4 a = src[0], b = src[1];
    u32 wv[8] = {a.x, a.y, a.z, a.w, b.x, b.y, b.z, b.w};
#pragma unroll
    for (int p = 0; p < 8; ++p) {
      Vsh[(2 * p) * 1032 + j]     = (u16)(wv[p] & 0xFFFFu);
      Vsh[(2 * p + 1) * 1032 + j] = (u16)(wv[p] >> 16);
    }
  }
  __syncthreads();

  int w = tid >> 6, l = tid & 63;
  int lr = l & 15, lg = l >> 4;
  int q32 = l & 31, hi = l >> 5;
  u16* P = Pt[w];
  int q0w = quarter * 256 + w * 32;
  int tbase = (q0w + 992) >> 4;
  const u16* rbh = rbT + (size_t)h * 126 * 512;

  short8v qf = *(const short8v*)(qb + base + (size_t)(q0w + q32) * 16 + hi * 8);
  short8v ones;
#pragma unroll
  for (int e = 0; e < 8; ++e) ones[e] = (short)0x3F80;

  f32x4 acc_e[2], acc_rb[2], acc_l[2];
#pragma unroll
  for (int qt = 0; qt < 2; ++qt) {
    acc_e[qt] = (f32x4){0.f, 0.f, 0.f, 0.f};
    acc_rb[qt] = (f32x4){0.f, 0.f, 0.f, 0.f};
    acc_l[qt] = (f32x4){0.f, 0.f, 0.f, 0.f};
  }
  const f32x16 z16 = {0.f,0.f,0.f,0.f,0.f,0.f,0.f,0.f,0.f,0.f,0.f,0.f,0.f,0.f,0.f,0.f};

  const u16* kfp = kb + base + (size_t)q32 * 16 + hi * 8;
  const u16* rfp = rbh + (size_t)tbase * 512 + l * 8;

  short8v kf_c = *(const short8v*)kfp;
  short8v rf0_c = *(const short8v*)rfp;
  short8v rf1_c = *(const short8v*)(rfp + 512);

  const int wswz = (q32 >> 3) & 3;                 // write-side chunk swizzle
  const int c0r = lg ^ ((lr >> 3) & 3);            // read swizzle, qt=0 (rows 0..15)
  const int c1r = lg ^ (((16 + lr) >> 3) & 3);     // read swizzle, qt=1 (rows 16..31)

  for (int jb = 0; jb < 32; ++jb) {
    short8v kf_n, rf0_n, rf1_n;
    if (jb < 31) {
      kf_n = *(const short8v*)(kfp + (size_t)(jb + 1) * 512);
      const u16* rp = rfp - (size_t)(jb + 1) * 1024;
      rf0_n = *(const short8v*)rp;
      rf1_n = *(const short8v*)(rp + 512);
    }
    f32x16 s = __builtin_amdgcn_mfma_f32_32x32x16_bf16(kf_c, qf, z16, 0, 0, 0);
    float ev[16];
#pragma unroll
    for (int r = 0; r < 16; ++r) ev[r] = __builtin_amdgcn_exp2f(s[r]);
#pragma unroll
    for (int rq = 0; rq < 4; ++rq) {
      u32 p0, p1;
      asm("v_cvt_pk_bf16_f32 %0, %1, %2" : "=v"(p0) : "v"(ev[4 * rq]), "v"(ev[4 * rq + 1]));
      asm("v_cvt_pk_bf16_f32 %0, %1, %2" : "=v"(p1) : "v"(ev[4 * rq + 2]), "v"(ev[4 * rq + 3]));
      *(uint2*)(P + q32 * 40 + (rq ^ wswz) * 8 + hi * 4) = make_uint2(p0, p1);
    }
    short8v vf = *(const short8v*)(Vsh + lr * 1032 + jb * 32 + lg * 8);
    {
      short8v pf0 = *(const short8v*)(P + lr * 40 + c0r * 8);
      acc_e[0]  = __builtin_amdgcn_mfma_f32_16x16x32_bf16(pf0, vf, acc_e[0], 0, 0, 0);
      acc_l[0]  = __builtin_amdgcn_mfma_f32_16x16x32_bf16(pf0, ones, acc_l[0], 0, 0, 0);
      acc_rb[0] = __builtin_amdgcn_mfma_f32_16x16x32_bf16(rf0_c, vf, acc_rb[0], 0, 0, 0);
      short8v pf1 = *(const short8v*)(P + (16 + lr) * 40 + c1r * 8);
      acc_e[1]  = __builtin_amdgcn_mfma_f32_16x16x32_bf16(pf1, vf, acc_e[1], 0, 0, 0);
      acc_l[1]  = __builtin_amdgcn_mfma_f32_16x16x32_bf16(pf1, ones, acc_l[1], 0, 0, 0);
      acc_rb[1] = __builtin_amdgcn_mfma_f32_16x16x32_bf16(rf1_c, vf, acc_rb[1], 0, 0, 0);
    }
    if (jb < 31) {
      kf_c = kf_n; rf0_c = rf0_n; rf1_c = rf1_n;
    }
  }

#pragma unroll
  for (int qt = 0; qt < 2; ++qt) {
#pragma unroll
    for (int r = 0; r < 4; ++r) {
      int qloc = qt * 16 + lg * 4 + r;
      int row = q0w + qloc;
      o[(size_t)(bb * kS + row) * kE + h * kDH + lr] =
          acc_e[qt][r] / acc_l[qt][r] + acc_rb[qt][r];
    }
  }
}

// ---------------- LN(attn out) + residual + LN1 -> att (f32 + bf16) ----------------
__global__ __launch_bounds__(256) void ln_kernel(
    cfp o, cfp xsrc, cfp lag, cfp lab, cfp l1g, cfp l1b,
    float* __restrict__ att, u16* __restrict__ attb) {
  int row = blockIdx.x * 4 + (threadIdx.x >> 6);
  int lane = threadIdx.x & 63;
  float2 a = ((const float2*)(o + (size_t)row * kE))[lane];
  float sum = a.x + a.y;
  for (int off = 1; off < 64; off <<= 1) sum += __shfl_xor(sum, off);
  float mean = sum * (1.f / 128.f);
  float d0 = a.x - mean, d1 = a.y - mean;
  float ss = d0 * d0 + d1 * d1;
  for (int off = 1; off < 64; off <<= 1) ss += __shfl_xor(ss, off);
  float inv = 1.f / sqrtf(ss * (1.f / 128.f) + kEps);
  float t0 = d0 * inv * lag[2 * lane] + lab[2 * lane];
  float t1 = d1 * inv * lag[2 * lane + 1] + lab[2 * lane + 1];
  float2 xv = ((const float2*)(xsrc + (size_t)row * kE))[lane];
  t0 += xv.x; t1 += xv.y;
  float sum2 = t0 + t1;
  for (int off = 1; off < 64; off <<= 1) sum2 += __shfl_xor(sum2, off);
  float mean2 = sum2 * (1.f / 128.f);
  float e0 = t0 - mean2, e1 = t1 - mean2;
  float ss2 = e0 * e0 + e1 * e1;
  for (int off = 1; off < 64; off <<= 1) ss2 += __shfl_xor(ss2, off);
  float inv2 = 1.f / sqrtf(ss2 * (1.f / 128.f) + kEps);
  float r0 = e0 * inv2 * l1g[2 * lane] + l1b[2 * lane];
  float r1 = e1 * inv2 * l1g[2 * lane + 1] + l1b[2 * lane + 1];
  ((float2*)(att + (size_t)row * kE))[lane] = make_float2(r0, r1);
  ((u32*)attb)[(size_t)row * 64 + lane] = (u32)f2b(r0) | ((u32)f2b(r1) << 16);
}

extern "C" void kernel_launch(void* const* d_in, const int* in_sizes, int n_in,
                              void* d_out, int out_size, void* d_ws, size_t ws_size,
                              hipStream_t stream) {
  const float* wf[27];
  for (int i = 0; i < n_in && i < 27; ++i) wf[i] = (const float*)d_in[i];

  float* ws = (float*)d_ws;
  float* xsrc  = ws;                             // 2,097,152 f32
  float* att   = xsrc + 2097152;                 // 2,097,152 f32
  float* qkv0  = att + 2097152;                  // 3,145,728 (q,k,v bf16)
  float* ext   = qkv0 + 3145728;                 // 1,048,576 (ff1b tail only)
  float* o     = ext + 1048576;                  // 2,097,152
  u16* xpeb    = (u16*)(o + 2097152);            // 2,097,152 u16
  u16* w2b     = xpeb + 2097152;                 // 262,144 u16
  u16* rbT     = w2b + 262144;                   // 516,096 u16
  u16* w2fb    = rbT + 516096;                   // 65,536 u16
  u16* Abuf    = w2fb + 65536;                   // 33,554,432 u16 (67 MB)
  u16* wqkvb   = Abuf + 33554432;                // 49,152 u16
  u16* w1fb    = wqkvb + 49152;                  // 65,536 u16

  u16* qb = (u16*)qkv0;
  u16* kb = qb + 2097152;
  u16* vb = kb + 2097152;
  u16* ff1b = (u16*)qkv0;
  u16* attb = xpeb;
  float* doutf = (float*)d_out;

  setup_kernel<<<2517, 256, 0, stream>>>(
      wf[0], wf[1], wf[2], wf[3], wf[4], wf[5], wf[6], Abuf,
      wf[7], w2b, wf[16], rbT, wf[23], w2fb, doutf,
      wf[13], wf[14], wf[15], wqkvb, wf[21], w1fb);

  convgemm_kernel<<<512, 256, 0, stream>>>(
      Abuf, w2b, wf[8], wf[9], wf[10], wf[11], wf[12], xsrc, xpeb);

  gemm_kernel<3, 1, 128, 64><<<dim3(256, 2, 3), 256, 0, stream>>>(
      xpeb, wqkvb, nullptr, wqkvb + 16384, wqkvb + 32768, qb, nullptr, 0);

  attn_kernel<<<512, 512, 0, stream>>>(qb, kb, vb, rbT, o);
  ln_kernel<<<4096, 256, 0, stream>>>(o, xsrc, wf[17], wf[18], wf[19], wf[20], att, attb);

  gemm_kernel<3, 2, 128, 64><<<dim3(256, 8), 256, 0, stream>>>(
      attb, w1fb, wf[22], nullptr, nullptr, ff1b, nullptr, 0);

  ff2ln_kernel<<<512, 256, 0, stream>>>(ff1b, w2fb, wf[24], wf[25], wf[26], att, doutf);
}